// Round 6
// baseline (11556.076 us; speedup 1.0000x reference)
//
#include <hip/hip_runtime.h>
#include <math.h>

constexpr int A_TOT  = 40001;
constexpr int NB     = 6;
constexpr int BN_TOT = 160001;
constexpr int AF     = 133;
constexpr int BF     = 147;
constexpr int H      = 300;
constexpr int NMOL   = 1000;
constexpr int ASZ    = 40;

// Packed-weight layout: P[(k4*300+f)*4+j] = W[(k4*4+j)*300+f], zero-padded.
// Packs live in d_out scratch (dead until mean_kernel).
constexpr int PK_WH0 = 0;
constexpr int PK_WH1 = 90000;
constexpr int PK_WIB = 180000;
constexpr int PK_WIA = 224400;

// ---------------------------------------------------------------------------
// Raw GEMV core (W_lr and PATH B).
// ---------------------------------------------------------------------------
template<int NR, int P>
__device__ __forceinline__ void gemv4(const float (*rows)[P], const float* __restrict__ W,
                                      int K, int f, float* __restrict__ acc)
{
    int k4 = 0;
    for (; k4 + 4 <= K; k4 += 4) {
        float w0 = W[(k4 + 0) * H + f];
        float w1 = W[(k4 + 1) * H + f];
        float w2 = W[(k4 + 2) * H + f];
        float w3 = W[(k4 + 3) * H + f];
#pragma unroll
        for (int i = 0; i < NR; ++i) {
            float4 b = *(const float4*)&rows[i][k4];
            acc[i] = fmaf(b.x, w0, fmaf(b.y, w1, fmaf(b.z, w2, fmaf(b.w, w3, acc[i]))));
        }
    }
    for (; k4 < K; ++k4) {
        float wv = W[k4 * H + f];
#pragma unroll
        for (int i = 0; i < NR; ++i) acc[i] = fmaf(rows[i][k4], wv, acc[i]);
    }
}

// ---------------------------------------------------------------------------
// Packed GEMV core: one float4 weight load per k4. Rows zero-padded in LDS.
// REGISTER COST ~5*NR VGPRs (NR staged b-float4s + NR acc): keep NR <= 8,
// else the compiler spills to scratch (R5: NR=24 -> 128 VGPR + 6.4 GB spill).
// ---------------------------------------------------------------------------
template<int NR, int P>
__device__ __forceinline__ void gemv4p(const float (*rows)[P], const float4* __restrict__ Pw,
                                       int K4, int f, float* __restrict__ acc)
{
    for (int k4i = 0; k4i < K4; ++k4i) {
        float4 w = Pw[k4i * 300 + f];
#pragma unroll
        for (int i = 0; i < NR; ++i) {
            float4 b = *(const float4*)&rows[i][k4i * 4];
            acc[i] = fmaf(b.x, w.x, fmaf(b.y, w.y, fmaf(b.z, w.z, fmaf(b.w, w.w, acc[i]))));
        }
    }
}

// ===========================================================================
// Pack Wh0/Wh1/Wi_bond/Wi_atom into d_out scratch.
// ===========================================================================
__global__ __launch_bounds__(256) void k_packmp(
    const float* __restrict__ s0, const float* __restrict__ s1,
    const float* __restrict__ s2, const float* __restrict__ s3,
    float* __restrict__ dout)
{
    const float* S[4] = {s0, s1, s2, s3};
    const int Ks[4]  = {300, 300, 147, 133};
    const int K4s[4] = {75, 75, 37, 34};
    const int off[4] = {PK_WH0, PK_WH1, PK_WIB, PK_WIA};
    int z = blockIdx.y;
    int o = blockIdx.x * 256 + threadIdx.x;
    int n = K4s[z] * 1200;
    if (o < n) {
        int k4 = o / 1200; int rem = o - k4 * 1200;
        int f = rem >> 2;  int j = rem & 3;
        int k = k4 * 4 + j;
        dout[off[z] + o] = (k < Ks[z]) ? S[z][(size_t)k * 300 + f] : 0.f;
    }
}

// ===========================================================================
// K1: msgA1[a,:] = relu(f_atoms[a]@Wi_atom) + sum*max of x_b.
// v3: bond GEMV chunked per atom (NR=6) to avoid the NR=24 spill (R5 lesson).
// ===========================================================================
#define GA 4
__global__ __launch_bounds__(320) void k_msga1(
    const float* __restrict__ f_atoms, const float* __restrict__ f_bonds,
    const float4* __restrict__ PWia, const float4* __restrict__ PWib,
    const int* __restrict__ a2b, float* __restrict__ msgA1)
{
    __shared__ __align__(16) float fb[GA * NB][152];
    __shared__ __align__(16) float fa[GA][136];
    __shared__ int bidx[GA * NB];

    const int a0 = blockIdx.x * GA;
    const int tid = threadIdx.x;
    const int f = tid;

    if (tid < GA * NB) {
        int a = a0 + tid / NB;
        bidx[tid] = (a < A_TOT) ? a2b[a * NB + (tid % NB)] : 0;
    }
    __syncthreads();
    for (int idx = tid; idx < GA * NB * 148; idx += 320) {
        int i = idx / 148, k = idx - i * 148;
        fb[i][k] = (k < BF) ? f_bonds[(size_t)bidx[i] * BF + k] : 0.f;
    }
    for (int idx = tid; idx < GA * 136; idx += 320) {
        int l = idx / 136, k = idx - l * 136;
        int a = a0 + l;
        fa[l][k] = (a < A_TOT && k < AF) ? f_atoms[(size_t)a * AF + k] : 0.f;
    }
    __syncthreads();

    if (f < H) {
        float part[GA];
#pragma unroll
        for (int l = 0; l < GA; ++l) {
            float acc[NB];
#pragma unroll
            for (int j = 0; j < NB; ++j) acc[j] = 0.f;
            gemv4p<NB, 152>((const float (*)[152])&fb[l * NB], PWib, 37, f, acc);
            float s = 0.f, mx = -INFINITY;
#pragma unroll
            for (int j = 0; j < NB; ++j) {
                float x = fmaxf(acc[j], 0.f);
                s += x; mx = fmaxf(mx, x);
            }
            part[l] = s * mx;
        }
        float acc2[GA];
#pragma unroll
        for (int l = 0; l < GA; ++l) acc2[l] = 0.f;
        gemv4p<GA, 136>(fa, PWia, 34, f, acc2);
#pragma unroll
        for (int l = 0; l < GA; ++l) {
            int a = a0 + l;
            if (a < A_TOT) msgA1[(size_t)a * H + f] = fmaxf(acc2[l], 0.f) + part[l];
        }
    }
}

// ===========================================================================
// PATH A: m1 fp32 materialization.  NR2=8: no spill (~50 VGPR), 6 blocks/CU.
// ===========================================================================
#define NR2 8
__global__ __launch_bounds__(320) void k_m1f(
    const float* __restrict__ f_bonds, const float4* __restrict__ PWib,
    const float4* __restrict__ PWh0, const float* __restrict__ msgA1,
    const int* __restrict__ b2a, const int* __restrict__ b2revb,
    float* __restrict__ m1)
{
    __shared__ __align__(16) float v[NR2][304];
    __shared__ __align__(16) float fbl[NR2][152];
    __shared__ int r_[NR2], q_[NR2], p_[NR2];

    const int r0 = blockIdx.x * NR2;
    const int tid = threadIdx.x;
    const int f = tid;

    if (tid < NR2) {
        int r = r0 + tid;
        if (r >= BN_TOT) r = 0;
        r_[tid] = r;
        q_[tid] = b2revb[r];
        p_[tid] = b2a[r];
    }
    __syncthreads();
    for (int idx = tid; idx < NR2 * 75; idx += 320) {
        int i = idx / 75, k4 = idx - i * 75;
        ((float4*)v[i])[k4] = ((const float4*)(msgA1 + (size_t)p_[i] * H))[k4];
    }
    for (int idx = tid; idx < NR2 * 148; idx += 320) {
        int i = idx / 148, k = idx - i * 148;
        fbl[i][k] = (k < BF) ? f_bonds[(size_t)q_[i] * BF + k] : 0.f;
    }
    __syncthreads();
    if (f < H) {
        float acc[NR2];
#pragma unroll
        for (int i = 0; i < NR2; ++i) acc[i] = 0.f;
        gemv4p<NR2, 152>(fbl, PWib, 37, f, acc);
#pragma unroll
        for (int i = 0; i < NR2; ++i) v[i][f] -= fmaxf(acc[i], 0.f);
    }
    __syncthreads();
    for (int idx = tid; idx < NR2 * 148; idx += 320) {
        int i = idx / 148, k = idx - i * 148;
        fbl[i][k] = (k < BF) ? f_bonds[(size_t)r_[i] * BF + k] : 0.f;
    }
    float accm[NR2];
#pragma unroll
    for (int i = 0; i < NR2; ++i) accm[i] = 0.f;
    if (f < H) gemv4p<NR2, 304>(v, PWh0, 75, f, accm);
    __syncthreads();
    if (f < H) {
        float accr[NR2];
#pragma unroll
        for (int i = 0; i < NR2; ++i) accr[i] = 0.f;
        gemv4p<NR2, 152>(fbl, PWib, 37, f, accr);
#pragma unroll
        for (int i = 0; i < NR2; ++i) {
            int r = r0 + i;
            if (r < BN_TOT)
                m1[(size_t)r * H + f] = fmaxf(fmaxf(accr[i], 0.f) + accm[i], 0.f);
        }
    }
}

__global__ __launch_bounds__(256) void k_msga2ef(
    const float* __restrict__ m1, const int* __restrict__ a2b, float* msgA)
{
    int idx = blockIdx.x * 256 + threadIdx.x;
    if (idx >= A_TOT * H) return;
    int a = idx / H;
    int f = idx - a * H;
    float s = 0.f, mx = -INFINITY;
#pragma unroll
    for (int j = 0; j < NB; ++j) {
        int r = a2b[a * NB + j];
        float v = m1[(size_t)r * H + f];
        s += v;
        mx = fmaxf(mx, v);
    }
    msgA[idx] += s * mx;
}

// GC=1: LDS ~15.2 KB -> 6 blocks/CU (wave-capped), 40001 blocks.
#define GC 1
#define RC (GC * NB)   // 6
__global__ __launch_bounds__(320) void k_aggl2f(
    const float* __restrict__ f_atoms, const float* __restrict__ f_bonds,
    const float4* __restrict__ PWia, const float4* __restrict__ PWib,
    const float4* __restrict__ PWh1, const float* __restrict__ W_lr,
    const float* __restrict__ msgA2, const float* __restrict__ m1,
    const int* __restrict__ a2b, const int* __restrict__ b2a,
    const int* __restrict__ b2revb, float* __restrict__ aggL)
{
    __shared__ __align__(16) float w[RC][304];
    __shared__ __align__(16) float fbl[RC][152];
    __shared__ __align__(16) float agg3r[GC][304];
    __shared__ __align__(16) float mA2r[GC][304];
    __shared__ __align__(16) float inAr[GC][304];
    __shared__ __align__(16) float fa[GC][136];
    __shared__ int b_[RC], rp_[RC], p2_[RC];

    const int a0 = blockIdx.x * GC;
    const int tid = threadIdx.x;
    const int f = tid;

    if (tid < RC) {
        int a = a0 + tid / NB;
        int b = (a < A_TOT) ? a2b[a * NB + (tid % NB)] : 0;
        b_[tid] = b;
        rp_[tid] = b2revb[b];
        p2_[tid] = b2a[b];
    }
    __syncthreads();
    for (int idx = tid; idx < RC * 75; idx += 320) {
        int i = idx / 75, k4 = idx - i * 75;
        float4 a4 = ((const float4*)(msgA2 + (size_t)p2_[i] * H))[k4];
        float4 b4 = ((const float4*)(m1 + (size_t)rp_[i] * H))[k4];
        ((float4*)w[i])[k4] = make_float4(a4.x - b4.x, a4.y - b4.y, a4.z - b4.z, a4.w - b4.w);
    }
    for (int idx = tid; idx < RC * 148; idx += 320) {
        int i = idx / 148, k = idx - i * 148;
        fbl[i][k] = (k < BF) ? f_bonds[(size_t)b_[i] * BF + k] : 0.f;
    }
    for (int idx = tid; idx < GC * 75; idx += 320) {
        int l = idx / 75, k4 = idx - l * 75;
        int a = a0 + l;
        ((float4*)mA2r[l])[k4] = (a < A_TOT) ? ((const float4*)(msgA2 + (size_t)a * H))[k4]
                                             : make_float4(0.f, 0.f, 0.f, 0.f);
    }
    for (int idx = tid; idx < GC * 136; idx += 320) {
        int l = idx / 136, k = idx - l * 136;
        int a = a0 + l;
        fa[l][k] = (a < A_TOT && k < AF) ? f_atoms[(size_t)a * AF + k] : 0.f;
    }
    __syncthreads();

    if (f < H) {
        float accm[RC], accb[RC];
#pragma unroll
        for (int i = 0; i < RC; ++i) { accm[i] = 0.f; accb[i] = 0.f; }
        gemv4p<RC, 304>(w, PWh1, 75, f, accm);
        gemv4p<RC, 152>(fbl, PWib, 37, f, accb);
#pragma unroll
        for (int l = 0; l < GC; ++l) {
            float s = 0.f, mx = -INFINITY;
#pragma unroll
            for (int j = 0; j < NB; ++j) {
                int i = l * NB + j;
                float m2 = fmaxf(fmaxf(accb[i], 0.f) + accm[i], 0.f);
                s += m2; mx = fmaxf(mx, m2);
            }
            agg3r[l][f] = s * mx;
        }
        float acc2[GC];
#pragma unroll
        for (int l = 0; l < GC; ++l) acc2[l] = 0.f;
        gemv4p<GC, 136>(fa, PWia, 34, f, acc2);
#pragma unroll
        for (int l = 0; l < GC; ++l) inAr[l][f] = fmaxf(acc2[l], 0.f);
    }
    __syncthreads();

    if (f < H) {
        float accL[GC];
#pragma unroll
        for (int l = 0; l < GC; ++l) accL[l] = 0.f;
        gemv4<GC, 304>(agg3r, W_lr,            H, f, accL);
        gemv4<GC, 304>(mA2r, W_lr + 300 * 300, H, f, accL);
        gemv4<GC, 304>(inAr, W_lr + 600 * 300, H, f, accL);
#pragma unroll
        for (int l = 0; l < GC; ++l) {
            int a = a0 + l;
            if (a < A_TOT) aggL[(size_t)a * H + f] = accL[l];
        }
    }
}

// ===========================================================================
// PATH B kernels (not exercised when bigws) — unchanged.
// ===========================================================================
#define GB 4
#define RB (GB * NB)   // 24
__global__ __launch_bounds__(320) void k_msga2b(
    const float* __restrict__ f_bonds, const float* __restrict__ Wi_bond,
    const float* __restrict__ Wh0,
    const float* __restrict__ msgA1, float* __restrict__ msgA2,
    const int* __restrict__ a2b, const int* __restrict__ b2a,
    const int* __restrict__ b2revb)
{
    __shared__ __align__(16) float v[RB][304];
    __shared__ __align__(16) float fbl[RB][152];
    __shared__ int r_[RB], q_[RB], p_[RB];

    const int a0 = blockIdx.x * GB;
    const int tid = threadIdx.x;
    const int f = tid;

    if (tid < RB) {
        int a = a0 + tid / NB;
        int r = (a < A_TOT) ? a2b[a * NB + (tid % NB)] : 0;
        r_[tid] = r;
        q_[tid] = b2revb[r];
        p_[tid] = b2a[r];
    }
    __syncthreads();
    for (int idx = tid; idx < RB * 75; idx += 320) {
        int i = idx / 75, k4 = idx - i * 75;
        ((float4*)v[i])[k4] = ((const float4*)(msgA1 + (size_t)p_[i] * H))[k4];
    }
    for (int idx = tid; idx < RB * BF; idx += 320) {
        int i = idx / BF, k = idx - i * BF;
        fbl[i][k] = f_bonds[(size_t)q_[i] * BF + k];
    }
    __syncthreads();
    if (f < H) {
        float acc[RB];
#pragma unroll
        for (int i = 0; i < RB; ++i) acc[i] = 0.f;
        gemv4<RB, 152>(fbl, Wi_bond, BF, f, acc);
#pragma unroll
        for (int i = 0; i < RB; ++i) v[i][f] -= fmaxf(acc[i], 0.f);
    }
    __syncthreads();
    for (int idx = tid; idx < RB * BF; idx += 320) {
        int i = idx / BF, k = idx - i * BF;
        fbl[i][k] = f_bonds[(size_t)r_[i] * BF + k];
    }
    float accm[RB];
#pragma unroll
    for (int i = 0; i < RB; ++i) accm[i] = 0.f;
    if (f < H) gemv4<RB, 304>(v, Wh0, H, f, accm);
    __syncthreads();
    if (f < H) {
        float accr[RB];
#pragma unroll
        for (int i = 0; i < RB; ++i) accr[i] = 0.f;
        gemv4<RB, 152>(fbl, Wi_bond, BF, f, accr);
#pragma unroll
        for (int l = 0; l < GB; ++l) {
            float s = 0.f, mx = -INFINITY;
#pragma unroll
            for (int j = 0; j < NB; ++j) {
                int i = l * NB + j;
                float m1 = fmaxf(fmaxf(accr[i], 0.f) + accm[i], 0.f);
                s += m1; mx = fmaxf(mx, m1);
            }
            int a = a0 + l;
            if (a < A_TOT)
                msgA2[(size_t)a * H + f] = msgA1[(size_t)a * H + f] + s * mx;
        }
    }
}

#define GCB 2
#define RCB (GCB * NB)   // 12
__global__ __launch_bounds__(320) void k_agglb(
    const float* __restrict__ f_atoms, const float* __restrict__ f_bonds,
    const float* __restrict__ Wi_atom, const float* __restrict__ Wi_bond,
    const float* __restrict__ Wh0, const float* __restrict__ Wh1,
    const float* __restrict__ W_lr,
    const float* __restrict__ msgA1, const float* __restrict__ msgA2,
    const int* __restrict__ a2b, const int* __restrict__ b2a,
    const int* __restrict__ b2revb, float* __restrict__ aggL)
{
    __shared__ __align__(16) float u[RCB][304];
    __shared__ __align__(16) float w[RCB][304];
    __shared__ __align__(16) float fbl[RCB][152];
    __shared__ __align__(16) float agg3r[GCB][304];
    __shared__ __align__(16) float mA2r[GCB][304];
    __shared__ __align__(16) float inAr[GCB][304];
    __shared__ __align__(16) float fa[GCB][136];
    __shared__ int b_[RCB], rp_[RCB], p1_[RCB], q1_[RCB], p2_[RCB];

    const int a0 = blockIdx.x * GCB;
    const int tid = threadIdx.x;
    const int f = tid;

    if (tid < RCB) {
        int a = a0 + tid / NB;
        int b = (a < A_TOT) ? a2b[a * NB + (tid % NB)] : 0;
        int rp = b2revb[b];
        b_[tid] = b; rp_[tid] = rp;
        p1_[tid] = b2a[rp]; q1_[tid] = b2revb[rp]; p2_[tid] = b2a[b];
    }
    __syncthreads();
    for (int idx = tid; idx < RCB * 75; idx += 320) {
        int i = idx / 75, k4 = idx - i * 75;
        ((float4*)u[i])[k4] = ((const float4*)(msgA1 + (size_t)p1_[i] * H))[k4];
        ((float4*)w[i])[k4] = ((const float4*)(msgA2 + (size_t)p2_[i] * H))[k4];
    }
    for (int idx = tid; idx < RCB * BF; idx += 320) {
        int i = idx / BF, k = idx - i * BF;
        fbl[i][k] = f_bonds[(size_t)q1_[i] * BF + k];
    }
    for (int idx = tid; idx < GCB * 75; idx += 320) {
        int l = idx / 75, k4 = idx - l * 75;
        int a = a0 + l;
        ((float4*)mA2r[l])[k4] = (a < A_TOT) ? ((const float4*)(msgA2 + (size_t)a * H))[k4]
                                             : make_float4(0.f, 0.f, 0.f, 0.f);
    }
    for (int idx = tid; idx < GCB * AF; idx += 320) {
        int l = idx / AF, k = idx - l * AF;
        int a = a0 + l;
        fa[l][k] = (a < A_TOT) ? f_atoms[(size_t)a * AF + k] : 0.f;
    }
    __syncthreads();
    if (f < H) {
        float acc[RCB];
#pragma unroll
        for (int i = 0; i < RCB; ++i) acc[i] = 0.f;
        gemv4<RCB, 152>(fbl, Wi_bond, BF, f, acc);
#pragma unroll
        for (int i = 0; i < RCB; ++i) u[i][f] -= fmaxf(acc[i], 0.f);
    }
    __syncthreads();
    for (int idx = tid; idx < RCB * BF; idx += 320) {
        int i = idx / BF, k = idx - i * BF;
        fbl[i][k] = f_bonds[(size_t)rp_[i] * BF + k];
    }
    __syncthreads();
    if (f < H) {
        float accm[RCB], accr[RCB];
#pragma unroll
        for (int i = 0; i < RCB; ++i) { accm[i] = 0.f; accr[i] = 0.f; }
        gemv4<RCB, 304>(u, Wh0, H, f, accm);
        gemv4<RCB, 152>(fbl, Wi_bond, BF, f, accr);
#pragma unroll
        for (int i = 0; i < RCB; ++i)
            w[i][f] -= fmaxf(fmaxf(accr[i], 0.f) + accm[i], 0.f);
    }
    __syncthreads();
    for (int idx = tid; idx < RCB * BF; idx += 320) {
        int i = idx / BF, k = idx - i * BF;
        fbl[i][k] = f_bonds[(size_t)b_[i] * BF + k];
    }
    __syncthreads();
    if (f < H) {
        float accm[RCB], accb[RCB];
#pragma unroll
        for (int i = 0; i < RCB; ++i) { accm[i] = 0.f; accb[i] = 0.f; }
        gemv4<RCB, 304>(w, Wh1, H, f, accm);
        gemv4<RCB, 152>(fbl, Wi_bond, BF, f, accb);
#pragma unroll
        for (int l = 0; l < GCB; ++l) {
            float s = 0.f, mx = -INFINITY;
#pragma unroll
            for (int j = 0; j < NB; ++j) {
                int i = l * NB + j;
                float m2 = fmaxf(fmaxf(accb[i], 0.f) + accm[i], 0.f);
                s += m2; mx = fmaxf(mx, m2);
            }
            agg3r[l][f] = s * mx;
        }
        float acc2[GCB];
#pragma unroll
        for (int l = 0; l < GCB; ++l) acc2[l] = 0.f;
        gemv4<GCB, 136>(fa, Wi_atom, AF, f, acc2);
#pragma unroll
        for (int l = 0; l < GCB; ++l) inAr[l][f] = fmaxf(acc2[l], 0.f);
    }
    __syncthreads();
    if (f < H) {
        float accL[GCB];
#pragma unroll
        for (int l = 0; l < GCB; ++l) accL[l] = 0.f;
        gemv4<GCB, 304>(agg3r, W_lr,            H, f, accL);
        gemv4<GCB, 304>(mA2r, W_lr + 300 * 300, H, f, accL);
        gemv4<GCB, 304>(inAr, W_lr + 600 * 300, H, f, accL);
#pragma unroll
        for (int l = 0; l < GCB; ++l) {
            int a = a0 + l;
            if (a < A_TOT) aggL[(size_t)a * H + f] = accL[l];
        }
    }
}

// ===========================================================================
// Pack 4 [900,300] GRU weight mats -> P[k/4][gate][f][k%4]  (270000 each)
// ===========================================================================
__global__ __launch_bounds__(256) void k_pack4(
    const float* __restrict__ s0, const float* __restrict__ s1,
    const float* __restrict__ s2, const float* __restrict__ s3,
    float* __restrict__ d0, float* __restrict__ d1,
    float* __restrict__ d2, float* __restrict__ d3)
{
    const float* S[4] = {s0, s1, s2, s3};
    float* D[4] = {d0, d1, d2, d3};
    int z = blockIdx.y;
    int o = blockIdx.x * 256 + threadIdx.x;
    if (o < 270000) {
        int k4 = o / 3600; int rem = o - k4 * 3600;
        int g = rem / 1200; int rem2 = rem - g * 1200;
        int fx = rem2 >> 2; int kk = rem2 & 3;
        int k = k4 * 4 + kk;
        D[z][o] = S[z][(size_t)(g * 300 + fx) * 300 + k];
    }
}

// ===========================================================================
// prep: h0[m] = max_t aggL[1+m*40+t]; then aggL row <- relu(row + gru_bias)
// ===========================================================================
__global__ __launch_bounds__(256) void prep_kernel(
    float* aggL, const float* __restrict__ gru_bias, float* __restrict__ h0)
{
    int m = blockIdx.x;
    for (int f = threadIdx.x; f < H; f += 256) {
        float b = gru_bias[f];
        float mx = -INFINITY;
        for (int t = 0; t < ASZ; ++t) {
            size_t o = (size_t)(1 + m * ASZ + t) * H + f;
            float v = aggL[o];
            mx = fmaxf(mx, v);
            aggL[o] = fmaxf(v + b, 0.f);
        }
        h0[(size_t)m * H + f] = mx;
    }
}

__device__ __forceinline__ float dev_sigmoid(float x) {
    return 1.f / (1.f + __expf(-x));
}
__device__ __forceinline__ float dev_tanh(float x) {
    return 1.f - 2.f / (__expf(2.f * x) + 1.f);
}

// ===========================================================================
// Persistent GRU, v3 (R3-verified).
// ===========================================================================
#define GM 8
__global__ __launch_bounds__(320) void k_gru_all(
    const float* __restrict__ msg,
    const float* __restrict__ Pih_f, const float* __restrict__ Phh_f,
    const float* __restrict__ bih_f, const float* __restrict__ bhh_f,
    const float* __restrict__ Pih_b, const float* __restrict__ Phh_b,
    const float* __restrict__ bih_b, const float* __restrict__ bhh_b,
    const float* __restrict__ h0, float* __restrict__ out_f,
    float* __restrict__ out_b)
{
    __shared__ __align__(16) float hs[GM][304];
    __shared__ __align__(16) float ms[2][GM][304];

    const int bid  = blockIdx.x;
    const int xcd  = bid & 7;
    const int slot = bid >> 3;
    const int dir  = xcd >> 2;
    const int lg   = (xcd & 3) * 32 + slot;
    const int m0   = lg * GM;
    if (m0 >= NMOL) return;

    const float* Pih = dir ? Pih_b : Pih_f;
    const float* Phh = dir ? Phh_b : Phh_f;
    const float* bih = dir ? bih_b : bih_f;
    const float* bhh = dir ? bhh_b : bhh_f;
    float* out       = dir ? out_b : out_f;

    const int tid  = threadIdx.x;
    const bool act = tid < H;
    const int f    = act ? tid : (H - 1);

    for (int idx = tid; idx < GM * 75; idx += 320) {
        int i = idx / 75, k4 = idx - i * 75;
        int m = m0 + i;
        ((float4*)hs[i])[k4] = (m < NMOL) ? ((const float4*)(h0 + (size_t)m * H))[k4]
                                          : make_float4(0.f, 0.f, 0.f, 0.f);
    }
    {
        const int t0 = dir ? (ASZ - 1) : 0;
        for (int idx = tid; idx < GM * 75; idx += 320) {
            int i = idx / 75, k4 = idx - i * 75;
            int m = m0 + i;
            ((float4*)ms[0][i])[k4] = (m < NMOL)
                ? ((const float4*)(msg + (size_t)(m * ASZ + t0) * H))[k4]
                : make_float4(0.f, 0.f, 0.f, 0.f);
        }
    }

    float bR = 0.f, bZ = 0.f, bIN = 0.f, bHN = 0.f;
    if (act) {
        bR  = bih[f] + bhh[f];
        bZ  = bih[300 + f] + bhh[300 + f];
        bIN = bih[600 + f];
        bHN = bhh[600 + f];
    }
    const float* pi = Pih + (size_t)f * 4;
    const float* ph = Phh + (size_t)f * 4;

    for (int s = 0; s < ASZ; ++s) {
        const int cur = s & 1;
        const int t = dir ? (ASZ - 1 - s) : s;
        __syncthreads();

        float4 st0 = make_float4(0.f, 0.f, 0.f, 0.f);
        float4 st1 = make_float4(0.f, 0.f, 0.f, 0.f);
        const bool more = (s + 1 < ASZ);
        if (more) {
            const int tn = dir ? (ASZ - 2 - s) : (s + 1);
            {
                int i = tid / 75, k4 = tid - i * 75;
                int m = m0 + i;
                if (m < NMOL)
                    st0 = ((const float4*)(msg + (size_t)(m * ASZ + tn) * H))[k4];
            }
            {
                int idx = tid + 320;
                if (idx < GM * 75) {
                    int i = idx / 75, k4 = idx - i * 75;
                    int m = m0 + i;
                    if (m < NMOL)
                        st1 = ((const float4*)(msg + (size_t)(m * ASZ + tn) * H))[k4];
                }
            }
        }

        float aR[GM], aZ[GM], aIN[GM], aHN[GM];
#pragma unroll
        for (int i = 0; i < GM; ++i) { aR[i] = 0.f; aZ[i] = 0.f; aIN[i] = 0.f; aHN[i] = 0.f; }

        float4 wiR = *(const float4*)(pi);
        float4 wiZ = *(const float4*)(pi + 1200);
        float4 wiN = *(const float4*)(pi + 2400);
        float4 whR = *(const float4*)(ph);
        float4 whZ = *(const float4*)(ph + 1200);
        float4 whN = *(const float4*)(ph + 2400);

        for (int k4i = 0; k4i < 75; ++k4i) {
            const int kn = k4i + (k4i < 74 ? 1 : 0);
            const float* pin = pi + (size_t)kn * 3600;
            const float* phn = ph + (size_t)kn * 3600;
            float4 nR = *(const float4*)(pin);
            float4 nZ = *(const float4*)(pin + 1200);
            float4 nN = *(const float4*)(pin + 2400);
            float4 oR = *(const float4*)(phn);
            float4 oZ = *(const float4*)(phn + 1200);
            float4 oN = *(const float4*)(phn + 2400);

            const int k4 = k4i * 4;
#pragma unroll
            for (int i = 0; i < GM; ++i) {
                float4 m4 = *(const float4*)&ms[cur][i][k4];
                float4 h4 = *(const float4*)&hs[i][k4];
                aR[i]  = fmaf(m4.x, wiR.x, fmaf(m4.y, wiR.y, fmaf(m4.z, wiR.z, fmaf(m4.w, wiR.w, aR[i]))));
                aR[i]  = fmaf(h4.x, whR.x, fmaf(h4.y, whR.y, fmaf(h4.z, whR.z, fmaf(h4.w, whR.w, aR[i]))));
                aZ[i]  = fmaf(m4.x, wiZ.x, fmaf(m4.y, wiZ.y, fmaf(m4.z, wiZ.z, fmaf(m4.w, wiZ.w, aZ[i]))));
                aZ[i]  = fmaf(h4.x, whZ.x, fmaf(h4.y, whZ.y, fmaf(h4.z, whZ.z, fmaf(h4.w, whZ.w, aZ[i]))));
                aIN[i] = fmaf(m4.x, wiN.x, fmaf(m4.y, wiN.y, fmaf(m4.z, wiN.z, fmaf(m4.w, wiN.w, aIN[i]))));
                aHN[i] = fmaf(h4.x, whN.x, fmaf(h4.y, whN.y, fmaf(h4.z, whN.z, fmaf(h4.w, whN.w, aHN[i]))));
            }
            wiR = nR; wiZ = nZ; wiN = nN;
            whR = oR; whZ = oZ; whN = oN;
        }
        __syncthreads();

        if (act) {
#pragma unroll
            for (int i = 0; i < GM; ++i) {
                int m = m0 + i;
                if (m < NMOL) {
                    float r = dev_sigmoid(aR[i] + bR);
                    float z = dev_sigmoid(aZ[i] + bZ);
                    float n = dev_tanh(aIN[i] + bIN + r * (aHN[i] + bHN));
                    float hn = (1.f - z) * n + z * hs[i][f];
                    hs[i][f] = hn;
                    __builtin_nontemporal_store(hn, out + (size_t)(m * ASZ + t) * H + f);
                }
            }
        }
        if (more) {
            const int nxt = cur ^ 1;
            {
                int i = tid / 75, k4 = tid - i * 75;
                ((float4*)ms[nxt][i])[k4] = st0;
            }
            {
                int idx = tid + 320;
                if (idx < GM * 75) {
                    int i = idx / 75, k4 = idx - i * 75;
                    ((float4*)ms[nxt][i])[k4] = st1;
                }
            }
        }
    }
}

// ===========================================================================
// Fused output projection: hid = relu([outf|outb] @ W_o + b_o), K=600.
// ===========================================================================
__global__ __launch_bounds__(256) void gemm_wo(
    const float* __restrict__ A0, const float* __restrict__ A1,
    const float* __restrict__ W, float* __restrict__ C,
    const float* __restrict__ bias)
{
    const int M = NMOL * ASZ, K2 = 600, N = H;
    __shared__ float As[16][64];
    __shared__ float Bs[16][64];
    const int tx = threadIdx.x, ty = threadIdx.y;
    const int tid = ty * 16 + tx;
    const int m0 = blockIdx.x * 64, n0 = blockIdx.y * 64;
    const int am = tid >> 2, ak = (tid & 3) * 4;
    const int bk = tid >> 4, bn = (tid & 15) * 4;
    const int arow = m0 + am;

    float acc[4][4];
#pragma unroll
    for (int i = 0; i < 4; ++i)
#pragma unroll
        for (int j = 0; j < 4; ++j) acc[i][j] = 0.f;

    for (int k0 = 0; k0 < K2; k0 += 16) {
#pragma unroll
        for (int j = 0; j < 4; ++j) {
            int k = k0 + ak + j;
            float v = 0.f;
            if (arow < M && k < K2)
                v = (k < 300) ? A0[(size_t)arow * 300 + k]
                              : A1[(size_t)arow * 300 + (k - 300)];
            As[ak + j][am] = v;
        }
#pragma unroll
        for (int j = 0; j < 4; ++j) {
            int k = k0 + bk, n = n0 + bn + j;
            Bs[bk][bn + j] = (k < K2 && n < N) ? W[(size_t)k * N + n] : 0.f;
        }
        __syncthreads();
#pragma unroll
        for (int kk = 0; kk < 16; ++kk) {
            float4 av = *(const float4*)&As[kk][ty * 4];
            float4 bv = *(const float4*)&Bs[kk][tx * 4];
            float a4[4] = {av.x, av.y, av.z, av.w};
            float b4[4] = {bv.x, bv.y, bv.z, bv.w};
#pragma unroll
            for (int i = 0; i < 4; ++i)
#pragma unroll
                for (int j = 0; j < 4; ++j)
                    acc[i][j] = fmaf(a4[i], b4[j], acc[i][j]);
        }
        __syncthreads();
    }
#pragma unroll
    for (int i = 0; i < 4; ++i) {
        int m = m0 + ty * 4 + i;
        if (m >= M) continue;
#pragma unroll
        for (int j = 0; j < 4; ++j) {
            int n = n0 + tx * 4 + j;
            if (n >= N) continue;
            C[(size_t)m * N + n] = fmaxf(acc[i][j] + bias[n], 0.f);
        }
    }
}

__global__ __launch_bounds__(256) void mean_kernel(
    const float* __restrict__ hid, float* __restrict__ out)
{
    int m = blockIdx.x;
    for (int f = threadIdx.x; f < H; f += 256) {
        float s = 0.f;
        for (int t = 0; t < ASZ; ++t)
            s += hid[(size_t)(m * ASZ + t) * H + f];
        out[(size_t)m * H + f] = s * (1.f / 40.f);
    }
}

// ===========================================================================
extern "C" void kernel_launch(void* const* d_in, const int* in_sizes, int n_in,
                              void* d_out, int out_size, void* d_ws, size_t ws_size,
                              hipStream_t stream)
{
    const float* f_atoms  = (const float*)d_in[0];
    const float* f_bonds  = (const float*)d_in[1];
    const float* Wi_atom  = (const float*)d_in[2];
    const float* Wi_bond  = (const float*)d_in[3];
    const float* Wh0      = (const float*)d_in[4];
    const float* Wh1      = (const float*)d_in[5];
    const float* W_lr     = (const float*)d_in[6];
    const float* W_o      = (const float*)d_in[7];
    const float* b_o      = (const float*)d_in[8];
    const float* gru_bias = (const float*)d_in[9];
    const float* gWih_f   = (const float*)d_in[10];
    const float* gWhh_f   = (const float*)d_in[11];
    const float* gbih_f   = (const float*)d_in[12];
    const float* gbhh_f   = (const float*)d_in[13];
    const float* gWih_b   = (const float*)d_in[14];
    const float* gWhh_b   = (const float*)d_in[15];
    const float* gbih_b   = (const float*)d_in[16];
    const float* gbhh_b   = (const float*)d_in[17];
    const int*   a2b      = (const int*)d_in[18];
    const int*   b2a      = (const int*)d_in[19];
    const int*   b2revb   = (const int*)d_in[20];

    char* wsb = (char*)d_ws;
    const bool bigws = (ws_size >= (size_t)288003600);

    // Pack MP weights into d_out scratch (dead until mean_kernel overwrites it)
    float* dscratch = (float*)d_out;
    {
        dim3 g((90000 + 255) / 256, 4);
        k_packmp<<<g, 256, 0, stream>>>(Wh0, Wh1, Wi_bond, Wi_atom, dscratch);
    }
    const float4* PWh0 = (const float4*)(dscratch + PK_WH0);
    const float4* PWh1 = (const float4*)(dscratch + PK_WH1);
    const float4* PWib = (const float4*)(dscratch + PK_WIB);
    const float4* PWia = (const float4*)(dscratch + PK_WIA);

    float *aggLp, *outfp, *outbp, *h0p, *P0, *P1, *P2, *P3, *hidp;

    if (bigws) {
        // PATH A: fp32 m1 materialization.  Peak = 288,003,600 B.
        float* msgA = (float*)wsb;
        float* aggL = (float*)(wsb + 48001200);
        float* m1   = (float*)(wsb + 96002400);
        outfp = (float*)(wsb + 96002400);
        outbp = (float*)(wsb + 144002400);
        P0 = (float*)(wsb + 192002400);
        P1 = P0 + 270000; P2 = P1 + 270000; P3 = P2 + 270000;
        h0p = (float*)(wsb + 196322400);
        aggLp = aggL; hidp = msgA;

        k_msga1<<<(A_TOT + GA - 1) / GA, 320, 0, stream>>>(
            f_atoms, f_bonds, PWia, PWib, a2b, msgA);
        k_m1f<<<(BN_TOT + NR2 - 1) / NR2, 320, 0, stream>>>(
            f_bonds, PWib, PWh0, msgA, b2a, b2revb, m1);
        k_msga2ef<<<(A_TOT * H + 255) / 256, 256, 0, stream>>>(m1, a2b, msgA);
        k_aggl2f<<<(A_TOT + GC - 1) / GC, 320, 0, stream>>>(
            f_atoms, f_bonds, PWia, PWib, PWh1, W_lr,
            msgA, m1, a2b, b2a, b2revb, aggL);
    } else {
        // PATH B: recompute path (no m1 buffer).  Peak = 240,003,600 B.
        float* ws = (float*)d_ws;
        float* msgA1 = ws;
        float* msgA2 = ws + 12000300;
        float* aggL  = ws + 24000600;
        outfp = ws + 36000900;
        outbp = ws + 48000900;
        h0p   = ws;
        P0 = ws + 300000; P1 = ws + 570000; P2 = ws + 840000; P3 = ws + 1110000;
        aggLp = aggL; hidp = msgA2;

        k_msga1<<<(A_TOT + GA - 1) / GA, 320, 0, stream>>>(
            f_atoms, f_bonds, PWia, PWib, a2b, msgA1);
        k_msga2b<<<(A_TOT + GB - 1) / GB, 320, 0, stream>>>(
            f_bonds, Wi_bond, Wh0, msgA1, msgA2, a2b, b2a, b2revb);
        k_agglb<<<(A_TOT + GCB - 1) / GCB, 320, 0, stream>>>(
            f_atoms, f_bonds, Wi_atom, Wi_bond, Wh0, Wh1, W_lr,
            msgA1, msgA2, a2b, b2a, b2revb, aggL);
    }

    // pack GRU weights (into regions dead after the MP phase)
    {
        dim3 g((270000 + 255) / 256, 4);
        k_pack4<<<g, 256, 0, stream>>>(gWih_f, gWhh_f, gWih_b, gWhh_b,
                                       P0, P1, P2, P3);
    }

    // h0 + in-place relu(aggL + bias)
    prep_kernel<<<NMOL, 256, 0, stream>>>(aggLp, gru_bias, h0p);

    // persistent GRU v3: 256 1D blocks x 320 threads, XCD-partitioned by dir
    k_gru_all<<<256, 320, 0, stream>>>(
        aggLp + H, P0, P1, gbih_f, gbhh_f, P2, P3, gbih_b, gbhh_b,
        h0p, outfp, outbp);

    // hid = relu([outf|outb]@W_o + b_o)
    {
        dim3 grid((NMOL * ASZ + 63) / 64, (H + 63) / 64);
        dim3 block(16, 16);
        gemm_wo<<<grid, block, 0, stream>>>(outfp, outbp, W_o, hidp, b_o);
    }

    // per-mol mean -> d_out (overwrites the weight-pack scratch)
    mean_kernel<<<NMOL, 256, 0, stream>>>(hidp, (float*)d_out);
}

// Round 7
// 7807.131 us; speedup vs baseline: 1.4802x; 1.4802x over previous
//
#include <hip/hip_runtime.h>
#include <math.h>

constexpr int A_TOT  = 40001;
constexpr int NB     = 6;
constexpr int BN_TOT = 160001;
constexpr int AF     = 133;
constexpr int BF     = 147;
constexpr int H      = 300;
constexpr int NMOL   = 1000;
constexpr int ASZ    = 40;

// Packed-weight layout: P[(k4*300+f)*4+j] = W[(k4*4+j)*300+f], zero-padded.
// Packs live in d_out scratch (dead until mean_kernel).
constexpr int PK_WH0 = 0;
constexpr int PK_WH1 = 90000;
constexpr int PK_WIB = 180000;
constexpr int PK_WIA = 224400;

// ---------------------------------------------------------------------------
// Raw GEMV core (W_lr and PATH B).
// ---------------------------------------------------------------------------
template<int NR, int P>
__device__ __forceinline__ void gemv4(const float (*rows)[P], const float* __restrict__ W,
                                      int K, int f, float* __restrict__ acc)
{
    int k4 = 0;
    for (; k4 + 4 <= K; k4 += 4) {
        float w0 = W[(k4 + 0) * H + f];
        float w1 = W[(k4 + 1) * H + f];
        float w2 = W[(k4 + 2) * H + f];
        float w3 = W[(k4 + 3) * H + f];
#pragma unroll
        for (int i = 0; i < NR; ++i) {
            float4 b = *(const float4*)&rows[i][k4];
            acc[i] = fmaf(b.x, w0, fmaf(b.y, w1, fmaf(b.z, w2, fmaf(b.w, w3, acc[i]))));
        }
    }
    for (; k4 < K; ++k4) {
        float wv = W[k4 * H + f];
#pragma unroll
        for (int i = 0; i < NR; ++i) acc[i] = fmaf(rows[i][k4], wv, acc[i]);
    }
}

// ---------------------------------------------------------------------------
// Packed GEMV core: one float4 weight load per k4. Rows zero-padded in LDS.
// k4i loop MUST stay rolled: with compile-time K4 (37) the compiler fully
// unrolls and hoists all weight loads -> ~148 VGPR demand -> 128-cap spill
// (R5/R6: msga1 WRITE 6.3 GB of scratch traffic, invariant under NR).
// ---------------------------------------------------------------------------
template<int NR, int P>
__device__ __forceinline__ void gemv4p(const float (*rows)[P], const float4* __restrict__ Pw,
                                       int K4, int f, float* __restrict__ acc)
{
#pragma clang loop unroll(disable)
    for (int k4i = 0; k4i < K4; ++k4i) {
        float4 w = Pw[k4i * 300 + f];
#pragma unroll
        for (int i = 0; i < NR; ++i) {
            float4 b = *(const float4*)&rows[i][k4i * 4];
            acc[i] = fmaf(b.x, w.x, fmaf(b.y, w.y, fmaf(b.z, w.z, fmaf(b.w, w.w, acc[i]))));
        }
    }
}

// ===========================================================================
// Pack Wh0/Wh1/Wi_bond/Wi_atom into d_out scratch.
// ===========================================================================
__global__ __launch_bounds__(256) void k_packmp(
    const float* __restrict__ s0, const float* __restrict__ s1,
    const float* __restrict__ s2, const float* __restrict__ s3,
    float* __restrict__ dout)
{
    const float* S[4] = {s0, s1, s2, s3};
    const int Ks[4]  = {300, 300, 147, 133};
    const int K4s[4] = {75, 75, 37, 34};
    const int off[4] = {PK_WH0, PK_WH1, PK_WIB, PK_WIA};
    int z = blockIdx.y;
    int o = blockIdx.x * 256 + threadIdx.x;
    int n = K4s[z] * 1200;
    if (o < n) {
        int k4 = o / 1200; int rem = o - k4 * 1200;
        int f = rem >> 2;  int j = rem & 3;
        int k = k4 * 4 + j;
        dout[off[z] + o] = (k < Ks[z]) ? S[z][(size_t)k * 300 + f] : 0.f;
    }
}

// ===========================================================================
// K1: msgA1[a,:] = relu(f_atoms[a]@Wi_atom) + sum*max of x_b.
// Chunked bond GEMV (NR=6) + rolled k4i loop (see gemv4p note).
// ===========================================================================
#define GA 4
__global__ __launch_bounds__(320) void k_msga1(
    const float* __restrict__ f_atoms, const float* __restrict__ f_bonds,
    const float4* __restrict__ PWia, const float4* __restrict__ PWib,
    const int* __restrict__ a2b, float* __restrict__ msgA1)
{
    __shared__ __align__(16) float fb[GA * NB][152];
    __shared__ __align__(16) float fa[GA][136];
    __shared__ int bidx[GA * NB];

    const int a0 = blockIdx.x * GA;
    const int tid = threadIdx.x;
    const int f = tid;

    if (tid < GA * NB) {
        int a = a0 + tid / NB;
        bidx[tid] = (a < A_TOT) ? a2b[a * NB + (tid % NB)] : 0;
    }
    __syncthreads();
    for (int idx = tid; idx < GA * NB * 148; idx += 320) {
        int i = idx / 148, k = idx - i * 148;
        fb[i][k] = (k < BF) ? f_bonds[(size_t)bidx[i] * BF + k] : 0.f;
    }
    for (int idx = tid; idx < GA * 136; idx += 320) {
        int l = idx / 136, k = idx - l * 136;
        int a = a0 + l;
        fa[l][k] = (a < A_TOT && k < AF) ? f_atoms[(size_t)a * AF + k] : 0.f;
    }
    __syncthreads();

    if (f < H) {
        float part[GA];
#pragma unroll
        for (int l = 0; l < GA; ++l) {
            float acc[NB];
#pragma unroll
            for (int j = 0; j < NB; ++j) acc[j] = 0.f;
            gemv4p<NB, 152>((const float (*)[152])&fb[l * NB], PWib, 37, f, acc);
            float s = 0.f, mx = -INFINITY;
#pragma unroll
            for (int j = 0; j < NB; ++j) {
                float x = fmaxf(acc[j], 0.f);
                s += x; mx = fmaxf(mx, x);
            }
            part[l] = s * mx;
        }
        float acc2[GA];
#pragma unroll
        for (int l = 0; l < GA; ++l) acc2[l] = 0.f;
        gemv4p<GA, 136>(fa, PWia, 34, f, acc2);
#pragma unroll
        for (int l = 0; l < GA; ++l) {
            int a = a0 + l;
            if (a < A_TOT) msgA1[(size_t)a * H + f] = fmaxf(acc2[l], 0.f) + part[l];
        }
    }
}

// ===========================================================================
// PATH A: m1 fp32 materialization.  NR2=8, rolled gemv loops.
// ===========================================================================
#define NR2 8
__global__ __launch_bounds__(320) void k_m1f(
    const float* __restrict__ f_bonds, const float4* __restrict__ PWib,
    const float4* __restrict__ PWh0, const float* __restrict__ msgA1,
    const int* __restrict__ b2a, const int* __restrict__ b2revb,
    float* __restrict__ m1)
{
    __shared__ __align__(16) float v[NR2][304];
    __shared__ __align__(16) float fbl[NR2][152];
    __shared__ int r_[NR2], q_[NR2], p_[NR2];

    const int r0 = blockIdx.x * NR2;
    const int tid = threadIdx.x;
    const int f = tid;

    if (tid < NR2) {
        int r = r0 + tid;
        if (r >= BN_TOT) r = 0;
        r_[tid] = r;
        q_[tid] = b2revb[r];
        p_[tid] = b2a[r];
    }
    __syncthreads();
    for (int idx = tid; idx < NR2 * 75; idx += 320) {
        int i = idx / 75, k4 = idx - i * 75;
        ((float4*)v[i])[k4] = ((const float4*)(msgA1 + (size_t)p_[i] * H))[k4];
    }
    for (int idx = tid; idx < NR2 * 148; idx += 320) {
        int i = idx / 148, k = idx - i * 148;
        fbl[i][k] = (k < BF) ? f_bonds[(size_t)q_[i] * BF + k] : 0.f;
    }
    __syncthreads();
    if (f < H) {
        float acc[NR2];
#pragma unroll
        for (int i = 0; i < NR2; ++i) acc[i] = 0.f;
        gemv4p<NR2, 152>(fbl, PWib, 37, f, acc);
#pragma unroll
        for (int i = 0; i < NR2; ++i) v[i][f] -= fmaxf(acc[i], 0.f);
    }
    __syncthreads();
    for (int idx = tid; idx < NR2 * 148; idx += 320) {
        int i = idx / 148, k = idx - i * 148;
        fbl[i][k] = (k < BF) ? f_bonds[(size_t)r_[i] * BF + k] : 0.f;
    }
    float accm[NR2];
#pragma unroll
    for (int i = 0; i < NR2; ++i) accm[i] = 0.f;
    if (f < H) gemv4p<NR2, 304>(v, PWh0, 75, f, accm);
    __syncthreads();
    if (f < H) {
        float accr[NR2];
#pragma unroll
        for (int i = 0; i < NR2; ++i) accr[i] = 0.f;
        gemv4p<NR2, 152>(fbl, PWib, 37, f, accr);
#pragma unroll
        for (int i = 0; i < NR2; ++i) {
            int r = r0 + i;
            if (r < BN_TOT)
                m1[(size_t)r * H + f] = fmaxf(fmaxf(accr[i], 0.f) + accm[i], 0.f);
        }
    }
}

__global__ __launch_bounds__(256) void k_msga2ef(
    const float* __restrict__ m1, const int* __restrict__ a2b, float* msgA)
{
    int idx = blockIdx.x * 256 + threadIdx.x;
    if (idx >= A_TOT * H) return;
    int a = idx / H;
    int f = idx - a * H;
    float s = 0.f, mx = -INFINITY;
#pragma unroll
    for (int j = 0; j < NB; ++j) {
        int r = a2b[a * NB + j];
        float v = m1[(size_t)r * H + f];
        s += v;
        mx = fmaxf(mx, v);
    }
    msgA[idx] += s * mx;
}

// GC=1: LDS ~15.2 KB -> 6 blocks/CU (wave-capped), 40001 blocks.
#define GC 1
#define RC (GC * NB)   // 6
__global__ __launch_bounds__(320) void k_aggl2f(
    const float* __restrict__ f_atoms, const float* __restrict__ f_bonds,
    const float4* __restrict__ PWia, const float4* __restrict__ PWib,
    const float4* __restrict__ PWh1, const float* __restrict__ W_lr,
    const float* __restrict__ msgA2, const float* __restrict__ m1,
    const int* __restrict__ a2b, const int* __restrict__ b2a,
    const int* __restrict__ b2revb, float* __restrict__ aggL)
{
    __shared__ __align__(16) float w[RC][304];
    __shared__ __align__(16) float fbl[RC][152];
    __shared__ __align__(16) float agg3r[GC][304];
    __shared__ __align__(16) float mA2r[GC][304];
    __shared__ __align__(16) float inAr[GC][304];
    __shared__ __align__(16) float fa[GC][136];
    __shared__ int b_[RC], rp_[RC], p2_[RC];

    const int a0 = blockIdx.x * GC;
    const int tid = threadIdx.x;
    const int f = tid;

    if (tid < RC) {
        int a = a0 + tid / NB;
        int b = (a < A_TOT) ? a2b[a * NB + (tid % NB)] : 0;
        b_[tid] = b;
        rp_[tid] = b2revb[b];
        p2_[tid] = b2a[b];
    }
    __syncthreads();
    for (int idx = tid; idx < RC * 75; idx += 320) {
        int i = idx / 75, k4 = idx - i * 75;
        float4 a4 = ((const float4*)(msgA2 + (size_t)p2_[i] * H))[k4];
        float4 b4 = ((const float4*)(m1 + (size_t)rp_[i] * H))[k4];
        ((float4*)w[i])[k4] = make_float4(a4.x - b4.x, a4.y - b4.y, a4.z - b4.z, a4.w - b4.w);
    }
    for (int idx = tid; idx < RC * 148; idx += 320) {
        int i = idx / 148, k = idx - i * 148;
        fbl[i][k] = (k < BF) ? f_bonds[(size_t)b_[i] * BF + k] : 0.f;
    }
    for (int idx = tid; idx < GC * 75; idx += 320) {
        int l = idx / 75, k4 = idx - l * 75;
        int a = a0 + l;
        ((float4*)mA2r[l])[k4] = (a < A_TOT) ? ((const float4*)(msgA2 + (size_t)a * H))[k4]
                                             : make_float4(0.f, 0.f, 0.f, 0.f);
    }
    for (int idx = tid; idx < GC * 136; idx += 320) {
        int l = idx / 136, k = idx - l * 136;
        int a = a0 + l;
        fa[l][k] = (a < A_TOT && k < AF) ? f_atoms[(size_t)a * AF + k] : 0.f;
    }
    __syncthreads();

    if (f < H) {
        float accm[RC], accb[RC];
#pragma unroll
        for (int i = 0; i < RC; ++i) { accm[i] = 0.f; accb[i] = 0.f; }
        gemv4p<RC, 304>(w, PWh1, 75, f, accm);
        gemv4p<RC, 152>(fbl, PWib, 37, f, accb);
#pragma unroll
        for (int l = 0; l < GC; ++l) {
            float s = 0.f, mx = -INFINITY;
#pragma unroll
            for (int j = 0; j < NB; ++j) {
                int i = l * NB + j;
                float m2 = fmaxf(fmaxf(accb[i], 0.f) + accm[i], 0.f);
                s += m2; mx = fmaxf(mx, m2);
            }
            agg3r[l][f] = s * mx;
        }
        float acc2[GC];
#pragma unroll
        for (int l = 0; l < GC; ++l) acc2[l] = 0.f;
        gemv4p<GC, 136>(fa, PWia, 34, f, acc2);
#pragma unroll
        for (int l = 0; l < GC; ++l) inAr[l][f] = fmaxf(acc2[l], 0.f);
    }
    __syncthreads();

    if (f < H) {
        float accL[GC];
#pragma unroll
        for (int l = 0; l < GC; ++l) accL[l] = 0.f;
        gemv4<GC, 304>(agg3r, W_lr,            H, f, accL);
        gemv4<GC, 304>(mA2r, W_lr + 300 * 300, H, f, accL);
        gemv4<GC, 304>(inAr, W_lr + 600 * 300, H, f, accL);
#pragma unroll
        for (int l = 0; l < GC; ++l) {
            int a = a0 + l;
            if (a < A_TOT) aggL[(size_t)a * H + f] = accL[l];
        }
    }
}

// ===========================================================================
// PATH B kernels (not exercised when bigws) — unchanged.
// ===========================================================================
#define GB 4
#define RB (GB * NB)   // 24
__global__ __launch_bounds__(320) void k_msga2b(
    const float* __restrict__ f_bonds, const float* __restrict__ Wi_bond,
    const float* __restrict__ Wh0,
    const float* __restrict__ msgA1, float* __restrict__ msgA2,
    const int* __restrict__ a2b, const int* __restrict__ b2a,
    const int* __restrict__ b2revb)
{
    __shared__ __align__(16) float v[RB][304];
    __shared__ __align__(16) float fbl[RB][152];
    __shared__ int r_[RB], q_[RB], p_[RB];

    const int a0 = blockIdx.x * GB;
    const int tid = threadIdx.x;
    const int f = tid;

    if (tid < RB) {
        int a = a0 + tid / NB;
        int r = (a < A_TOT) ? a2b[a * NB + (tid % NB)] : 0;
        r_[tid] = r;
        q_[tid] = b2revb[r];
        p_[tid] = b2a[r];
    }
    __syncthreads();
    for (int idx = tid; idx < RB * 75; idx += 320) {
        int i = idx / 75, k4 = idx - i * 75;
        ((float4*)v[i])[k4] = ((const float4*)(msgA1 + (size_t)p_[i] * H))[k4];
    }
    for (int idx = tid; idx < RB * BF; idx += 320) {
        int i = idx / BF, k = idx - i * BF;
        fbl[i][k] = f_bonds[(size_t)q_[i] * BF + k];
    }
    __syncthreads();
    if (f < H) {
        float acc[RB];
#pragma unroll
        for (int i = 0; i < RB; ++i) acc[i] = 0.f;
        gemv4<RB, 152>(fbl, Wi_bond, BF, f, acc);
#pragma unroll
        for (int i = 0; i < RB; ++i) v[i][f] -= fmaxf(acc[i], 0.f);
    }
    __syncthreads();
    for (int idx = tid; idx < RB * BF; idx += 320) {
        int i = idx / BF, k = idx - i * BF;
        fbl[i][k] = f_bonds[(size_t)r_[i] * BF + k];
    }
    float accm[RB];
#pragma unroll
    for (int i = 0; i < RB; ++i) accm[i] = 0.f;
    if (f < H) gemv4<RB, 304>(v, Wh0, H, f, accm);
    __syncthreads();
    if (f < H) {
        float accr[RB];
#pragma unroll
        for (int i = 0; i < RB; ++i) accr[i] = 0.f;
        gemv4<RB, 152>(fbl, Wi_bond, BF, f, accr);
#pragma unroll
        for (int l = 0; l < GB; ++l) {
            float s = 0.f, mx = -INFINITY;
#pragma unroll
            for (int j = 0; j < NB; ++j) {
                int i = l * NB + j;
                float m1 = fmaxf(fmaxf(accr[i], 0.f) + accm[i], 0.f);
                s += m1; mx = fmaxf(mx, m1);
            }
            int a = a0 + l;
            if (a < A_TOT)
                msgA2[(size_t)a * H + f] = msgA1[(size_t)a * H + f] + s * mx;
        }
    }
}

#define GCB 2
#define RCB (GCB * NB)   // 12
__global__ __launch_bounds__(320) void k_agglb(
    const float* __restrict__ f_atoms, const float* __restrict__ f_bonds,
    const float* __restrict__ Wi_atom, const float* __restrict__ Wi_bond,
    const float* __restrict__ Wh0, const float* __restrict__ Wh1,
    const float* __restrict__ W_lr,
    const float* __restrict__ msgA1, const float* __restrict__ msgA2,
    const int* __restrict__ a2b, const int* __restrict__ b2a,
    const int* __restrict__ b2revb, float* __restrict__ aggL)
{
    __shared__ __align__(16) float u[RCB][304];
    __shared__ __align__(16) float w[RCB][304];
    __shared__ __align__(16) float fbl[RCB][152];
    __shared__ __align__(16) float agg3r[GCB][304];
    __shared__ __align__(16) float mA2r[GCB][304];
    __shared__ __align__(16) float inAr[GCB][304];
    __shared__ __align__(16) float fa[GCB][136];
    __shared__ int b_[RCB], rp_[RCB], p1_[RCB], q1_[RCB], p2_[RCB];

    const int a0 = blockIdx.x * GCB;
    const int tid = threadIdx.x;
    const int f = tid;

    if (tid < RCB) {
        int a = a0 + tid / NB;
        int b = (a < A_TOT) ? a2b[a * NB + (tid % NB)] : 0;
        int rp = b2revb[b];
        b_[tid] = b; rp_[tid] = rp;
        p1_[tid] = b2a[rp]; q1_[tid] = b2revb[rp]; p2_[tid] = b2a[b];
    }
    __syncthreads();
    for (int idx = tid; idx < RCB * 75; idx += 320) {
        int i = idx / 75, k4 = idx - i * 75;
        ((float4*)u[i])[k4] = ((const float4*)(msgA1 + (size_t)p1_[i] * H))[k4];
        ((float4*)w[i])[k4] = ((const float4*)(msgA2 + (size_t)p2_[i] * H))[k4];
    }
    for (int idx = tid; idx < RCB * BF; idx += 320) {
        int i = idx / BF, k = idx - i * BF;
        fbl[i][k] = f_bonds[(size_t)q1_[i] * BF + k];
    }
    for (int idx = tid; idx < GCB * 75; idx += 320) {
        int l = idx / 75, k4 = idx - l * 75;
        int a = a0 + l;
        ((float4*)mA2r[l])[k4] = (a < A_TOT) ? ((const float4*)(msgA2 + (size_t)a * H))[k4]
                                             : make_float4(0.f, 0.f, 0.f, 0.f);
    }
    for (int idx = tid; idx < GCB * AF; idx += 320) {
        int l = idx / AF, k = idx - l * AF;
        int a = a0 + l;
        fa[l][k] = (a < A_TOT) ? f_atoms[(size_t)a * AF + k] : 0.f;
    }
    __syncthreads();
    if (f < H) {
        float acc[RCB];
#pragma unroll
        for (int i = 0; i < RCB; ++i) acc[i] = 0.f;
        gemv4<RCB, 152>(fbl, Wi_bond, BF, f, acc);
#pragma unroll
        for (int i = 0; i < RCB; ++i) u[i][f] -= fmaxf(acc[i], 0.f);
    }
    __syncthreads();
    for (int idx = tid; idx < RCB * BF; idx += 320) {
        int i = idx / BF, k = idx - i * BF;
        fbl[i][k] = f_bonds[(size_t)rp_[i] * BF + k];
    }
    __syncthreads();
    if (f < H) {
        float accm[RCB], accr[RCB];
#pragma unroll
        for (int i = 0; i < RCB; ++i) { accm[i] = 0.f; accr[i] = 0.f; }
        gemv4<RCB, 304>(u, Wh0, H, f, accm);
        gemv4<RCB, 152>(fbl, Wi_bond, BF, f, accr);
#pragma unroll
        for (int i = 0; i < RCB; ++i)
            w[i][f] -= fmaxf(fmaxf(accr[i], 0.f) + accm[i], 0.f);
    }
    __syncthreads();
    for (int idx = tid; idx < RCB * BF; idx += 320) {
        int i = idx / BF, k = idx - i * BF;
        fbl[i][k] = f_bonds[(size_t)b_[i] * BF + k];
    }
    __syncthreads();
    if (f < H) {
        float accm[RCB], accb[RCB];
#pragma unroll
        for (int i = 0; i < RCB; ++i) { accm[i] = 0.f; accb[i] = 0.f; }
        gemv4<RCB, 304>(w, Wh1, H, f, accm);
        gemv4<RCB, 152>(fbl, Wi_bond, BF, f, accb);
#pragma unroll
        for (int l = 0; l < GCB; ++l) {
            float s = 0.f, mx = -INFINITY;
#pragma unroll
            for (int j = 0; j < NB; ++j) {
                int i = l * NB + j;
                float m2 = fmaxf(fmaxf(accb[i], 0.f) + accm[i], 0.f);
                s += m2; mx = fmaxf(mx, m2);
            }
            agg3r[l][f] = s * mx;
        }
        float acc2[GCB];
#pragma unroll
        for (int l = 0; l < GCB; ++l) acc2[l] = 0.f;
        gemv4<GCB, 136>(fa, Wi_atom, AF, f, acc2);
#pragma unroll
        for (int l = 0; l < GCB; ++l) inAr[l][f] = fmaxf(acc2[l], 0.f);
    }
    __syncthreads();
    if (f < H) {
        float accL[GCB];
#pragma unroll
        for (int l = 0; l < GCB; ++l) accL[l] = 0.f;
        gemv4<GCB, 304>(agg3r, W_lr,            H, f, accL);
        gemv4<GCB, 304>(mA2r, W_lr + 300 * 300, H, f, accL);
        gemv4<GCB, 304>(inAr, W_lr + 600 * 300, H, f, accL);
#pragma unroll
        for (int l = 0; l < GCB; ++l) {
            int a = a0 + l;
            if (a < A_TOT) aggL[(size_t)a * H + f] = accL[l];
        }
    }
}

// ===========================================================================
// Pack 4 [900,300] GRU weight mats -> P[k/4][gate][f][k%4]  (270000 each)
// ===========================================================================
__global__ __launch_bounds__(256) void k_pack4(
    const float* __restrict__ s0, const float* __restrict__ s1,
    const float* __restrict__ s2, const float* __restrict__ s3,
    float* __restrict__ d0, float* __restrict__ d1,
    float* __restrict__ d2, float* __restrict__ d3)
{
    const float* S[4] = {s0, s1, s2, s3};
    float* D[4] = {d0, d1, d2, d3};
    int z = blockIdx.y;
    int o = blockIdx.x * 256 + threadIdx.x;
    if (o < 270000) {
        int k4 = o / 3600; int rem = o - k4 * 3600;
        int g = rem / 1200; int rem2 = rem - g * 1200;
        int fx = rem2 >> 2; int kk = rem2 & 3;
        int k = k4 * 4 + kk;
        D[z][o] = S[z][(size_t)(g * 300 + fx) * 300 + k];
    }
}

// ===========================================================================
// prep: h0[m] = max_t aggL[1+m*40+t]; then aggL row <- relu(row + gru_bias)
// ===========================================================================
__global__ __launch_bounds__(256) void prep_kernel(
    float* aggL, const float* __restrict__ gru_bias, float* __restrict__ h0)
{
    int m = blockIdx.x;
    for (int f = threadIdx.x; f < H; f += 256) {
        float b = gru_bias[f];
        float mx = -INFINITY;
        for (int t = 0; t < ASZ; ++t) {
            size_t o = (size_t)(1 + m * ASZ + t) * H + f;
            float v = aggL[o];
            mx = fmaxf(mx, v);
            aggL[o] = fmaxf(v + b, 0.f);
        }
        h0[(size_t)m * H + f] = mx;
    }
}

__device__ __forceinline__ float dev_sigmoid(float x) {
    return 1.f / (1.f + __expf(-x));
}
__device__ __forceinline__ float dev_tanh(float x) {
    return 1.f - 2.f / (__expf(2.f * x) + 1.f);
}

// ===========================================================================
// Persistent GRU, v3 (R3-verified).
// ===========================================================================
#define GM 8
__global__ __launch_bounds__(320) void k_gru_all(
    const float* __restrict__ msg,
    const float* __restrict__ Pih_f, const float* __restrict__ Phh_f,
    const float* __restrict__ bih_f, const float* __restrict__ bhh_f,
    const float* __restrict__ Pih_b, const float* __restrict__ Phh_b,
    const float* __restrict__ bih_b, const float* __restrict__ bhh_b,
    const float* __restrict__ h0, float* __restrict__ out_f,
    float* __restrict__ out_b)
{
    __shared__ __align__(16) float hs[GM][304];
    __shared__ __align__(16) float ms[2][GM][304];

    const int bid  = blockIdx.x;
    const int xcd  = bid & 7;
    const int slot = bid >> 3;
    const int dir  = xcd >> 2;
    const int lg   = (xcd & 3) * 32 + slot;
    const int m0   = lg * GM;
    if (m0 >= NMOL) return;

    const float* Pih = dir ? Pih_b : Pih_f;
    const float* Phh = dir ? Phh_b : Phh_f;
    const float* bih = dir ? bih_b : bih_f;
    const float* bhh = dir ? bhh_b : bhh_f;
    float* out       = dir ? out_b : out_f;

    const int tid  = threadIdx.x;
    const bool act = tid < H;
    const int f    = act ? tid : (H - 1);

    for (int idx = tid; idx < GM * 75; idx += 320) {
        int i = idx / 75, k4 = idx - i * 75;
        int m = m0 + i;
        ((float4*)hs[i])[k4] = (m < NMOL) ? ((const float4*)(h0 + (size_t)m * H))[k4]
                                          : make_float4(0.f, 0.f, 0.f, 0.f);
    }
    {
        const int t0 = dir ? (ASZ - 1) : 0;
        for (int idx = tid; idx < GM * 75; idx += 320) {
            int i = idx / 75, k4 = idx - i * 75;
            int m = m0 + i;
            ((float4*)ms[0][i])[k4] = (m < NMOL)
                ? ((const float4*)(msg + (size_t)(m * ASZ + t0) * H))[k4]
                : make_float4(0.f, 0.f, 0.f, 0.f);
        }
    }

    float bR = 0.f, bZ = 0.f, bIN = 0.f, bHN = 0.f;
    if (act) {
        bR  = bih[f] + bhh[f];
        bZ  = bih[300 + f] + bhh[300 + f];
        bIN = bih[600 + f];
        bHN = bhh[600 + f];
    }
    const float* pi = Pih + (size_t)f * 4;
    const float* ph = Phh + (size_t)f * 4;

    for (int s = 0; s < ASZ; ++s) {
        const int cur = s & 1;
        const int t = dir ? (ASZ - 1 - s) : s;
        __syncthreads();

        float4 st0 = make_float4(0.f, 0.f, 0.f, 0.f);
        float4 st1 = make_float4(0.f, 0.f, 0.f, 0.f);
        const bool more = (s + 1 < ASZ);
        if (more) {
            const int tn = dir ? (ASZ - 2 - s) : (s + 1);
            {
                int i = tid / 75, k4 = tid - i * 75;
                int m = m0 + i;
                if (m < NMOL)
                    st0 = ((const float4*)(msg + (size_t)(m * ASZ + tn) * H))[k4];
            }
            {
                int idx = tid + 320;
                if (idx < GM * 75) {
                    int i = idx / 75, k4 = idx - i * 75;
                    int m = m0 + i;
                    if (m < NMOL)
                        st1 = ((const float4*)(msg + (size_t)(m * ASZ + tn) * H))[k4];
                }
            }
        }

        float aR[GM], aZ[GM], aIN[GM], aHN[GM];
#pragma unroll
        for (int i = 0; i < GM; ++i) { aR[i] = 0.f; aZ[i] = 0.f; aIN[i] = 0.f; aHN[i] = 0.f; }

        float4 wiR = *(const float4*)(pi);
        float4 wiZ = *(const float4*)(pi + 1200);
        float4 wiN = *(const float4*)(pi + 2400);
        float4 whR = *(const float4*)(ph);
        float4 whZ = *(const float4*)(ph + 1200);
        float4 whN = *(const float4*)(ph + 2400);

        for (int k4i = 0; k4i < 75; ++k4i) {
            const int kn = k4i + (k4i < 74 ? 1 : 0);
            const float* pin = pi + (size_t)kn * 3600;
            const float* phn = ph + (size_t)kn * 3600;
            float4 nR = *(const float4*)(pin);
            float4 nZ = *(const float4*)(pin + 1200);
            float4 nN = *(const float4*)(pin + 2400);
            float4 oR = *(const float4*)(phn);
            float4 oZ = *(const float4*)(phn + 1200);
            float4 oN = *(const float4*)(phn + 2400);

            const int k4 = k4i * 4;
#pragma unroll
            for (int i = 0; i < GM; ++i) {
                float4 m4 = *(const float4*)&ms[cur][i][k4];
                float4 h4 = *(const float4*)&hs[i][k4];
                aR[i]  = fmaf(m4.x, wiR.x, fmaf(m4.y, wiR.y, fmaf(m4.z, wiR.z, fmaf(m4.w, wiR.w, aR[i]))));
                aR[i]  = fmaf(h4.x, whR.x, fmaf(h4.y, whR.y, fmaf(h4.z, whR.z, fmaf(h4.w, whR.w, aR[i]))));
                aZ[i]  = fmaf(m4.x, wiZ.x, fmaf(m4.y, wiZ.y, fmaf(m4.z, wiZ.z, fmaf(m4.w, wiZ.w, aZ[i]))));
                aZ[i]  = fmaf(h4.x, whZ.x, fmaf(h4.y, whZ.y, fmaf(h4.z, whZ.z, fmaf(h4.w, whZ.w, aZ[i]))));
                aIN[i] = fmaf(m4.x, wiN.x, fmaf(m4.y, wiN.y, fmaf(m4.z, wiN.z, fmaf(m4.w, wiN.w, aIN[i]))));
                aHN[i] = fmaf(h4.x, whN.x, fmaf(h4.y, whN.y, fmaf(h4.z, whN.z, fmaf(h4.w, whN.w, aHN[i]))));
            }
            wiR = nR; wiZ = nZ; wiN = nN;
            whR = oR; whZ = oZ; whN = oN;
        }
        __syncthreads();

        if (act) {
#pragma unroll
            for (int i = 0; i < GM; ++i) {
                int m = m0 + i;
                if (m < NMOL) {
                    float r = dev_sigmoid(aR[i] + bR);
                    float z = dev_sigmoid(aZ[i] + bZ);
                    float n = dev_tanh(aIN[i] + bIN + r * (aHN[i] + bHN));
                    float hn = (1.f - z) * n + z * hs[i][f];
                    hs[i][f] = hn;
                    __builtin_nontemporal_store(hn, out + (size_t)(m * ASZ + t) * H + f);
                }
            }
        }
        if (more) {
            const int nxt = cur ^ 1;
            {
                int i = tid / 75, k4 = tid - i * 75;
                ((float4*)ms[nxt][i])[k4] = st0;
            }
            {
                int idx = tid + 320;
                if (idx < GM * 75) {
                    int i = idx / 75, k4 = idx - i * 75;
                    ((float4*)ms[nxt][i])[k4] = st1;
                }
            }
        }
    }
}

// ===========================================================================
// Fused output projection: hid = relu([outf|outb] @ W_o + b_o), K=600.
// ===========================================================================
__global__ __launch_bounds__(256) void gemm_wo(
    const float* __restrict__ A0, const float* __restrict__ A1,
    const float* __restrict__ W, float* __restrict__ C,
    const float* __restrict__ bias)
{
    const int M = NMOL * ASZ, K2 = 600, N = H;
    __shared__ float As[16][64];
    __shared__ float Bs[16][64];
    const int tx = threadIdx.x, ty = threadIdx.y;
    const int tid = ty * 16 + tx;
    const int m0 = blockIdx.x * 64, n0 = blockIdx.y * 64;
    const int am = tid >> 2, ak = (tid & 3) * 4;
    const int bk = tid >> 4, bn = (tid & 15) * 4;
    const int arow = m0 + am;

    float acc[4][4];
#pragma unroll
    for (int i = 0; i < 4; ++i)
#pragma unroll
        for (int j = 0; j < 4; ++j) acc[i][j] = 0.f;

    for (int k0 = 0; k0 < K2; k0 += 16) {
#pragma unroll
        for (int j = 0; j < 4; ++j) {
            int k = k0 + ak + j;
            float v = 0.f;
            if (arow < M && k < K2)
                v = (k < 300) ? A0[(size_t)arow * 300 + k]
                              : A1[(size_t)arow * 300 + (k - 300)];
            As[ak + j][am] = v;
        }
#pragma unroll
        for (int j = 0; j < 4; ++j) {
            int k = k0 + bk, n = n0 + bn + j;
            Bs[bk][bn + j] = (k < K2 && n < N) ? W[(size_t)k * N + n] : 0.f;
        }
        __syncthreads();
#pragma unroll
        for (int kk = 0; kk < 16; ++kk) {
            float4 av = *(const float4*)&As[kk][ty * 4];
            float4 bv = *(const float4*)&Bs[kk][tx * 4];
            float a4[4] = {av.x, av.y, av.z, av.w};
            float b4[4] = {bv.x, bv.y, bv.z, bv.w};
#pragma unroll
            for (int i = 0; i < 4; ++i)
#pragma unroll
                for (int j = 0; j < 4; ++j)
                    acc[i][j] = fmaf(a4[i], b4[j], acc[i][j]);
        }
        __syncthreads();
    }
#pragma unroll
    for (int i = 0; i < 4; ++i) {
        int m = m0 + ty * 4 + i;
        if (m >= M) continue;
#pragma unroll
        for (int j = 0; j < 4; ++j) {
            int n = n0 + tx * 4 + j;
            if (n >= N) continue;
            C[(size_t)m * N + n] = fmaxf(acc[i][j] + bias[n], 0.f);
        }
    }
}

__global__ __launch_bounds__(256) void mean_kernel(
    const float* __restrict__ hid, float* __restrict__ out)
{
    int m = blockIdx.x;
    for (int f = threadIdx.x; f < H; f += 256) {
        float s = 0.f;
        for (int t = 0; t < ASZ; ++t)
            s += hid[(size_t)(m * ASZ + t) * H + f];
        out[(size_t)m * H + f] = s * (1.f / 40.f);
    }
}

// ===========================================================================
extern "C" void kernel_launch(void* const* d_in, const int* in_sizes, int n_in,
                              void* d_out, int out_size, void* d_ws, size_t ws_size,
                              hipStream_t stream)
{
    const float* f_atoms  = (const float*)d_in[0];
    const float* f_bonds  = (const float*)d_in[1];
    const float* Wi_atom  = (const float*)d_in[2];
    const float* Wi_bond  = (const float*)d_in[3];
    const float* Wh0      = (const float*)d_in[4];
    const float* Wh1      = (const float*)d_in[5];
    const float* W_lr     = (const float*)d_in[6];
    const float* W_o      = (const float*)d_in[7];
    const float* b_o      = (const float*)d_in[8];
    const float* gru_bias = (const float*)d_in[9];
    const float* gWih_f   = (const float*)d_in[10];
    const float* gWhh_f   = (const float*)d_in[11];
    const float* gbih_f   = (const float*)d_in[12];
    const float* gbhh_f   = (const float*)d_in[13];
    const float* gWih_b   = (const float*)d_in[14];
    const float* gWhh_b   = (const float*)d_in[15];
    const float* gbih_b   = (const float*)d_in[16];
    const float* gbhh_b   = (const float*)d_in[17];
    const int*   a2b      = (const int*)d_in[18];
    const int*   b2a      = (const int*)d_in[19];
    const int*   b2revb   = (const int*)d_in[20];

    char* wsb = (char*)d_ws;
    const bool bigws = (ws_size >= (size_t)288003600);

    // Pack MP weights into d_out scratch (dead until mean_kernel overwrites it)
    float* dscratch = (float*)d_out;
    {
        dim3 g((90000 + 255) / 256, 4);
        k_packmp<<<g, 256, 0, stream>>>(Wh0, Wh1, Wi_bond, Wi_atom, dscratch);
    }
    const float4* PWh0 = (const float4*)(dscratch + PK_WH0);
    const float4* PWh1 = (const float4*)(dscratch + PK_WH1);
    const float4* PWib = (const float4*)(dscratch + PK_WIB);
    const float4* PWia = (const float4*)(dscratch + PK_WIA);

    float *aggLp, *outfp, *outbp, *h0p, *P0, *P1, *P2, *P3, *hidp;

    if (bigws) {
        // PATH A: fp32 m1 materialization.  Peak = 288,003,600 B.
        float* msgA = (float*)wsb;
        float* aggL = (float*)(wsb + 48001200);
        float* m1   = (float*)(wsb + 96002400);
        outfp = (float*)(wsb + 96002400);
        outbp = (float*)(wsb + 144002400);
        P0 = (float*)(wsb + 192002400);
        P1 = P0 + 270000; P2 = P1 + 270000; P3 = P2 + 270000;
        h0p = (float*)(wsb + 196322400);
        aggLp = aggL; hidp = msgA;

        k_msga1<<<(A_TOT + GA - 1) / GA, 320, 0, stream>>>(
            f_atoms, f_bonds, PWia, PWib, a2b, msgA);
        k_m1f<<<(BN_TOT + NR2 - 1) / NR2, 320, 0, stream>>>(
            f_bonds, PWib, PWh0, msgA, b2a, b2revb, m1);
        k_msga2ef<<<(A_TOT * H + 255) / 256, 256, 0, stream>>>(m1, a2b, msgA);
        k_aggl2f<<<(A_TOT + GC - 1) / GC, 320, 0, stream>>>(
            f_atoms, f_bonds, PWia, PWib, PWh1, W_lr,
            msgA, m1, a2b, b2a, b2revb, aggL);
    } else {
        // PATH B: recompute path (no m1 buffer).  Peak = 240,003,600 B.
        float* ws = (float*)d_ws;
        float* msgA1 = ws;
        float* msgA2 = ws + 12000300;
        float* aggL  = ws + 24000600;
        outfp = ws + 36000900;
        outbp = ws + 48000900;
        h0p   = ws;
        P0 = ws + 300000; P1 = ws + 570000; P2 = ws + 840000; P3 = ws + 1110000;
        aggLp = aggL; hidp = msgA2;

        k_msga1<<<(A_TOT + GA - 1) / GA, 320, 0, stream>>>(
            f_atoms, f_bonds, PWia, PWib, a2b, msgA1);
        k_msga2b<<<(A_TOT + GB - 1) / GB, 320, 0, stream>>>(
            f_bonds, Wi_bond, Wh0, msgA1, msgA2, a2b, b2a, b2revb);
        k_agglb<<<(A_TOT + GCB - 1) / GCB, 320, 0, stream>>>(
            f_atoms, f_bonds, Wi_atom, Wi_bond, Wh0, Wh1, W_lr,
            msgA1, msgA2, a2b, b2a, b2revb, aggL);
    }

    // pack GRU weights (into regions dead after the MP phase)
    {
        dim3 g((270000 + 255) / 256, 4);
        k_pack4<<<g, 256, 0, stream>>>(gWih_f, gWhh_f, gWih_b, gWhh_b,
                                       P0, P1, P2, P3);
    }

    // h0 + in-place relu(aggL + bias)
    prep_kernel<<<NMOL, 256, 0, stream>>>(aggLp, gru_bias, h0p);

    // persistent GRU v3: 256 1D blocks x 320 threads, XCD-partitioned by dir
    k_gru_all<<<256, 320, 0, stream>>>(
        aggLp + H, P0, P1, gbih_f, gbhh_f, P2, P3, gbih_b, gbhh_b,
        h0p, outfp, outbp);

    // hid = relu([outf|outb]@W_o + b_o)
    {
        dim3 grid((NMOL * ASZ + 63) / 64, (H + 63) / 64);
        dim3 block(16, 16);
        gemm_wo<<<grid, block, 0, stream>>>(outfp, outbp, W_o, hidp, b_o);
    }

    // per-mol mean -> d_out (overwrites the weight-pack scratch)
    mean_kernel<<<NMOL, 256, 0, stream>>>(hidp, (float*)d_out);
}

// Round 8
// 7322.443 us; speedup vs baseline: 1.5782x; 1.0662x over previous
//
#include <hip/hip_runtime.h>
#include <math.h>

constexpr int A_TOT  = 40001;
constexpr int NB     = 6;
constexpr int BN_TOT = 160001;
constexpr int AF     = 133;
constexpr int BF     = 147;
constexpr int H      = 300;
constexpr int NMOL   = 1000;
constexpr int ASZ    = 40;

// Packed-weight layout: P[(k4*300+f)*4+j] = W[(k4*4+j)*300+f], zero-padded.
// Packs live in d_out scratch (dead until mean_kernel).
constexpr int PK_WH0 = 0;
constexpr int PK_WH1 = 90000;
constexpr int PK_WIB = 180000;
constexpr int PK_WIA = 224400;

// ---------------------------------------------------------------------------
// Raw GEMV core (W_lr and PATH B).
// ---------------------------------------------------------------------------
template<int NR, int P>
__device__ __forceinline__ void gemv4(const float (*rows)[P], const float* __restrict__ W,
                                      int K, int f, float* __restrict__ acc)
{
    int k4 = 0;
    for (; k4 + 4 <= K; k4 += 4) {
        float w0 = W[(k4 + 0) * H + f];
        float w1 = W[(k4 + 1) * H + f];
        float w2 = W[(k4 + 2) * H + f];
        float w3 = W[(k4 + 3) * H + f];
#pragma unroll
        for (int i = 0; i < NR; ++i) {
            float4 b = *(const float4*)&rows[i][k4];
            acc[i] = fmaf(b.x, w0, fmaf(b.y, w1, fmaf(b.z, w2, fmaf(b.w, w3, acc[i]))));
        }
    }
    for (; k4 < K; ++k4) {
        float wv = W[k4 * H + f];
#pragma unroll
        for (int i = 0; i < NR; ++i) acc[i] = fmaf(rows[i][k4], wv, acc[i]);
    }
}

// ---------------------------------------------------------------------------
// Packed GEMV core: one float4 weight load per k4. Rows zero-padded in LDS.
// k4i loop MUST stay rolled: with compile-time K4 (37) the compiler fully
// unrolls and hoists all weight loads -> ~148 VGPR demand -> 128-cap spill
// (R5/R6: msga1 WRITE 6.3 GB of scratch traffic, invariant under NR).
// AMORTIZATION RULE (R7): rows-per-weight-load dominates; prefer NR=12 over
// NR=6 once >=2 blocks/CU (R4 GC=2: 2.75 ms vs R7 GC=1: 3.5 ms).
// ---------------------------------------------------------------------------
template<int NR, int P>
__device__ __forceinline__ void gemv4p(const float (*rows)[P], const float4* __restrict__ Pw,
                                       int K4, int f, float* __restrict__ acc)
{
#pragma clang loop unroll(disable)
    for (int k4i = 0; k4i < K4; ++k4i) {
        float4 w = Pw[k4i * 300 + f];
#pragma unroll
        for (int i = 0; i < NR; ++i) {
            float4 b = *(const float4*)&rows[i][k4i * 4];
            acc[i] = fmaf(b.x, w.x, fmaf(b.y, w.y, fmaf(b.z, w.z, fmaf(b.w, w.w, acc[i]))));
        }
    }
}

// ===========================================================================
// Pack Wh0/Wh1/Wi_bond/Wi_atom into d_out scratch.
// ===========================================================================
__global__ __launch_bounds__(256) void k_packmp(
    const float* __restrict__ s0, const float* __restrict__ s1,
    const float* __restrict__ s2, const float* __restrict__ s3,
    float* __restrict__ dout)
{
    const float* S[4] = {s0, s1, s2, s3};
    const int Ks[4]  = {300, 300, 147, 133};
    const int K4s[4] = {75, 75, 37, 34};
    const int off[4] = {PK_WH0, PK_WH1, PK_WIB, PK_WIA};
    int z = blockIdx.y;
    int o = blockIdx.x * 256 + threadIdx.x;
    int n = K4s[z] * 1200;
    if (o < n) {
        int k4 = o / 1200; int rem = o - k4 * 1200;
        int f = rem >> 2;  int j = rem & 3;
        int k = k4 * 4 + j;
        dout[off[z] + o] = (k < Ks[z]) ? S[z][(size_t)k * 300 + f] : 0.f;
    }
}

// ===========================================================================
// K1: msgA1[a,:] = relu(f_atoms[a]@Wi_atom) + sum*max of x_b.
// Chunked bond GEMV (NR=6) + rolled k4i loop (see gemv4p note).
// ===========================================================================
#define GA 4
__global__ __launch_bounds__(320) void k_msga1(
    const float* __restrict__ f_atoms, const float* __restrict__ f_bonds,
    const float4* __restrict__ PWia, const float4* __restrict__ PWib,
    const int* __restrict__ a2b, float* __restrict__ msgA1)
{
    __shared__ __align__(16) float fb[GA * NB][152];
    __shared__ __align__(16) float fa[GA][136];
    __shared__ int bidx[GA * NB];

    const int a0 = blockIdx.x * GA;
    const int tid = threadIdx.x;
    const int f = tid;

    if (tid < GA * NB) {
        int a = a0 + tid / NB;
        bidx[tid] = (a < A_TOT) ? a2b[a * NB + (tid % NB)] : 0;
    }
    __syncthreads();
    for (int idx = tid; idx < GA * NB * 148; idx += 320) {
        int i = idx / 148, k = idx - i * 148;
        fb[i][k] = (k < BF) ? f_bonds[(size_t)bidx[i] * BF + k] : 0.f;
    }
    for (int idx = tid; idx < GA * 136; idx += 320) {
        int l = idx / 136, k = idx - l * 136;
        int a = a0 + l;
        fa[l][k] = (a < A_TOT && k < AF) ? f_atoms[(size_t)a * AF + k] : 0.f;
    }
    __syncthreads();

    if (f < H) {
        float part[GA];
#pragma unroll
        for (int l = 0; l < GA; ++l) {
            float acc[NB];
#pragma unroll
            for (int j = 0; j < NB; ++j) acc[j] = 0.f;
            gemv4p<NB, 152>((const float (*)[152])&fb[l * NB], PWib, 37, f, acc);
            float s = 0.f, mx = -INFINITY;
#pragma unroll
            for (int j = 0; j < NB; ++j) {
                float x = fmaxf(acc[j], 0.f);
                s += x; mx = fmaxf(mx, x);
            }
            part[l] = s * mx;
        }
        float acc2[GA];
#pragma unroll
        for (int l = 0; l < GA; ++l) acc2[l] = 0.f;
        gemv4p<GA, 136>(fa, PWia, 34, f, acc2);
#pragma unroll
        for (int l = 0; l < GA; ++l) {
            int a = a0 + l;
            if (a < A_TOT) msgA1[(size_t)a * H + f] = fmaxf(acc2[l], 0.f) + part[l];
        }
    }
}

// ===========================================================================
// PATH A: m1 fp32 materialization.  NR2=8, rolled gemv loops.
// ===========================================================================
#define NR2 8
__global__ __launch_bounds__(320) void k_m1f(
    const float* __restrict__ f_bonds, const float4* __restrict__ PWib,
    const float4* __restrict__ PWh0, const float* __restrict__ msgA1,
    const int* __restrict__ b2a, const int* __restrict__ b2revb,
    float* __restrict__ m1)
{
    __shared__ __align__(16) float v[NR2][304];
    __shared__ __align__(16) float fbl[NR2][152];
    __shared__ int r_[NR2], q_[NR2], p_[NR2];

    const int r0 = blockIdx.x * NR2;
    const int tid = threadIdx.x;
    const int f = tid;

    if (tid < NR2) {
        int r = r0 + tid;
        if (r >= BN_TOT) r = 0;
        r_[tid] = r;
        q_[tid] = b2revb[r];
        p_[tid] = b2a[r];
    }
    __syncthreads();
    for (int idx = tid; idx < NR2 * 75; idx += 320) {
        int i = idx / 75, k4 = idx - i * 75;
        ((float4*)v[i])[k4] = ((const float4*)(msgA1 + (size_t)p_[i] * H))[k4];
    }
    for (int idx = tid; idx < NR2 * 148; idx += 320) {
        int i = idx / 148, k = idx - i * 148;
        fbl[i][k] = (k < BF) ? f_bonds[(size_t)q_[i] * BF + k] : 0.f;
    }
    __syncthreads();
    if (f < H) {
        float acc[NR2];
#pragma unroll
        for (int i = 0; i < NR2; ++i) acc[i] = 0.f;
        gemv4p<NR2, 152>(fbl, PWib, 37, f, acc);
#pragma unroll
        for (int i = 0; i < NR2; ++i) v[i][f] -= fmaxf(acc[i], 0.f);
    }
    __syncthreads();
    for (int idx = tid; idx < NR2 * 148; idx += 320) {
        int i = idx / 148, k = idx - i * 148;
        fbl[i][k] = (k < BF) ? f_bonds[(size_t)r_[i] * BF + k] : 0.f;
    }
    float accm[NR2];
#pragma unroll
    for (int i = 0; i < NR2; ++i) accm[i] = 0.f;
    if (f < H) gemv4p<NR2, 304>(v, PWh0, 75, f, accm);
    __syncthreads();
    if (f < H) {
        float accr[NR2];
#pragma unroll
        for (int i = 0; i < NR2; ++i) accr[i] = 0.f;
        gemv4p<NR2, 152>(fbl, PWib, 37, f, accr);
#pragma unroll
        for (int i = 0; i < NR2; ++i) {
            int r = r0 + i;
            if (r < BN_TOT)
                m1[(size_t)r * H + f] = fmaxf(fmaxf(accr[i], 0.f) + accm[i], 0.f);
        }
    }
}

__global__ __launch_bounds__(256) void k_msga2ef(
    const float* __restrict__ m1, const int* __restrict__ a2b, float* msgA)
{
    int idx = blockIdx.x * 256 + threadIdx.x;
    if (idx >= A_TOT * H) return;
    int a = idx / H;
    int f = idx - a * H;
    float s = 0.f, mx = -INFINITY;
#pragma unroll
    for (int j = 0; j < NB; ++j) {
        int r = a2b[a * NB + j];
        float v = m1[(size_t)r * H + f];
        s += v;
        mx = fmaxf(mx, v);
    }
    msgA[idx] += s * mx;
}

// GC=2 (R7->R8 revert: R4 A/B showed GC=2 2.75ms vs GC=1 3.5ms — weight-load
// amortization beats occupancy). Rolled gemv4p keeps VGPR ~44, no spill.
#define GC 2
#define RC (GC * NB)   // 12
__global__ __launch_bounds__(320) void k_aggl2f(
    const float* __restrict__ f_atoms, const float* __restrict__ f_bonds,
    const float4* __restrict__ PWia, const float4* __restrict__ PWib,
    const float4* __restrict__ PWh1, const float* __restrict__ W_lr,
    const float* __restrict__ msgA2, const float* __restrict__ m1,
    const int* __restrict__ a2b, const int* __restrict__ b2a,
    const int* __restrict__ b2revb, float* __restrict__ aggL)
{
    __shared__ __align__(16) float w[RC][304];
    __shared__ __align__(16) float fbl[RC][152];
    __shared__ __align__(16) float agg3r[GC][304];
    __shared__ __align__(16) float mA2r[GC][304];
    __shared__ __align__(16) float inAr[GC][304];
    __shared__ __align__(16) float fa[GC][136];
    __shared__ int b_[RC], rp_[RC], p2_[RC];

    const int a0 = blockIdx.x * GC;
    const int tid = threadIdx.x;
    const int f = tid;

    if (tid < RC) {
        int a = a0 + tid / NB;
        int b = (a < A_TOT) ? a2b[a * NB + (tid % NB)] : 0;
        b_[tid] = b;
        rp_[tid] = b2revb[b];
        p2_[tid] = b2a[b];
    }
    __syncthreads();
    for (int idx = tid; idx < RC * 75; idx += 320) {
        int i = idx / 75, k4 = idx - i * 75;
        float4 a4 = ((const float4*)(msgA2 + (size_t)p2_[i] * H))[k4];
        float4 b4 = ((const float4*)(m1 + (size_t)rp_[i] * H))[k4];
        ((float4*)w[i])[k4] = make_float4(a4.x - b4.x, a4.y - b4.y, a4.z - b4.z, a4.w - b4.w);
    }
    for (int idx = tid; idx < RC * 148; idx += 320) {
        int i = idx / 148, k = idx - i * 148;
        fbl[i][k] = (k < BF) ? f_bonds[(size_t)b_[i] * BF + k] : 0.f;
    }
    for (int idx = tid; idx < GC * 75; idx += 320) {
        int l = idx / 75, k4 = idx - l * 75;
        int a = a0 + l;
        ((float4*)mA2r[l])[k4] = (a < A_TOT) ? ((const float4*)(msgA2 + (size_t)a * H))[k4]
                                             : make_float4(0.f, 0.f, 0.f, 0.f);
    }
    for (int idx = tid; idx < GC * 136; idx += 320) {
        int l = idx / 136, k = idx - l * 136;
        int a = a0 + l;
        fa[l][k] = (a < A_TOT && k < AF) ? f_atoms[(size_t)a * AF + k] : 0.f;
    }
    __syncthreads();

    if (f < H) {
        float accm[RC];
#pragma unroll
        for (int i = 0; i < RC; ++i) accm[i] = 0.f;
        gemv4p<RC, 304>(w, PWh1, 75, f, accm);
        float accb[RC];
#pragma unroll
        for (int i = 0; i < RC; ++i) accb[i] = 0.f;
        gemv4p<RC, 152>(fbl, PWib, 37, f, accb);
#pragma unroll
        for (int l = 0; l < GC; ++l) {
            float s = 0.f, mx = -INFINITY;
#pragma unroll
            for (int j = 0; j < NB; ++j) {
                int i = l * NB + j;
                float m2 = fmaxf(fmaxf(accb[i], 0.f) + accm[i], 0.f);
                s += m2; mx = fmaxf(mx, m2);
            }
            agg3r[l][f] = s * mx;
        }
        float acc2[GC];
#pragma unroll
        for (int l = 0; l < GC; ++l) acc2[l] = 0.f;
        gemv4p<GC, 136>(fa, PWia, 34, f, acc2);
#pragma unroll
        for (int l = 0; l < GC; ++l) inAr[l][f] = fmaxf(acc2[l], 0.f);
    }
    __syncthreads();

    if (f < H) {
        float accL[GC];
#pragma unroll
        for (int l = 0; l < GC; ++l) accL[l] = 0.f;
        gemv4<GC, 304>(agg3r, W_lr,            H, f, accL);
        gemv4<GC, 304>(mA2r, W_lr + 300 * 300, H, f, accL);
        gemv4<GC, 304>(inAr, W_lr + 600 * 300, H, f, accL);
#pragma unroll
        for (int l = 0; l < GC; ++l) {
            int a = a0 + l;
            if (a < A_TOT) aggL[(size_t)a * H + f] = accL[l];
        }
    }
}

// ===========================================================================
// PATH B kernels (not exercised when bigws) — unchanged.
// ===========================================================================
#define GB 4
#define RB (GB * NB)   // 24
__global__ __launch_bounds__(320) void k_msga2b(
    const float* __restrict__ f_bonds, const float* __restrict__ Wi_bond,
    const float* __restrict__ Wh0,
    const float* __restrict__ msgA1, float* __restrict__ msgA2,
    const int* __restrict__ a2b, const int* __restrict__ b2a,
    const int* __restrict__ b2revb)
{
    __shared__ __align__(16) float v[RB][304];
    __shared__ __align__(16) float fbl[RB][152];
    __shared__ int r_[RB], q_[RB], p_[RB];

    const int a0 = blockIdx.x * GB;
    const int tid = threadIdx.x;
    const int f = tid;

    if (tid < RB) {
        int a = a0 + tid / NB;
        int r = (a < A_TOT) ? a2b[a * NB + (tid % NB)] : 0;
        r_[tid] = r;
        q_[tid] = b2revb[r];
        p_[tid] = b2a[r];
    }
    __syncthreads();
    for (int idx = tid; idx < RB * 75; idx += 320) {
        int i = idx / 75, k4 = idx - i * 75;
        ((float4*)v[i])[k4] = ((const float4*)(msgA1 + (size_t)p_[i] * H))[k4];
    }
    for (int idx = tid; idx < RB * BF; idx += 320) {
        int i = idx / BF, k = idx - i * BF;
        fbl[i][k] = f_bonds[(size_t)q_[i] * BF + k];
    }
    __syncthreads();
    if (f < H) {
        float acc[RB];
#pragma unroll
        for (int i = 0; i < RB; ++i) acc[i] = 0.f;
        gemv4<RB, 152>(fbl, Wi_bond, BF, f, acc);
#pragma unroll
        for (int i = 0; i < RB; ++i) v[i][f] -= fmaxf(acc[i], 0.f);
    }
    __syncthreads();
    for (int idx = tid; idx < RB * BF; idx += 320) {
        int i = idx / BF, k = idx - i * BF;
        fbl[i][k] = f_bonds[(size_t)r_[i] * BF + k];
    }
    float accm[RB];
#pragma unroll
    for (int i = 0; i < RB; ++i) accm[i] = 0.f;
    if (f < H) gemv4<RB, 304>(v, Wh0, H, f, accm);
    __syncthreads();
    if (f < H) {
        float accr[RB];
#pragma unroll
        for (int i = 0; i < RB; ++i) accr[i] = 0.f;
        gemv4<RB, 152>(fbl, Wi_bond, BF, f, accr);
#pragma unroll
        for (int l = 0; l < GB; ++l) {
            float s = 0.f, mx = -INFINITY;
#pragma unroll
            for (int j = 0; j < NB; ++j) {
                int i = l * NB + j;
                float m1 = fmaxf(fmaxf(accr[i], 0.f) + accm[i], 0.f);
                s += m1; mx = fmaxf(mx, m1);
            }
            int a = a0 + l;
            if (a < A_TOT)
                msgA2[(size_t)a * H + f] = msgA1[(size_t)a * H + f] + s * mx;
        }
    }
}

#define GCB 2
#define RCB (GCB * NB)   // 12
__global__ __launch_bounds__(320) void k_agglb(
    const float* __restrict__ f_atoms, const float* __restrict__ f_bonds,
    const float* __restrict__ Wi_atom, const float* __restrict__ Wi_bond,
    const float* __restrict__ Wh0, const float* __restrict__ Wh1,
    const float* __restrict__ W_lr,
    const float* __restrict__ msgA1, const float* __restrict__ msgA2,
    const int* __restrict__ a2b, const int* __restrict__ b2a,
    const int* __restrict__ b2revb, float* __restrict__ aggL)
{
    __shared__ __align__(16) float u[RCB][304];
    __shared__ __align__(16) float w[RCB][304];
    __shared__ __align__(16) float fbl[RCB][152];
    __shared__ __align__(16) float agg3r[GCB][304];
    __shared__ __align__(16) float mA2r[GCB][304];
    __shared__ __align__(16) float inAr[GCB][304];
    __shared__ __align__(16) float fa[GCB][136];
    __shared__ int b_[RCB], rp_[RCB], p1_[RCB], q1_[RCB], p2_[RCB];

    const int a0 = blockIdx.x * GCB;
    const int tid = threadIdx.x;
    const int f = tid;

    if (tid < RCB) {
        int a = a0 + tid / NB;
        int b = (a < A_TOT) ? a2b[a * NB + (tid % NB)] : 0;
        int rp = b2revb[b];
        b_[tid] = b; rp_[tid] = rp;
        p1_[tid] = b2a[rp]; q1_[tid] = b2revb[rp]; p2_[tid] = b2a[b];
    }
    __syncthreads();
    for (int idx = tid; idx < RCB * 75; idx += 320) {
        int i = idx / 75, k4 = idx - i * 75;
        ((float4*)u[i])[k4] = ((const float4*)(msgA1 + (size_t)p1_[i] * H))[k4];
        ((float4*)w[i])[k4] = ((const float4*)(msgA2 + (size_t)p2_[i] * H))[k4];
    }
    for (int idx = tid; idx < RCB * BF; idx += 320) {
        int i = idx / BF, k = idx - i * BF;
        fbl[i][k] = f_bonds[(size_t)q1_[i] * BF + k];
    }
    for (int idx = tid; idx < GCB * 75; idx += 320) {
        int l = idx / 75, k4 = idx - l * 75;
        int a = a0 + l;
        ((float4*)mA2r[l])[k4] = (a < A_TOT) ? ((const float4*)(msgA2 + (size_t)a * H))[k4]
                                             : make_float4(0.f, 0.f, 0.f, 0.f);
    }
    for (int idx = tid; idx < GCB * AF; idx += 320) {
        int l = idx / AF, k = idx - l * AF;
        int a = a0 + l;
        fa[l][k] = (a < A_TOT) ? f_atoms[(size_t)a * AF + k] : 0.f;
    }
    __syncthreads();
    if (f < H) {
        float acc[RCB];
#pragma unroll
        for (int i = 0; i < RCB; ++i) acc[i] = 0.f;
        gemv4<RCB, 152>(fbl, Wi_bond, BF, f, acc);
#pragma unroll
        for (int i = 0; i < RCB; ++i) u[i][f] -= fmaxf(acc[i], 0.f);
    }
    __syncthreads();
    for (int idx = tid; idx < RCB * BF; idx += 320) {
        int i = idx / BF, k = idx - i * BF;
        fbl[i][k] = f_bonds[(size_t)rp_[i] * BF + k];
    }
    __syncthreads();
    if (f < H) {
        float accm[RCB], accr[RCB];
#pragma unroll
        for (int i = 0; i < RCB; ++i) { accm[i] = 0.f; accr[i] = 0.f; }
        gemv4<RCB, 304>(u, Wh0, H, f, accm);
        gemv4<RCB, 152>(fbl, Wi_bond, BF, f, accr);
#pragma unroll
        for (int i = 0; i < RCB; ++i)
            w[i][f] -= fmaxf(fmaxf(accr[i], 0.f) + accm[i], 0.f);
    }
    __syncthreads();
    for (int idx = tid; idx < RCB * BF; idx += 320) {
        int i = idx / BF, k = idx - i * BF;
        fbl[i][k] = f_bonds[(size_t)b_[i] * BF + k];
    }
    __syncthreads();
    if (f < H) {
        float accm[RCB], accb[RCB];
#pragma unroll
        for (int i = 0; i < RCB; ++i) { accm[i] = 0.f; accb[i] = 0.f; }
        gemv4<RCB, 304>(w, Wh1, H, f, accm);
        gemv4<RCB, 152>(fbl, Wi_bond, BF, f, accb);
#pragma unroll
        for (int l = 0; l < GCB; ++l) {
            float s = 0.f, mx = -INFINITY;
#pragma unroll
            for (int j = 0; j < NB; ++j) {
                int i = l * NB + j;
                float m2 = fmaxf(fmaxf(accb[i], 0.f) + accm[i], 0.f);
                s += m2; mx = fmaxf(mx, m2);
            }
            agg3r[l][f] = s * mx;
        }
        float acc2[GCB];
#pragma unroll
        for (int l = 0; l < GCB; ++l) acc2[l] = 0.f;
        gemv4<GCB, 136>(fa, Wi_atom, AF, f, acc2);
#pragma unroll
        for (int l = 0; l < GCB; ++l) inAr[l][f] = fmaxf(acc2[l], 0.f);
    }
    __syncthreads();
    if (f < H) {
        float accL[GCB];
#pragma unroll
        for (int l = 0; l < GCB; ++l) accL[l] = 0.f;
        gemv4<GCB, 304>(agg3r, W_lr,            H, f, accL);
        gemv4<GCB, 304>(mA2r, W_lr + 300 * 300, H, f, accL);
        gemv4<GCB, 304>(inAr, W_lr + 600 * 300, H, f, accL);
#pragma unroll
        for (int l = 0; l < GCB; ++l) {
            int a = a0 + l;
            if (a < A_TOT) aggL[(size_t)a * H + f] = accL[l];
        }
    }
}

// ===========================================================================
// Pack 4 [900,300] GRU weight mats -> P[k/4][gate][f][k%4]  (270000 each)
// ===========================================================================
__global__ __launch_bounds__(256) void k_pack4(
    const float* __restrict__ s0, const float* __restrict__ s1,
    const float* __restrict__ s2, const float* __restrict__ s3,
    float* __restrict__ d0, float* __restrict__ d1,
    float* __restrict__ d2, float* __restrict__ d3)
{
    const float* S[4] = {s0, s1, s2, s3};
    float* D[4] = {d0, d1, d2, d3};
    int z = blockIdx.y;
    int o = blockIdx.x * 256 + threadIdx.x;
    if (o < 270000) {
        int k4 = o / 3600; int rem = o - k4 * 3600;
        int g = rem / 1200; int rem2 = rem - g * 1200;
        int fx = rem2 >> 2; int kk = rem2 & 3;
        int k = k4 * 4 + kk;
        D[z][o] = S[z][(size_t)(g * 300 + fx) * 300 + k];
    }
}

// ===========================================================================
// prep: h0[m] = max_t aggL[1+m*40+t]; then aggL row <- relu(row + gru_bias)
// ===========================================================================
__global__ __launch_bounds__(256) void prep_kernel(
    float* aggL, const float* __restrict__ gru_bias, float* __restrict__ h0)
{
    int m = blockIdx.x;
    for (int f = threadIdx.x; f < H; f += 256) {
        float b = gru_bias[f];
        float mx = -INFINITY;
        for (int t = 0; t < ASZ; ++t) {
            size_t o = (size_t)(1 + m * ASZ + t) * H + f;
            float v = aggL[o];
            mx = fmaxf(mx, v);
            aggL[o] = fmaxf(v + b, 0.f);
        }
        h0[(size_t)m * H + f] = mx;
    }
}

__device__ __forceinline__ float dev_sigmoid(float x) {
    return 1.f / (1.f + __expf(-x));
}
__device__ __forceinline__ float dev_tanh(float x) {
    return 1.f - 2.f / (__expf(2.f * x) + 1.f);
}

// ===========================================================================
// Persistent GRU, v3 (R3-verified).
// ===========================================================================
#define GM 8
__global__ __launch_bounds__(320) void k_gru_all(
    const float* __restrict__ msg,
    const float* __restrict__ Pih_f, const float* __restrict__ Phh_f,
    const float* __restrict__ bih_f, const float* __restrict__ bhh_f,
    const float* __restrict__ Pih_b, const float* __restrict__ Phh_b,
    const float* __restrict__ bih_b, const float* __restrict__ bhh_b,
    const float* __restrict__ h0, float* __restrict__ out_f,
    float* __restrict__ out_b)
{
    __shared__ __align__(16) float hs[GM][304];
    __shared__ __align__(16) float ms[2][GM][304];

    const int bid  = blockIdx.x;
    const int xcd  = bid & 7;
    const int slot = bid >> 3;
    const int dir  = xcd >> 2;
    const int lg   = (xcd & 3) * 32 + slot;
    const int m0   = lg * GM;
    if (m0 >= NMOL) return;

    const float* Pih = dir ? Pih_b : Pih_f;
    const float* Phh = dir ? Phh_b : Phh_f;
    const float* bih = dir ? bih_b : bih_f;
    const float* bhh = dir ? bhh_b : bhh_f;
    float* out       = dir ? out_b : out_f;

    const int tid  = threadIdx.x;
    const bool act = tid < H;
    const int f    = act ? tid : (H - 1);

    for (int idx = tid; idx < GM * 75; idx += 320) {
        int i = idx / 75, k4 = idx - i * 75;
        int m = m0 + i;
        ((float4*)hs[i])[k4] = (m < NMOL) ? ((const float4*)(h0 + (size_t)m * H))[k4]
                                          : make_float4(0.f, 0.f, 0.f, 0.f);
    }
    {
        const int t0 = dir ? (ASZ - 1) : 0;
        for (int idx = tid; idx < GM * 75; idx += 320) {
            int i = idx / 75, k4 = idx - i * 75;
            int m = m0 + i;
            ((float4*)ms[0][i])[k4] = (m < NMOL)
                ? ((const float4*)(msg + (size_t)(m * ASZ + t0) * H))[k4]
                : make_float4(0.f, 0.f, 0.f, 0.f);
        }
    }

    float bR = 0.f, bZ = 0.f, bIN = 0.f, bHN = 0.f;
    if (act) {
        bR  = bih[f] + bhh[f];
        bZ  = bih[300 + f] + bhh[300 + f];
        bIN = bih[600 + f];
        bHN = bhh[600 + f];
    }
    const float* pi = Pih + (size_t)f * 4;
    const float* ph = Phh + (size_t)f * 4;

    for (int s = 0; s < ASZ; ++s) {
        const int cur = s & 1;
        const int t = dir ? (ASZ - 1 - s) : s;
        __syncthreads();

        float4 st0 = make_float4(0.f, 0.f, 0.f, 0.f);
        float4 st1 = make_float4(0.f, 0.f, 0.f, 0.f);
        const bool more = (s + 1 < ASZ);
        if (more) {
            const int tn = dir ? (ASZ - 2 - s) : (s + 1);
            {
                int i = tid / 75, k4 = tid - i * 75;
                int m = m0 + i;
                if (m < NMOL)
                    st0 = ((const float4*)(msg + (size_t)(m * ASZ + tn) * H))[k4];
            }
            {
                int idx = tid + 320;
                if (idx < GM * 75) {
                    int i = idx / 75, k4 = idx - i * 75;
                    int m = m0 + i;
                    if (m < NMOL)
                        st1 = ((const float4*)(msg + (size_t)(m * ASZ + tn) * H))[k4];
                }
            }
        }

        float aR[GM], aZ[GM], aIN[GM], aHN[GM];
#pragma unroll
        for (int i = 0; i < GM; ++i) { aR[i] = 0.f; aZ[i] = 0.f; aIN[i] = 0.f; aHN[i] = 0.f; }

        float4 wiR = *(const float4*)(pi);
        float4 wiZ = *(const float4*)(pi + 1200);
        float4 wiN = *(const float4*)(pi + 2400);
        float4 whR = *(const float4*)(ph);
        float4 whZ = *(const float4*)(ph + 1200);
        float4 whN = *(const float4*)(ph + 2400);

        for (int k4i = 0; k4i < 75; ++k4i) {
            const int kn = k4i + (k4i < 74 ? 1 : 0);
            const float* pin = pi + (size_t)kn * 3600;
            const float* phn = ph + (size_t)kn * 3600;
            float4 nR = *(const float4*)(pin);
            float4 nZ = *(const float4*)(pin + 1200);
            float4 nN = *(const float4*)(pin + 2400);
            float4 oR = *(const float4*)(phn);
            float4 oZ = *(const float4*)(phn + 1200);
            float4 oN = *(const float4*)(phn + 2400);

            const int k4 = k4i * 4;
#pragma unroll
            for (int i = 0; i < GM; ++i) {
                float4 m4 = *(const float4*)&ms[cur][i][k4];
                float4 h4 = *(const float4*)&hs[i][k4];
                aR[i]  = fmaf(m4.x, wiR.x, fmaf(m4.y, wiR.y, fmaf(m4.z, wiR.z, fmaf(m4.w, wiR.w, aR[i]))));
                aR[i]  = fmaf(h4.x, whR.x, fmaf(h4.y, whR.y, fmaf(h4.z, whR.z, fmaf(h4.w, whR.w, aR[i]))));
                aZ[i]  = fmaf(m4.x, wiZ.x, fmaf(m4.y, wiZ.y, fmaf(m4.z, wiZ.z, fmaf(m4.w, wiZ.w, aZ[i]))));
                aZ[i]  = fmaf(h4.x, whZ.x, fmaf(h4.y, whZ.y, fmaf(h4.z, whZ.z, fmaf(h4.w, whZ.w, aZ[i]))));
                aIN[i] = fmaf(m4.x, wiN.x, fmaf(m4.y, wiN.y, fmaf(m4.z, wiN.z, fmaf(m4.w, wiN.w, aIN[i]))));
                aHN[i] = fmaf(h4.x, whN.x, fmaf(h4.y, whN.y, fmaf(h4.z, whN.z, fmaf(h4.w, whN.w, aHN[i]))));
            }
            wiR = nR; wiZ = nZ; wiN = nN;
            whR = oR; whZ = oZ; whN = oN;
        }
        __syncthreads();

        if (act) {
#pragma unroll
            for (int i = 0; i < GM; ++i) {
                int m = m0 + i;
                if (m < NMOL) {
                    float r = dev_sigmoid(aR[i] + bR);
                    float z = dev_sigmoid(aZ[i] + bZ);
                    float n = dev_tanh(aIN[i] + bIN + r * (aHN[i] + bHN));
                    float hn = (1.f - z) * n + z * hs[i][f];
                    hs[i][f] = hn;
                    __builtin_nontemporal_store(hn, out + (size_t)(m * ASZ + t) * H + f);
                }
            }
        }
        if (more) {
            const int nxt = cur ^ 1;
            {
                int i = tid / 75, k4 = tid - i * 75;
                ((float4*)ms[nxt][i])[k4] = st0;
            }
            {
                int idx = tid + 320;
                if (idx < GM * 75) {
                    int i = idx / 75, k4 = idx - i * 75;
                    ((float4*)ms[nxt][i])[k4] = st1;
                }
            }
        }
    }
}

// ===========================================================================
// Fused output projection: hid = relu([outf|outb] @ W_o + b_o), K=600.
// ===========================================================================
__global__ __launch_bounds__(256) void gemm_wo(
    const float* __restrict__ A0, const float* __restrict__ A1,
    const float* __restrict__ W, float* __restrict__ C,
    const float* __restrict__ bias)
{
    const int M = NMOL * ASZ, K2 = 600, N = H;
    __shared__ float As[16][64];
    __shared__ float Bs[16][64];
    const int tx = threadIdx.x, ty = threadIdx.y;
    const int tid = ty * 16 + tx;
    const int m0 = blockIdx.x * 64, n0 = blockIdx.y * 64;
    const int am = tid >> 2, ak = (tid & 3) * 4;
    const int bk = tid >> 4, bn = (tid & 15) * 4;
    const int arow = m0 + am;

    float acc[4][4];
#pragma unroll
    for (int i = 0; i < 4; ++i)
#pragma unroll
        for (int j = 0; j < 4; ++j) acc[i][j] = 0.f;

    for (int k0 = 0; k0 < K2; k0 += 16) {
#pragma unroll
        for (int j = 0; j < 4; ++j) {
            int k = k0 + ak + j;
            float v = 0.f;
            if (arow < M && k < K2)
                v = (k < 300) ? A0[(size_t)arow * 300 + k]
                              : A1[(size_t)arow * 300 + (k - 300)];
            As[ak + j][am] = v;
        }
#pragma unroll
        for (int j = 0; j < 4; ++j) {
            int k = k0 + bk, n = n0 + bn + j;
            Bs[bk][bn + j] = (k < K2 && n < N) ? W[(size_t)k * N + n] : 0.f;
        }
        __syncthreads();
#pragma unroll
        for (int kk = 0; kk < 16; ++kk) {
            float4 av = *(const float4*)&As[kk][ty * 4];
            float4 bv = *(const float4*)&Bs[kk][tx * 4];
            float a4[4] = {av.x, av.y, av.z, av.w};
            float b4[4] = {bv.x, bv.y, bv.z, bv.w};
#pragma unroll
            for (int i = 0; i < 4; ++i)
#pragma unroll
                for (int j = 0; j < 4; ++j)
                    acc[i][j] = fmaf(a4[i], b4[j], acc[i][j]);
        }
        __syncthreads();
    }
#pragma unroll
    for (int i = 0; i < 4; ++i) {
        int m = m0 + ty * 4 + i;
        if (m >= M) continue;
#pragma unroll
        for (int j = 0; j < 4; ++j) {
            int n = n0 + tx * 4 + j;
            if (n >= N) continue;
            C[(size_t)m * N + n] = fmaxf(acc[i][j] + bias[n], 0.f);
        }
    }
}

__global__ __launch_bounds__(256) void mean_kernel(
    const float* __restrict__ hid, float* __restrict__ out)
{
    int m = blockIdx.x;
    for (int f = threadIdx.x; f < H; f += 256) {
        float s = 0.f;
        for (int t = 0; t < ASZ; ++t)
            s += hid[(size_t)(m * ASZ + t) * H + f];
        out[(size_t)m * H + f] = s * (1.f / 40.f);
    }
}

// ===========================================================================
extern "C" void kernel_launch(void* const* d_in, const int* in_sizes, int n_in,
                              void* d_out, int out_size, void* d_ws, size_t ws_size,
                              hipStream_t stream)
{
    const float* f_atoms  = (const float*)d_in[0];
    const float* f_bonds  = (const float*)d_in[1];
    const float* Wi_atom  = (const float*)d_in[2];
    const float* Wi_bond  = (const float*)d_in[3];
    const float* Wh0      = (const float*)d_in[4];
    const float* Wh1      = (const float*)d_in[5];
    const float* W_lr     = (const float*)d_in[6];
    const float* W_o      = (const float*)d_in[7];
    const float* b_o      = (const float*)d_in[8];
    const float* gru_bias = (const float*)d_in[9];
    const float* gWih_f   = (const float*)d_in[10];
    const float* gWhh_f   = (const float*)d_in[11];
    const float* gbih_f   = (const float*)d_in[12];
    const float* gbhh_f   = (const float*)d_in[13];
    const float* gWih_b   = (const float*)d_in[14];
    const float* gWhh_b   = (const float*)d_in[15];
    const float* gbih_b   = (const float*)d_in[16];
    const float* gbhh_b   = (const float*)d_in[17];
    const int*   a2b      = (const int*)d_in[18];
    const int*   b2a      = (const int*)d_in[19];
    const int*   b2revb   = (const int*)d_in[20];

    char* wsb = (char*)d_ws;
    const bool bigws = (ws_size >= (size_t)288003600);

    // Pack MP weights into d_out scratch (dead until mean_kernel overwrites it)
    float* dscratch = (float*)d_out;
    {
        dim3 g((90000 + 255) / 256, 4);
        k_packmp<<<g, 256, 0, stream>>>(Wh0, Wh1, Wi_bond, Wi_atom, dscratch);
    }
    const float4* PWh0 = (const float4*)(dscratch + PK_WH0);
    const float4* PWh1 = (const float4*)(dscratch + PK_WH1);
    const float4* PWib = (const float4*)(dscratch + PK_WIB);
    const float4* PWia = (const float4*)(dscratch + PK_WIA);

    float *aggLp, *outfp, *outbp, *h0p, *P0, *P1, *P2, *P3, *hidp;

    if (bigws) {
        // PATH A: fp32 m1 materialization.  Peak = 288,003,600 B.
        float* msgA = (float*)wsb;
        float* aggL = (float*)(wsb + 48001200);
        float* m1   = (float*)(wsb + 96002400);
        outfp = (float*)(wsb + 96002400);
        outbp = (float*)(wsb + 144002400);
        P0 = (float*)(wsb + 192002400);
        P1 = P0 + 270000; P2 = P1 + 270000; P3 = P2 + 270000;
        h0p = (float*)(wsb + 196322400);
        aggLp = aggL; hidp = msgA;

        k_msga1<<<(A_TOT + GA - 1) / GA, 320, 0, stream>>>(
            f_atoms, f_bonds, PWia, PWib, a2b, msgA);
        k_m1f<<<(BN_TOT + NR2 - 1) / NR2, 320, 0, stream>>>(
            f_bonds, PWib, PWh0, msgA, b2a, b2revb, m1);
        k_msga2ef<<<(A_TOT * H + 255) / 256, 256, 0, stream>>>(m1, a2b, msgA);
        k_aggl2f<<<(A_TOT + GC - 1) / GC, 320, 0, stream>>>(
            f_atoms, f_bonds, PWia, PWib, PWh1, W_lr,
            msgA, m1, a2b, b2a, b2revb, aggL);
    } else {
        // PATH B: recompute path (no m1 buffer).  Peak = 240,003,600 B.
        float* ws = (float*)d_ws;
        float* msgA1 = ws;
        float* msgA2 = ws + 12000300;
        float* aggL  = ws + 24000600;
        outfp = ws + 36000900;
        outbp = ws + 48000900;
        h0p   = ws;
        P0 = ws + 300000; P1 = ws + 570000; P2 = ws + 840000; P3 = ws + 1110000;
        aggLp = aggL; hidp = msgA2;

        k_msga1<<<(A_TOT + GA - 1) / GA, 320, 0, stream>>>(
            f_atoms, f_bonds, PWia, PWib, a2b, msgA1);
        k_msga2b<<<(A_TOT + GB - 1) / GB, 320, 0, stream>>>(
            f_bonds, Wi_bond, Wh0, msgA1, msgA2, a2b, b2a, b2revb);
        k_agglb<<<(A_TOT + GCB - 1) / GCB, 320, 0, stream>>>(
            f_atoms, f_bonds, Wi_atom, Wi_bond, Wh0, Wh1, W_lr,
            msgA1, msgA2, a2b, b2a, b2revb, aggL);
    }

    // pack GRU weights (into regions dead after the MP phase)
    {
        dim3 g((270000 + 255) / 256, 4);
        k_pack4<<<g, 256, 0, stream>>>(gWih_f, gWhh_f, gWih_b, gWhh_b,
                                       P0, P1, P2, P3);
    }

    // h0 + in-place relu(aggL + bias)
    prep_kernel<<<NMOL, 256, 0, stream>>>(aggLp, gru_bias, h0p);

    // persistent GRU v3: 256 1D blocks x 320 threads, XCD-partitioned by dir
    k_gru_all<<<256, 320, 0, stream>>>(
        aggLp + H, P0, P1, gbih_f, gbhh_f, P2, P3, gbih_b, gbhh_b,
        h0p, outfp, outbp);

    // hid = relu([outf|outb]@W_o + b_o)
    {
        dim3 grid((NMOL * ASZ + 63) / 64, (H + 63) / 64);
        dim3 block(16, 16);
        gemm_wo<<<grid, block, 0, stream>>>(outfp, outbp, W_o, hidp, b_o);
    }

    // per-mol mean -> d_out (overwrites the weight-pack scratch)
    mean_kernel<<<NMOL, 256, 0, stream>>>(hidp, (float*)d_out);
}

// Round 9
// 7176.052 us; speedup vs baseline: 1.6104x; 1.0204x over previous
//
#include <hip/hip_runtime.h>
#include <math.h>

constexpr int A_TOT  = 40001;
constexpr int NB     = 6;
constexpr int BN_TOT = 160001;
constexpr int AF     = 133;
constexpr int BF     = 147;
constexpr int H      = 300;
constexpr int NMOL   = 1000;
constexpr int ASZ    = 40;

// Packed-weight layout: P[(k4*300+f)*4+j] = W[(k4*4+j)*300+f], zero-padded.
// Packs live in d_out scratch (dead until mean_kernel).
constexpr int PK_WH0 = 0;
constexpr int PK_WH1 = 90000;
constexpr int PK_WIB = 180000;
constexpr int PK_WIA = 224400;

// ---------------------------------------------------------------------------
// Raw GEMV core (W_lr and PATH B).
// ---------------------------------------------------------------------------
template<int NR, int P>
__device__ __forceinline__ void gemv4(const float (*rows)[P], const float* __restrict__ W,
                                      int K, int f, float* __restrict__ acc)
{
    int k4 = 0;
    for (; k4 + 4 <= K; k4 += 4) {
        float w0 = W[(k4 + 0) * H + f];
        float w1 = W[(k4 + 1) * H + f];
        float w2 = W[(k4 + 2) * H + f];
        float w3 = W[(k4 + 3) * H + f];
#pragma unroll
        for (int i = 0; i < NR; ++i) {
            float4 b = *(const float4*)&rows[i][k4];
            acc[i] = fmaf(b.x, w0, fmaf(b.y, w1, fmaf(b.z, w2, fmaf(b.w, w3, acc[i]))));
        }
    }
    for (; k4 < K; ++k4) {
        float wv = W[k4 * H + f];
#pragma unroll
        for (int i = 0; i < NR; ++i) acc[i] = fmaf(rows[i][k4], wv, acc[i]);
    }
}

// Raw GEMV, two output features per thread (K multiple of 4).
template<int NR, int P>
__device__ __forceinline__ void gemv42(const float (*rows)[P], const float* __restrict__ W,
                                       int K, int f1, int f2,
                                       float* __restrict__ acc1, float* __restrict__ acc2)
{
#pragma clang loop unroll(disable)
    for (int k4 = 0; k4 < K; k4 += 4) {
        float w10 = W[(k4 + 0) * H + f1], w11 = W[(k4 + 1) * H + f1];
        float w12 = W[(k4 + 2) * H + f1], w13 = W[(k4 + 3) * H + f1];
        float w20 = W[(k4 + 0) * H + f2], w21 = W[(k4 + 1) * H + f2];
        float w22 = W[(k4 + 2) * H + f2], w23 = W[(k4 + 3) * H + f2];
#pragma unroll
        for (int i = 0; i < NR; ++i) {
            float4 b = *(const float4*)&rows[i][k4];
            acc1[i] = fmaf(b.x, w10, fmaf(b.y, w11, fmaf(b.z, w12, fmaf(b.w, w13, acc1[i]))));
            acc2[i] = fmaf(b.x, w20, fmaf(b.y, w21, fmaf(b.z, w22, fmaf(b.w, w23, acc2[i]))));
        }
    }
}

// ---------------------------------------------------------------------------
// Packed GEMV core: one float4 weight load per k4. Rows zero-padded in LDS.
// k4i loop MUST stay rolled (R6: full unroll -> 128-VGPR cap spill).
// AMORTIZATION RULE (R7): rows-per-weight-load dominates; NR=12 > NR=6.
// ---------------------------------------------------------------------------
template<int NR, int P>
__device__ __forceinline__ void gemv4p(const float (*rows)[P], const float4* __restrict__ Pw,
                                       int K4, int f, float* __restrict__ acc)
{
#pragma clang loop unroll(disable)
    for (int k4i = 0; k4i < K4; ++k4i) {
        float4 w = Pw[k4i * 300 + f];
#pragma unroll
        for (int i = 0; i < NR; ++i) {
            float4 b = *(const float4*)&rows[i][k4i * 4];
            acc[i] = fmaf(b.x, w.x, fmaf(b.y, w.y, fmaf(b.z, w.z, fmaf(b.w, w.w, acc[i]))));
        }
    }
}

// Packed GEMV, two output features per thread: each broadcast ds_read of a
// row float4 feeds 8 FMAs instead of 4 (LDS:FMA ratio 1:8) — R9 probe of the
// LDS-issue-ceiling theory.
template<int NR, int P>
__device__ __forceinline__ void gemv4p2(const float (*rows)[P], const float4* __restrict__ Pw,
                                        int K4, int f1, int f2,
                                        float* __restrict__ acc1, float* __restrict__ acc2)
{
#pragma clang loop unroll(disable)
    for (int k4i = 0; k4i < K4; ++k4i) {
        float4 w1 = Pw[k4i * 300 + f1];
        float4 w2 = Pw[k4i * 300 + f2];
#pragma unroll
        for (int i = 0; i < NR; ++i) {
            float4 b = *(const float4*)&rows[i][k4i * 4];
            acc1[i] = fmaf(b.x, w1.x, fmaf(b.y, w1.y, fmaf(b.z, w1.z, fmaf(b.w, w1.w, acc1[i]))));
            acc2[i] = fmaf(b.x, w2.x, fmaf(b.y, w2.y, fmaf(b.z, w2.z, fmaf(b.w, w2.w, acc2[i]))));
        }
    }
}

// ===========================================================================
// Pack Wh0/Wh1/Wi_bond/Wi_atom into d_out scratch.
// ===========================================================================
__global__ __launch_bounds__(256) void k_packmp(
    const float* __restrict__ s0, const float* __restrict__ s1,
    const float* __restrict__ s2, const float* __restrict__ s3,
    float* __restrict__ dout)
{
    const float* S[4] = {s0, s1, s2, s3};
    const int Ks[4]  = {300, 300, 147, 133};
    const int K4s[4] = {75, 75, 37, 34};
    const int off[4] = {PK_WH0, PK_WH1, PK_WIB, PK_WIA};
    int z = blockIdx.y;
    int o = blockIdx.x * 256 + threadIdx.x;
    int n = K4s[z] * 1200;
    if (o < n) {
        int k4 = o / 1200; int rem = o - k4 * 1200;
        int f = rem >> 2;  int j = rem & 3;
        int k = k4 * 4 + j;
        dout[off[z] + o] = (k < Ks[z]) ? S[z][(size_t)k * 300 + f] : 0.f;
    }
}

// ===========================================================================
// K1: msgA1[a,:] = relu(f_atoms[a]@Wi_atom) + sum*max of x_b.
// Chunked bond GEMV (NR=6) + rolled k4i loop.
// ===========================================================================
#define GA 4
__global__ __launch_bounds__(320) void k_msga1(
    const float* __restrict__ f_atoms, const float* __restrict__ f_bonds,
    const float4* __restrict__ PWia, const float4* __restrict__ PWib,
    const int* __restrict__ a2b, float* __restrict__ msgA1)
{
    __shared__ __align__(16) float fb[GA * NB][152];
    __shared__ __align__(16) float fa[GA][136];
    __shared__ int bidx[GA * NB];

    const int a0 = blockIdx.x * GA;
    const int tid = threadIdx.x;
    const int f = tid;

    if (tid < GA * NB) {
        int a = a0 + tid / NB;
        bidx[tid] = (a < A_TOT) ? a2b[a * NB + (tid % NB)] : 0;
    }
    __syncthreads();
    for (int idx = tid; idx < GA * NB * 148; idx += 320) {
        int i = idx / 148, k = idx - i * 148;
        fb[i][k] = (k < BF) ? f_bonds[(size_t)bidx[i] * BF + k] : 0.f;
    }
    for (int idx = tid; idx < GA * 136; idx += 320) {
        int l = idx / 136, k = idx - l * 136;
        int a = a0 + l;
        fa[l][k] = (a < A_TOT && k < AF) ? f_atoms[(size_t)a * AF + k] : 0.f;
    }
    __syncthreads();

    if (f < H) {
        float part[GA];
#pragma unroll
        for (int l = 0; l < GA; ++l) {
            float acc[NB];
#pragma unroll
            for (int j = 0; j < NB; ++j) acc[j] = 0.f;
            gemv4p<NB, 152>((const float (*)[152])&fb[l * NB], PWib, 37, f, acc);
            float s = 0.f, mx = -INFINITY;
#pragma unroll
            for (int j = 0; j < NB; ++j) {
                float x = fmaxf(acc[j], 0.f);
                s += x; mx = fmaxf(mx, x);
            }
            part[l] = s * mx;
        }
        float acc2[GA];
#pragma unroll
        for (int l = 0; l < GA; ++l) acc2[l] = 0.f;
        gemv4p<GA, 136>(fa, PWia, 34, f, acc2);
#pragma unroll
        for (int l = 0; l < GA; ++l) {
            int a = a0 + l;
            if (a < A_TOT) msgA1[(size_t)a * H + f] = fmaxf(acc2[l], 0.f) + part[l];
        }
    }
}

// ===========================================================================
// PATH A: m1 fp32 materialization.  NR2=8, rolled gemv loops. (control)
// ===========================================================================
#define NR2 8
__global__ __launch_bounds__(320) void k_m1f(
    const float* __restrict__ f_bonds, const float4* __restrict__ PWib,
    const float4* __restrict__ PWh0, const float* __restrict__ msgA1,
    const int* __restrict__ b2a, const int* __restrict__ b2revb,
    float* __restrict__ m1)
{
    __shared__ __align__(16) float v[NR2][304];
    __shared__ __align__(16) float fbl[NR2][152];
    __shared__ int r_[NR2], q_[NR2], p_[NR2];

    const int r0 = blockIdx.x * NR2;
    const int tid = threadIdx.x;
    const int f = tid;

    if (tid < NR2) {
        int r = r0 + tid;
        if (r >= BN_TOT) r = 0;
        r_[tid] = r;
        q_[tid] = b2revb[r];
        p_[tid] = b2a[r];
    }
    __syncthreads();
    for (int idx = tid; idx < NR2 * 75; idx += 320) {
        int i = idx / 75, k4 = idx - i * 75;
        ((float4*)v[i])[k4] = ((const float4*)(msgA1 + (size_t)p_[i] * H))[k4];
    }
    for (int idx = tid; idx < NR2 * 148; idx += 320) {
        int i = idx / 148, k = idx - i * 148;
        fbl[i][k] = (k < BF) ? f_bonds[(size_t)q_[i] * BF + k] : 0.f;
    }
    __syncthreads();
    if (f < H) {
        float acc[NR2];
#pragma unroll
        for (int i = 0; i < NR2; ++i) acc[i] = 0.f;
        gemv4p<NR2, 152>(fbl, PWib, 37, f, acc);
#pragma unroll
        for (int i = 0; i < NR2; ++i) v[i][f] -= fmaxf(acc[i], 0.f);
    }
    __syncthreads();
    for (int idx = tid; idx < NR2 * 148; idx += 320) {
        int i = idx / 148, k = idx - i * 148;
        fbl[i][k] = (k < BF) ? f_bonds[(size_t)r_[i] * BF + k] : 0.f;
    }
    float accm[NR2];
#pragma unroll
    for (int i = 0; i < NR2; ++i) accm[i] = 0.f;
    if (f < H) gemv4p<NR2, 304>(v, PWh0, 75, f, accm);
    __syncthreads();
    if (f < H) {
        float accr[NR2];
#pragma unroll
        for (int i = 0; i < NR2; ++i) accr[i] = 0.f;
        gemv4p<NR2, 152>(fbl, PWib, 37, f, accr);
#pragma unroll
        for (int i = 0; i < NR2; ++i) {
            int r = r0 + i;
            if (r < BN_TOT)
                m1[(size_t)r * H + f] = fmaxf(fmaxf(accr[i], 0.f) + accm[i], 0.f);
        }
    }
}

__global__ __launch_bounds__(256) void k_msga2ef(
    const float* __restrict__ m1, const int* __restrict__ a2b, float* msgA)
{
    int idx = blockIdx.x * 256 + threadIdx.x;
    if (idx >= A_TOT * H) return;
    int a = idx / H;
    int f = idx - a * H;
    float s = 0.f, mx = -INFINITY;
#pragma unroll
    for (int j = 0; j < NB; ++j) {
        int r = a2b[a * NB + j];
        float v = m1[(size_t)r * H + f];
        s += v;
        mx = fmaxf(mx, v);
    }
    msgA[idx] += s * mx;
}

// ===========================================================================
// aggl2f v2 (R9): F_PER=2 — 192 threads, lanes<150 each compute features
// (f, f+150). Broadcast ds_read amortized over 8 FMAs (was 4): LDS wave-
// instructions x0.6, FMA wave-instructions x1.2. GC=2 kept (R7 rule).
// ===========================================================================
#define GC 2
#define RC (GC * NB)   // 12
__global__ __launch_bounds__(192) void k_aggl2f(
    const float* __restrict__ f_atoms, const float* __restrict__ f_bonds,
    const float4* __restrict__ PWia, const float4* __restrict__ PWib,
    const float4* __restrict__ PWh1, const float* __restrict__ W_lr,
    const float* __restrict__ msgA2, const float* __restrict__ m1,
    const int* __restrict__ a2b, const int* __restrict__ b2a,
    const int* __restrict__ b2revb, float* __restrict__ aggL)
{
    __shared__ __align__(16) float w[RC][304];
    __shared__ __align__(16) float fbl[RC][152];
    __shared__ __align__(16) float agg3r[GC][304];
    __shared__ __align__(16) float mA2r[GC][304];
    __shared__ __align__(16) float inAr[GC][304];
    __shared__ __align__(16) float fa[GC][136];
    __shared__ int b_[RC], rp_[RC], p2_[RC];

    const int a0 = blockIdx.x * GC;
    const int tid = threadIdx.x;
    const bool act = tid < 150;
    const int f1 = act ? tid : 0;
    const int f2 = f1 + 150;

    if (tid < RC) {
        int a = a0 + tid / NB;
        int b = (a < A_TOT) ? a2b[a * NB + (tid % NB)] : 0;
        b_[tid] = b;
        rp_[tid] = b2revb[b];
        p2_[tid] = b2a[b];
    }
    __syncthreads();
    for (int idx = tid; idx < RC * 75; idx += 192) {
        int i = idx / 75, k4 = idx - i * 75;
        float4 a4 = ((const float4*)(msgA2 + (size_t)p2_[i] * H))[k4];
        float4 b4 = ((const float4*)(m1 + (size_t)rp_[i] * H))[k4];
        ((float4*)w[i])[k4] = make_float4(a4.x - b4.x, a4.y - b4.y, a4.z - b4.z, a4.w - b4.w);
    }
    for (int idx = tid; idx < RC * 148; idx += 192) {
        int i = idx / 148, k = idx - i * 148;
        fbl[i][k] = (k < BF) ? f_bonds[(size_t)b_[i] * BF + k] : 0.f;
    }
    for (int idx = tid; idx < GC * 75; idx += 192) {
        int l = idx / 75, k4 = idx - l * 75;
        int a = a0 + l;
        ((float4*)mA2r[l])[k4] = (a < A_TOT) ? ((const float4*)(msgA2 + (size_t)a * H))[k4]
                                             : make_float4(0.f, 0.f, 0.f, 0.f);
    }
    for (int idx = tid; idx < GC * 136; idx += 192) {
        int l = idx / 136, k = idx - l * 136;
        int a = a0 + l;
        fa[l][k] = (a < A_TOT && k < AF) ? f_atoms[(size_t)a * AF + k] : 0.f;
    }
    __syncthreads();

    if (act) {
        float accm1[RC], accm2[RC];
#pragma unroll
        for (int i = 0; i < RC; ++i) { accm1[i] = 0.f; accm2[i] = 0.f; }
        gemv4p2<RC, 304>(w, PWh1, 75, f1, f2, accm1, accm2);
        float accb1[RC], accb2[RC];
#pragma unroll
        for (int i = 0; i < RC; ++i) { accb1[i] = 0.f; accb2[i] = 0.f; }
        gemv4p2<RC, 152>(fbl, PWib, 37, f1, f2, accb1, accb2);
#pragma unroll
        for (int l = 0; l < GC; ++l) {
            float s1 = 0.f, mx1 = -INFINITY, s2 = 0.f, mx2 = -INFINITY;
#pragma unroll
            for (int j = 0; j < NB; ++j) {
                int i = l * NB + j;
                float m21 = fmaxf(fmaxf(accb1[i], 0.f) + accm1[i], 0.f);
                float m22 = fmaxf(fmaxf(accb2[i], 0.f) + accm2[i], 0.f);
                s1 += m21; mx1 = fmaxf(mx1, m21);
                s2 += m22; mx2 = fmaxf(mx2, m22);
            }
            agg3r[l][f1] = s1 * mx1;
            agg3r[l][f2] = s2 * mx2;
        }
        float acc2a[GC], acc2b[GC];
#pragma unroll
        for (int l = 0; l < GC; ++l) { acc2a[l] = 0.f; acc2b[l] = 0.f; }
        gemv4p2<GC, 136>(fa, PWia, 34, f1, f2, acc2a, acc2b);
#pragma unroll
        for (int l = 0; l < GC; ++l) {
            inAr[l][f1] = fmaxf(acc2a[l], 0.f);
            inAr[l][f2] = fmaxf(acc2b[l], 0.f);
        }
    }
    __syncthreads();

    if (act) {
        float accL1[GC], accL2[GC];
#pragma unroll
        for (int l = 0; l < GC; ++l) { accL1[l] = 0.f; accL2[l] = 0.f; }
        gemv42<GC, 304>(agg3r, W_lr,            300, f1, f2, accL1, accL2);
        gemv42<GC, 304>(mA2r, W_lr + 300 * 300, 300, f1, f2, accL1, accL2);
        gemv42<GC, 304>(inAr, W_lr + 600 * 300, 300, f1, f2, accL1, accL2);
#pragma unroll
        for (int l = 0; l < GC; ++l) {
            int a = a0 + l;
            if (a < A_TOT) {
                aggL[(size_t)a * H + f1] = accL1[l];
                aggL[(size_t)a * H + f2] = accL2[l];
            }
        }
    }
}

// ===========================================================================
// PATH B kernels (not exercised when bigws) — unchanged.
// ===========================================================================
#define GB 4
#define RB (GB * NB)   // 24
__global__ __launch_bounds__(320) void k_msga2b(
    const float* __restrict__ f_bonds, const float* __restrict__ Wi_bond,
    const float* __restrict__ Wh0,
    const float* __restrict__ msgA1, float* __restrict__ msgA2,
    const int* __restrict__ a2b, const int* __restrict__ b2a,
    const int* __restrict__ b2revb)
{
    __shared__ __align__(16) float v[RB][304];
    __shared__ __align__(16) float fbl[RB][152];
    __shared__ int r_[RB], q_[RB], p_[RB];

    const int a0 = blockIdx.x * GB;
    const int tid = threadIdx.x;
    const int f = tid;

    if (tid < RB) {
        int a = a0 + tid / NB;
        int r = (a < A_TOT) ? a2b[a * NB + (tid % NB)] : 0;
        r_[tid] = r;
        q_[tid] = b2revb[r];
        p_[tid] = b2a[r];
    }
    __syncthreads();
    for (int idx = tid; idx < RB * 75; idx += 320) {
        int i = idx / 75, k4 = idx - i * 75;
        ((float4*)v[i])[k4] = ((const float4*)(msgA1 + (size_t)p_[i] * H))[k4];
    }
    for (int idx = tid; idx < RB * BF; idx += 320) {
        int i = idx / BF, k = idx - i * BF;
        fbl[i][k] = f_bonds[(size_t)q_[i] * BF + k];
    }
    __syncthreads();
    if (f < H) {
        float acc[RB];
#pragma unroll
        for (int i = 0; i < RB; ++i) acc[i] = 0.f;
        gemv4<RB, 152>(fbl, Wi_bond, BF, f, acc);
#pragma unroll
        for (int i = 0; i < RB; ++i) v[i][f] -= fmaxf(acc[i], 0.f);
    }
    __syncthreads();
    for (int idx = tid; idx < RB * BF; idx += 320) {
        int i = idx / BF, k = idx - i * BF;
        fbl[i][k] = f_bonds[(size_t)r_[i] * BF + k];
    }
    float accm[RB];
#pragma unroll
    for (int i = 0; i < RB; ++i) accm[i] = 0.f;
    if (f < H) gemv4<RB, 304>(v, Wh0, H, f, accm);
    __syncthreads();
    if (f < H) {
        float accr[RB];
#pragma unroll
        for (int i = 0; i < RB; ++i) accr[i] = 0.f;
        gemv4<RB, 152>(fbl, Wi_bond, BF, f, accr);
#pragma unroll
        for (int l = 0; l < GB; ++l) {
            float s = 0.f, mx = -INFINITY;
#pragma unroll
            for (int j = 0; j < NB; ++j) {
                int i = l * NB + j;
                float m1 = fmaxf(fmaxf(accr[i], 0.f) + accm[i], 0.f);
                s += m1; mx = fmaxf(mx, m1);
            }
            int a = a0 + l;
            if (a < A_TOT)
                msgA2[(size_t)a * H + f] = msgA1[(size_t)a * H + f] + s * mx;
        }
    }
}

#define GCB 2
#define RCB (GCB * NB)   // 12
__global__ __launch_bounds__(320) void k_agglb(
    const float* __restrict__ f_atoms, const float* __restrict__ f_bonds,
    const float* __restrict__ Wi_atom, const float* __restrict__ Wi_bond,
    const float* __restrict__ Wh0, const float* __restrict__ Wh1,
    const float* __restrict__ W_lr,
    const float* __restrict__ msgA1, const float* __restrict__ msgA2,
    const int* __restrict__ a2b, const int* __restrict__ b2a,
    const int* __restrict__ b2revb, float* __restrict__ aggL)
{
    __shared__ __align__(16) float u[RCB][304];
    __shared__ __align__(16) float w[RCB][304];
    __shared__ __align__(16) float fbl[RCB][152];
    __shared__ __align__(16) float agg3r[GCB][304];
    __shared__ __align__(16) float mA2r[GCB][304];
    __shared__ __align__(16) float inAr[GCB][304];
    __shared__ __align__(16) float fa[GCB][136];
    __shared__ int b_[RCB], rp_[RCB], p1_[RCB], q1_[RCB], p2_[RCB];

    const int a0 = blockIdx.x * GCB;
    const int tid = threadIdx.x;
    const int f = tid;

    if (tid < RCB) {
        int a = a0 + tid / NB;
        int b = (a < A_TOT) ? a2b[a * NB + (tid % NB)] : 0;
        int rp = b2revb[b];
        b_[tid] = b; rp_[tid] = rp;
        p1_[tid] = b2a[rp]; q1_[tid] = b2revb[rp]; p2_[tid] = b2a[b];
    }
    __syncthreads();
    for (int idx = tid; idx < RCB * 75; idx += 320) {
        int i = idx / 75, k4 = idx - i * 75;
        ((float4*)u[i])[k4] = ((const float4*)(msgA1 + (size_t)p1_[i] * H))[k4];
        ((float4*)w[i])[k4] = ((const float4*)(msgA2 + (size_t)p2_[i] * H))[k4];
    }
    for (int idx = tid; idx < RCB * BF; idx += 320) {
        int i = idx / BF, k = idx - i * BF;
        fbl[i][k] = f_bonds[(size_t)q1_[i] * BF + k];
    }
    for (int idx = tid; idx < GCB * 75; idx += 320) {
        int l = idx / 75, k4 = idx - l * 75;
        int a = a0 + l;
        ((float4*)mA2r[l])[k4] = (a < A_TOT) ? ((const float4*)(msgA2 + (size_t)a * H))[k4]
                                             : make_float4(0.f, 0.f, 0.f, 0.f);
    }
    for (int idx = tid; idx < GCB * AF; idx += 320) {
        int l = idx / AF, k = idx - l * AF;
        int a = a0 + l;
        fa[l][k] = (a < A_TOT) ? f_atoms[(size_t)a * AF + k] : 0.f;
    }
    __syncthreads();
    if (f < H) {
        float acc[RCB];
#pragma unroll
        for (int i = 0; i < RCB; ++i) acc[i] = 0.f;
        gemv4<RCB, 152>(fbl, Wi_bond, BF, f, acc);
#pragma unroll
        for (int i = 0; i < RCB; ++i) u[i][f] -= fmaxf(acc[i], 0.f);
    }
    __syncthreads();
    for (int idx = tid; idx < RCB * BF; idx += 320) {
        int i = idx / BF, k = idx - i * BF;
        fbl[i][k] = f_bonds[(size_t)rp_[i] * BF + k];
    }
    __syncthreads();
    if (f < H) {
        float accm[RCB], accr[RCB];
#pragma unroll
        for (int i = 0; i < RCB; ++i) { accm[i] = 0.f; accr[i] = 0.f; }
        gemv4<RCB, 304>(u, Wh0, H, f, accm);
        gemv4<RCB, 152>(fbl, Wi_bond, BF, f, accr);
#pragma unroll
        for (int i = 0; i < RCB; ++i)
            w[i][f] -= fmaxf(fmaxf(accr[i], 0.f) + accm[i], 0.f);
    }
    __syncthreads();
    for (int idx = tid; idx < RCB * BF; idx += 320) {
        int i = idx / BF, k = idx - i * BF;
        fbl[i][k] = f_bonds[(size_t)b_[i] * BF + k];
    }
    __syncthreads();
    if (f < H) {
        float accm[RCB], accb[RCB];
#pragma unroll
        for (int i = 0; i < RCB; ++i) { accm[i] = 0.f; accb[i] = 0.f; }
        gemv4<RCB, 304>(w, Wh1, H, f, accm);
        gemv4<RCB, 152>(fbl, Wi_bond, BF, f, accb);
#pragma unroll
        for (int l = 0; l < GCB; ++l) {
            float s = 0.f, mx = -INFINITY;
#pragma unroll
            for (int j = 0; j < NB; ++j) {
                int i = l * NB + j;
                float m2 = fmaxf(fmaxf(accb[i], 0.f) + accm[i], 0.f);
                s += m2; mx = fmaxf(mx, m2);
            }
            agg3r[l][f] = s * mx;
        }
        float acc2[GCB];
#pragma unroll
        for (int l = 0; l < GCB; ++l) acc2[l] = 0.f;
        gemv4<GCB, 136>(fa, Wi_atom, AF, f, acc2);
#pragma unroll
        for (int l = 0; l < GCB; ++l) inAr[l][f] = fmaxf(acc2[l], 0.f);
    }
    __syncthreads();
    if (f < H) {
        float accL[GCB];
#pragma unroll
        for (int l = 0; l < GCB; ++l) accL[l] = 0.f;
        gemv4<GCB, 304>(agg3r, W_lr,            H, f, accL);
        gemv4<GCB, 304>(mA2r, W_lr + 300 * 300, H, f, accL);
        gemv4<GCB, 304>(inAr, W_lr + 600 * 300, H, f, accL);
#pragma unroll
        for (int l = 0; l < GCB; ++l) {
            int a = a0 + l;
            if (a < A_TOT) aggL[(size_t)a * H + f] = accL[l];
        }
    }
}

// ===========================================================================
// Pack 4 [900,300] GRU weight mats -> P[k/4][gate][f][k%4]  (270000 each)
// ===========================================================================
__global__ __launch_bounds__(256) void k_pack4(
    const float* __restrict__ s0, const float* __restrict__ s1,
    const float* __restrict__ s2, const float* __restrict__ s3,
    float* __restrict__ d0, float* __restrict__ d1,
    float* __restrict__ d2, float* __restrict__ d3)
{
    const float* S[4] = {s0, s1, s2, s3};
    float* D[4] = {d0, d1, d2, d3};
    int z = blockIdx.y;
    int o = blockIdx.x * 256 + threadIdx.x;
    if (o < 270000) {
        int k4 = o / 3600; int rem = o - k4 * 3600;
        int g = rem / 1200; int rem2 = rem - g * 1200;
        int fx = rem2 >> 2; int kk = rem2 & 3;
        int k = k4 * 4 + kk;
        D[z][o] = S[z][(size_t)(g * 300 + fx) * 300 + k];
    }
}

// ===========================================================================
// prep: h0[m] = max_t aggL[1+m*40+t]; then aggL row <- relu(row + gru_bias)
// ===========================================================================
__global__ __launch_bounds__(256) void prep_kernel(
    float* aggL, const float* __restrict__ gru_bias, float* __restrict__ h0)
{
    int m = blockIdx.x;
    for (int f = threadIdx.x; f < H; f += 256) {
        float b = gru_bias[f];
        float mx = -INFINITY;
        for (int t = 0; t < ASZ; ++t) {
            size_t o = (size_t)(1 + m * ASZ + t) * H + f;
            float v = aggL[o];
            mx = fmaxf(mx, v);
            aggL[o] = fmaxf(v + b, 0.f);
        }
        h0[(size_t)m * H + f] = mx;
    }
}

__device__ __forceinline__ float dev_sigmoid(float x) {
    return 1.f / (1.f + __expf(-x));
}
__device__ __forceinline__ float dev_tanh(float x) {
    return 1.f - 2.f / (__expf(2.f * x) + 1.f);
}

// ===========================================================================
// Persistent GRU, v3 (R3-verified).
// ===========================================================================
#define GM 8
__global__ __launch_bounds__(320) void k_gru_all(
    const float* __restrict__ msg,
    const float* __restrict__ Pih_f, const float* __restrict__ Phh_f,
    const float* __restrict__ bih_f, const float* __restrict__ bhh_f,
    const float* __restrict__ Pih_b, const float* __restrict__ Phh_b,
    const float* __restrict__ bih_b, const float* __restrict__ bhh_b,
    const float* __restrict__ h0, float* __restrict__ out_f,
    float* __restrict__ out_b)
{
    __shared__ __align__(16) float hs[GM][304];
    __shared__ __align__(16) float ms[2][GM][304];

    const int bid  = blockIdx.x;
    const int xcd  = bid & 7;
    const int slot = bid >> 3;
    const int dir  = xcd >> 2;
    const int lg   = (xcd & 3) * 32 + slot;
    const int m0   = lg * GM;
    if (m0 >= NMOL) return;

    const float* Pih = dir ? Pih_b : Pih_f;
    const float* Phh = dir ? Phh_b : Phh_f;
    const float* bih = dir ? bih_b : bih_f;
    const float* bhh = dir ? bhh_b : bhh_f;
    float* out       = dir ? out_b : out_f;

    const int tid  = threadIdx.x;
    const bool act = tid < H;
    const int f    = act ? tid : (H - 1);

    for (int idx = tid; idx < GM * 75; idx += 320) {
        int i = idx / 75, k4 = idx - i * 75;
        int m = m0 + i;
        ((float4*)hs[i])[k4] = (m < NMOL) ? ((const float4*)(h0 + (size_t)m * H))[k4]
                                          : make_float4(0.f, 0.f, 0.f, 0.f);
    }
    {
        const int t0 = dir ? (ASZ - 1) : 0;
        for (int idx = tid; idx < GM * 75; idx += 320) {
            int i = idx / 75, k4 = idx - i * 75;
            int m = m0 + i;
            ((float4*)ms[0][i])[k4] = (m < NMOL)
                ? ((const float4*)(msg + (size_t)(m * ASZ + t0) * H))[k4]
                : make_float4(0.f, 0.f, 0.f, 0.f);
        }
    }

    float bR = 0.f, bZ = 0.f, bIN = 0.f, bHN = 0.f;
    if (act) {
        bR  = bih[f] + bhh[f];
        bZ  = bih[300 + f] + bhh[300 + f];
        bIN = bih[600 + f];
        bHN = bhh[600 + f];
    }
    const float* pi = Pih + (size_t)f * 4;
    const float* ph = Phh + (size_t)f * 4;

    for (int s = 0; s < ASZ; ++s) {
        const int cur = s & 1;
        const int t = dir ? (ASZ - 1 - s) : s;
        __syncthreads();

        float4 st0 = make_float4(0.f, 0.f, 0.f, 0.f);
        float4 st1 = make_float4(0.f, 0.f, 0.f, 0.f);
        const bool more = (s + 1 < ASZ);
        if (more) {
            const int tn = dir ? (ASZ - 2 - s) : (s + 1);
            {
                int i = tid / 75, k4 = tid - i * 75;
                int m = m0 + i;
                if (m < NMOL)
                    st0 = ((const float4*)(msg + (size_t)(m * ASZ + tn) * H))[k4];
            }
            {
                int idx = tid + 320;
                if (idx < GM * 75) {
                    int i = idx / 75, k4 = idx - i * 75;
                    int m = m0 + i;
                    if (m < NMOL)
                        st1 = ((const float4*)(msg + (size_t)(m * ASZ + tn) * H))[k4];
                }
            }
        }

        float aR[GM], aZ[GM], aIN[GM], aHN[GM];
#pragma unroll
        for (int i = 0; i < GM; ++i) { aR[i] = 0.f; aZ[i] = 0.f; aIN[i] = 0.f; aHN[i] = 0.f; }

        float4 wiR = *(const float4*)(pi);
        float4 wiZ = *(const float4*)(pi + 1200);
        float4 wiN = *(const float4*)(pi + 2400);
        float4 whR = *(const float4*)(ph);
        float4 whZ = *(const float4*)(ph + 1200);
        float4 whN = *(const float4*)(ph + 2400);

        for (int k4i = 0; k4i < 75; ++k4i) {
            const int kn = k4i + (k4i < 74 ? 1 : 0);
            const float* pin = pi + (size_t)kn * 3600;
            const float* phn = ph + (size_t)kn * 3600;
            float4 nR = *(const float4*)(pin);
            float4 nZ = *(const float4*)(pin + 1200);
            float4 nN = *(const float4*)(pin + 2400);
            float4 oR = *(const float4*)(phn);
            float4 oZ = *(const float4*)(phn + 1200);
            float4 oN = *(const float4*)(phn + 2400);

            const int k4 = k4i * 4;
#pragma unroll
            for (int i = 0; i < GM; ++i) {
                float4 m4 = *(const float4*)&ms[cur][i][k4];
                float4 h4 = *(const float4*)&hs[i][k4];
                aR[i]  = fmaf(m4.x, wiR.x, fmaf(m4.y, wiR.y, fmaf(m4.z, wiR.z, fmaf(m4.w, wiR.w, aR[i]))));
                aR[i]  = fmaf(h4.x, whR.x, fmaf(h4.y, whR.y, fmaf(h4.z, whR.z, fmaf(h4.w, whR.w, aR[i]))));
                aZ[i]  = fmaf(m4.x, wiZ.x, fmaf(m4.y, wiZ.y, fmaf(m4.z, wiZ.z, fmaf(m4.w, wiZ.w, aZ[i]))));
                aZ[i]  = fmaf(h4.x, whZ.x, fmaf(h4.y, whZ.y, fmaf(h4.z, whZ.z, fmaf(h4.w, whZ.w, aZ[i]))));
                aIN[i] = fmaf(m4.x, wiN.x, fmaf(m4.y, wiN.y, fmaf(m4.z, wiN.z, fmaf(m4.w, wiN.w, aIN[i]))));
                aHN[i] = fmaf(h4.x, whN.x, fmaf(h4.y, whN.y, fmaf(h4.z, whN.z, fmaf(h4.w, whN.w, aHN[i]))));
            }
            wiR = nR; wiZ = nZ; wiN = nN;
            whR = oR; whZ = oZ; whN = oN;
        }
        __syncthreads();

        if (act) {
#pragma unroll
            for (int i = 0; i < GM; ++i) {
                int m = m0 + i;
                if (m < NMOL) {
                    float r = dev_sigmoid(aR[i] + bR);
                    float z = dev_sigmoid(aZ[i] + bZ);
                    float n = dev_tanh(aIN[i] + bIN + r * (aHN[i] + bHN));
                    float hn = (1.f - z) * n + z * hs[i][f];
                    hs[i][f] = hn;
                    __builtin_nontemporal_store(hn, out + (size_t)(m * ASZ + t) * H + f);
                }
            }
        }
        if (more) {
            const int nxt = cur ^ 1;
            {
                int i = tid / 75, k4 = tid - i * 75;
                ((float4*)ms[nxt][i])[k4] = st0;
            }
            {
                int idx = tid + 320;
                if (idx < GM * 75) {
                    int i = idx / 75, k4 = idx - i * 75;
                    ((float4*)ms[nxt][i])[k4] = st1;
                }
            }
        }
    }
}

// ===========================================================================
// Fused output projection: hid = relu([outf|outb] @ W_o + b_o), K=600.
// ===========================================================================
__global__ __launch_bounds__(256) void gemm_wo(
    const float* __restrict__ A0, const float* __restrict__ A1,
    const float* __restrict__ W, float* __restrict__ C,
    const float* __restrict__ bias)
{
    const int M = NMOL * ASZ, K2 = 600, N = H;
    __shared__ float As[16][64];
    __shared__ float Bs[16][64];
    const int tx = threadIdx.x, ty = threadIdx.y;
    const int tid = ty * 16 + tx;
    const int m0 = blockIdx.x * 64, n0 = blockIdx.y * 64;
    const int am = tid >> 2, ak = (tid & 3) * 4;
    const int bk = tid >> 4, bn = (tid & 15) * 4;
    const int arow = m0 + am;

    float acc[4][4];
#pragma unroll
    for (int i = 0; i < 4; ++i)
#pragma unroll
        for (int j = 0; j < 4; ++j) acc[i][j] = 0.f;

    for (int k0 = 0; k0 < K2; k0 += 16) {
#pragma unroll
        for (int j = 0; j < 4; ++j) {
            int k = k0 + ak + j;
            float v = 0.f;
            if (arow < M && k < K2)
                v = (k < 300) ? A0[(size_t)arow * 300 + k]
                              : A1[(size_t)arow * 300 + (k - 300)];
            As[ak + j][am] = v;
        }
#pragma unroll
        for (int j = 0; j < 4; ++j) {
            int k = k0 + bk, n = n0 + bn + j;
            Bs[bk][bn + j] = (k < K2 && n < N) ? W[(size_t)k * N + n] : 0.f;
        }
        __syncthreads();
#pragma unroll
        for (int kk = 0; kk < 16; ++kk) {
            float4 av = *(const float4*)&As[kk][ty * 4];
            float4 bv = *(const float4*)&Bs[kk][tx * 4];
            float a4[4] = {av.x, av.y, av.z, av.w};
            float b4[4] = {bv.x, bv.y, bv.z, bv.w};
#pragma unroll
            for (int i = 0; i < 4; ++i)
#pragma unroll
                for (int j = 0; j < 4; ++j)
                    acc[i][j] = fmaf(a4[i], b4[j], acc[i][j]);
        }
        __syncthreads();
    }
#pragma unroll
    for (int i = 0; i < 4; ++i) {
        int m = m0 + ty * 4 + i;
        if (m >= M) continue;
#pragma unroll
        for (int j = 0; j < 4; ++j) {
            int n = n0 + tx * 4 + j;
            if (n >= N) continue;
            C[(size_t)m * N + n] = fmaxf(acc[i][j] + bias[n], 0.f);
        }
    }
}

__global__ __launch_bounds__(256) void mean_kernel(
    const float* __restrict__ hid, float* __restrict__ out)
{
    int m = blockIdx.x;
    for (int f = threadIdx.x; f < H; f += 256) {
        float s = 0.f;
        for (int t = 0; t < ASZ; ++t)
            s += hid[(size_t)(m * ASZ + t) * H + f];
        out[(size_t)m * H + f] = s * (1.f / 40.f);
    }
}

// ===========================================================================
extern "C" void kernel_launch(void* const* d_in, const int* in_sizes, int n_in,
                              void* d_out, int out_size, void* d_ws, size_t ws_size,
                              hipStream_t stream)
{
    const float* f_atoms  = (const float*)d_in[0];
    const float* f_bonds  = (const float*)d_in[1];
    const float* Wi_atom  = (const float*)d_in[2];
    const float* Wi_bond  = (const float*)d_in[3];
    const float* Wh0      = (const float*)d_in[4];
    const float* Wh1      = (const float*)d_in[5];
    const float* W_lr     = (const float*)d_in[6];
    const float* W_o      = (const float*)d_in[7];
    const float* b_o      = (const float*)d_in[8];
    const float* gru_bias = (const float*)d_in[9];
    const float* gWih_f   = (const float*)d_in[10];
    const float* gWhh_f   = (const float*)d_in[11];
    const float* gbih_f   = (const float*)d_in[12];
    const float* gbhh_f   = (const float*)d_in[13];
    const float* gWih_b   = (const float*)d_in[14];
    const float* gWhh_b   = (const float*)d_in[15];
    const float* gbih_b   = (const float*)d_in[16];
    const float* gbhh_b   = (const float*)d_in[17];
    const int*   a2b      = (const int*)d_in[18];
    const int*   b2a      = (const int*)d_in[19];
    const int*   b2revb   = (const int*)d_in[20];

    char* wsb = (char*)d_ws;
    const bool bigws = (ws_size >= (size_t)288003600);

    // Pack MP weights into d_out scratch (dead until mean_kernel overwrites it)
    float* dscratch = (float*)d_out;
    {
        dim3 g((90000 + 255) / 256, 4);
        k_packmp<<<g, 256, 0, stream>>>(Wh0, Wh1, Wi_bond, Wi_atom, dscratch);
    }
    const float4* PWh0 = (const float4*)(dscratch + PK_WH0);
    const float4* PWh1 = (const float4*)(dscratch + PK_WH1);
    const float4* PWib = (const float4*)(dscratch + PK_WIB);
    const float4* PWia = (const float4*)(dscratch + PK_WIA);

    float *aggLp, *outfp, *outbp, *h0p, *P0, *P1, *P2, *P3, *hidp;

    if (bigws) {
        // PATH A: fp32 m1 materialization.  Peak = 288,003,600 B.
        float* msgA = (float*)wsb;
        float* aggL = (float*)(wsb + 48001200);
        float* m1   = (float*)(wsb + 96002400);
        outfp = (float*)(wsb + 96002400);
        outbp = (float*)(wsb + 144002400);
        P0 = (float*)(wsb + 192002400);
        P1 = P0 + 270000; P2 = P1 + 270000; P3 = P2 + 270000;
        h0p = (float*)(wsb + 196322400);
        aggLp = aggL; hidp = msgA;

        k_msga1<<<(A_TOT + GA - 1) / GA, 320, 0, stream>>>(
            f_atoms, f_bonds, PWia, PWib, a2b, msgA);
        k_m1f<<<(BN_TOT + NR2 - 1) / NR2, 320, 0, stream>>>(
            f_bonds, PWib, PWh0, msgA, b2a, b2revb, m1);
        k_msga2ef<<<(A_TOT * H + 255) / 256, 256, 0, stream>>>(m1, a2b, msgA);
        k_aggl2f<<<(A_TOT + GC - 1) / GC, 192, 0, stream>>>(
            f_atoms, f_bonds, PWia, PWib, PWh1, W_lr,
            msgA, m1, a2b, b2a, b2revb, aggL);
    } else {
        // PATH B: recompute path (no m1 buffer).  Peak = 240,003,600 B.
        float* ws = (float*)d_ws;
        float* msgA1 = ws;
        float* msgA2 = ws + 12000300;
        float* aggL  = ws + 24000600;
        outfp = ws + 36000900;
        outbp = ws + 48000900;
        h0p   = ws;
        P0 = ws + 300000; P1 = ws + 570000; P2 = ws + 840000; P3 = ws + 1110000;
        aggLp = aggL; hidp = msgA2;

        k_msga1<<<(A_TOT + GA - 1) / GA, 320, 0, stream>>>(
            f_atoms, f_bonds, PWia, PWib, a2b, msgA1);
        k_msga2b<<<(A_TOT + GB - 1) / GB, 320, 0, stream>>>(
            f_bonds, Wi_bond, Wh0, msgA1, msgA2, a2b, b2a, b2revb);
        k_agglb<<<(A_TOT + GCB - 1) / GCB, 320, 0, stream>>>(
            f_atoms, f_bonds, Wi_atom, Wi_bond, Wh0, Wh1, W_lr,
            msgA1, msgA2, a2b, b2a, b2revb, aggL);
    }

    // pack GRU weights (into regions dead after the MP phase)
    {
        dim3 g((270000 + 255) / 256, 4);
        k_pack4<<<g, 256, 0, stream>>>(gWih_f, gWhh_f, gWih_b, gWhh_b,
                                       P0, P1, P2, P3);
    }

    // h0 + in-place relu(aggL + bias)
    prep_kernel<<<NMOL, 256, 0, stream>>>(aggLp, gru_bias, h0p);

    // persistent GRU v3: 256 1D blocks x 320 threads, XCD-partitioned by dir
    k_gru_all<<<256, 320, 0, stream>>>(
        aggLp + H, P0, P1, gbih_f, gbhh_f, P2, P3, gbih_b, gbhh_b,
        h0p, outfp, outbp);

    // hid = relu([outf|outb]@W_o + b_o)
    {
        dim3 grid((NMOL * ASZ + 63) / 64, (H + 63) / 64);
        dim3 block(16, 16);
        gemm_wo<<<grid, block, 0, stream>>>(outfp, outbp, W_o, hidp, b_o);
    }

    // per-mol mean -> d_out (overwrites the weight-pack scratch)
    mean_kernel<<<NMOL, 256, 0, stream>>>(hidp, (float*)d_out);
}

// Round 11
// 7048.409 us; speedup vs baseline: 1.6395x; 1.0181x over previous
//
#include <hip/hip_runtime.h>
#include <math.h>

constexpr int A_TOT  = 40001;
constexpr int NB     = 6;
constexpr int BN_TOT = 160001;
constexpr int AF     = 133;
constexpr int BF     = 147;
constexpr int H      = 300;
constexpr int NMOL   = 1000;
constexpr int ASZ    = 40;

// Packed-weight layout: P[(k4*300+f)*4+j] = W[(k4*4+j)*300+f], zero-padded.
// Packs live in d_out scratch (dead until mean_kernel).
constexpr int PK_WH0 = 0;
constexpr int PK_WH1 = 90000;
constexpr int PK_WIB = 180000;
constexpr int PK_WIA = 224400;

// ---------------------------------------------------------------------------
// Raw GEMV core (W_lr and PATH B).
// ---------------------------------------------------------------------------
template<int NR, int P>
__device__ __forceinline__ void gemv4(const float (*rows)[P], const float* __restrict__ W,
                                      int K, int f, float* __restrict__ acc)
{
    int k4 = 0;
    for (; k4 + 4 <= K; k4 += 4) {
        float w0 = W[(k4 + 0) * H + f];
        float w1 = W[(k4 + 1) * H + f];
        float w2 = W[(k4 + 2) * H + f];
        float w3 = W[(k4 + 3) * H + f];
#pragma unroll
        for (int i = 0; i < NR; ++i) {
            float4 b = *(const float4*)&rows[i][k4];
            acc[i] = fmaf(b.x, w0, fmaf(b.y, w1, fmaf(b.z, w2, fmaf(b.w, w3, acc[i]))));
        }
    }
    for (; k4 < K; ++k4) {
        float wv = W[k4 * H + f];
#pragma unroll
        for (int i = 0; i < NR; ++i) acc[i] = fmaf(rows[i][k4], wv, acc[i]);
    }
}

// ---------------------------------------------------------------------------
// Packed GEMV core: one float4 weight load per k4. Rows zero-padded in LDS.
// k4i loop MUST stay rolled (R6: full unroll -> 128-VGPR cap spill).
// AMORTIZATION RULE (R7): rows-per-weight-load dominates; NR=12 > NR=6.
// ---------------------------------------------------------------------------
template<int NR, int P>
__device__ __forceinline__ void gemv4p(const float (*rows)[P], const float4* __restrict__ Pw,
                                       int K4, int f, float* __restrict__ acc)
{
#pragma clang loop unroll(disable)
    for (int k4i = 0; k4i < K4; ++k4i) {
        float4 w = Pw[k4i * 300 + f];
#pragma unroll
        for (int i = 0; i < NR; ++i) {
            float4 b = *(const float4*)&rows[i][k4i * 4];
            acc[i] = fmaf(b.x, w.x, fmaf(b.y, w.y, fmaf(b.z, w.z, fmaf(b.w, w.w, acc[i]))));
        }
    }
}

// ===========================================================================
// Pack Wh0/Wh1/Wi_bond/Wi_atom into d_out scratch.
// ===========================================================================
__global__ __launch_bounds__(256) void k_packmp(
    const float* __restrict__ s0, const float* __restrict__ s1,
    const float* __restrict__ s2, const float* __restrict__ s3,
    float* __restrict__ dout)
{
    const float* S[4] = {s0, s1, s2, s3};
    const int Ks[4]  = {300, 300, 147, 133};
    const int K4s[4] = {75, 75, 37, 34};
    const int off[4] = {PK_WH0, PK_WH1, PK_WIB, PK_WIA};
    int z = blockIdx.y;
    int o = blockIdx.x * 256 + threadIdx.x;
    int n = K4s[z] * 1200;
    if (o < n) {
        int k4 = o / 1200; int rem = o - k4 * 1200;
        int f = rem >> 2;  int j = rem & 3;
        int k = k4 * 4 + j;
        dout[off[z] + o] = (k < Ks[z]) ? S[z][(size_t)k * 300 + f] : 0.f;
    }
}

// ===========================================================================
// Row-staged GEMM: dst[M,300] = src[M,300] @ Wh1 (packed).  SAFE FOR
// dst == src: each block owns RG rows, stages them fully in LDS before any
// write, and no block touches another block's rows.  (R10 bug: the tiled
// gemm_nn had 5 n-blocks per row-group -> cross-block read/write race.)
// ===========================================================================
#define RG 16
__global__ __launch_bounds__(320) void k_gemm_rp(
    const float* __restrict__ src, float* __restrict__ dst,
    const float4* __restrict__ Pw, int M)
{
    __shared__ __align__(16) float rows[RG][304];
    const int r0 = blockIdx.x * RG;
    const int tid = threadIdx.x;
    const int f = tid;

    for (int idx = tid; idx < RG * 75; idx += 320) {
        int i = idx / 75, k4 = idx - i * 75;
        int r = r0 + i;
        ((float4*)rows[i])[k4] = (r < M) ? ((const float4*)(src + (size_t)r * H))[k4]
                                         : make_float4(0.f, 0.f, 0.f, 0.f);
    }
    __syncthreads();
    if (f < H) {
        float acc[RG];
#pragma unroll
        for (int i = 0; i < RG; ++i) acc[i] = 0.f;
        gemv4p<RG, 304>(rows, Pw, 75, f, acc);
#pragma unroll
        for (int i = 0; i < RG; ++i) {
            int r = r0 + i;
            if (r < M) dst[(size_t)r * H + f] = acc[i];
        }
    }
}

// ===========================================================================
// K1: msgA1[a,:] = relu(f_atoms[a]@Wi_atom) + sum*max of x_b.
// Chunked bond GEMV (NR=6) + rolled k4i loop.
// ===========================================================================
#define GA 4
__global__ __launch_bounds__(320) void k_msga1(
    const float* __restrict__ f_atoms, const float* __restrict__ f_bonds,
    const float4* __restrict__ PWia, const float4* __restrict__ PWib,
    const int* __restrict__ a2b, float* __restrict__ msgA1)
{
    __shared__ __align__(16) float fb[GA * NB][152];
    __shared__ __align__(16) float fa[GA][136];
    __shared__ int bidx[GA * NB];

    const int a0 = blockIdx.x * GA;
    const int tid = threadIdx.x;
    const int f = tid;

    if (tid < GA * NB) {
        int a = a0 + tid / NB;
        bidx[tid] = (a < A_TOT) ? a2b[a * NB + (tid % NB)] : 0;
    }
    __syncthreads();
    for (int idx = tid; idx < GA * NB * 148; idx += 320) {
        int i = idx / 148, k = idx - i * 148;
        fb[i][k] = (k < BF) ? f_bonds[(size_t)bidx[i] * BF + k] : 0.f;
    }
    for (int idx = tid; idx < GA * 136; idx += 320) {
        int l = idx / 136, k = idx - l * 136;
        int a = a0 + l;
        fa[l][k] = (a < A_TOT && k < AF) ? f_atoms[(size_t)a * AF + k] : 0.f;
    }
    __syncthreads();

    if (f < H) {
        float part[GA];
#pragma unroll
        for (int l = 0; l < GA; ++l) {
            float acc[NB];
#pragma unroll
            for (int j = 0; j < NB; ++j) acc[j] = 0.f;
            gemv4p<NB, 152>((const float (*)[152])&fb[l * NB], PWib, 37, f, acc);
            float s = 0.f, mx = -INFINITY;
#pragma unroll
            for (int j = 0; j < NB; ++j) {
                float x = fmaxf(acc[j], 0.f);
                s += x; mx = fmaxf(mx, x);
            }
            part[l] = s * mx;
        }
        float acc2[GA];
#pragma unroll
        for (int l = 0; l < GA; ++l) acc2[l] = 0.f;
        gemv4p<GA, 136>(fa, PWia, 34, f, acc2);
#pragma unroll
        for (int l = 0; l < GA; ++l) {
            int a = a0 + l;
            if (a < A_TOT) msgA1[(size_t)a * H + f] = fmaxf(acc2[l], 0.f) + part[l];
        }
    }
}

// ===========================================================================
// PATH A: m1 fp32 materialization.  NR2=8, rolled gemv loops.
// ===========================================================================
#define NR2 8
__global__ __launch_bounds__(320) void k_m1f(
    const float* __restrict__ f_bonds, const float4* __restrict__ PWib,
    const float4* __restrict__ PWh0, const float* __restrict__ msgA1,
    const int* __restrict__ b2a, const int* __restrict__ b2revb,
    float* __restrict__ m1)
{
    __shared__ __align__(16) float v[NR2][304];
    __shared__ __align__(16) float fbl[NR2][152];
    __shared__ int r_[NR2], q_[NR2], p_[NR2];

    const int r0 = blockIdx.x * NR2;
    const int tid = threadIdx.x;
    const int f = tid;

    if (tid < NR2) {
        int r = r0 + tid;
        if (r >= BN_TOT) r = 0;
        r_[tid] = r;
        q_[tid] = b2revb[r];
        p_[tid] = b2a[r];
    }
    __syncthreads();
    for (int idx = tid; idx < NR2 * 75; idx += 320) {
        int i = idx / 75, k4 = idx - i * 75;
        ((float4*)v[i])[k4] = ((const float4*)(msgA1 + (size_t)p_[i] * H))[k4];
    }
    for (int idx = tid; idx < NR2 * 148; idx += 320) {
        int i = idx / 148, k = idx - i * 148;
        fbl[i][k] = (k < BF) ? f_bonds[(size_t)q_[i] * BF + k] : 0.f;
    }
    __syncthreads();
    if (f < H) {
        float acc[NR2];
#pragma unroll
        for (int i = 0; i < NR2; ++i) acc[i] = 0.f;
        gemv4p<NR2, 152>(fbl, PWib, 37, f, acc);
#pragma unroll
        for (int i = 0; i < NR2; ++i) v[i][f] -= fmaxf(acc[i], 0.f);
    }
    __syncthreads();
    for (int idx = tid; idx < NR2 * 148; idx += 320) {
        int i = idx / 148, k = idx - i * 148;
        fbl[i][k] = (k < BF) ? f_bonds[(size_t)r_[i] * BF + k] : 0.f;
    }
    float accm[NR2];
#pragma unroll
    for (int i = 0; i < NR2; ++i) accm[i] = 0.f;
    if (f < H) gemv4p<NR2, 304>(v, PWh0, 75, f, accm);
    __syncthreads();
    if (f < H) {
        float accr[NR2];
#pragma unroll
        for (int i = 0; i < NR2; ++i) accr[i] = 0.f;
        gemv4p<NR2, 152>(fbl, PWib, 37, f, accr);
#pragma unroll
        for (int i = 0; i < NR2; ++i) {
            int r = r0 + i;
            if (r < BN_TOT)
                m1[(size_t)r * H + f] = fmaxf(fmaxf(accr[i], 0.f) + accm[i], 0.f);
        }
    }
}

__global__ __launch_bounds__(256) void k_msga2ef(
    const float* __restrict__ m1, const int* __restrict__ a2b, float* msgA)
{
    int idx = blockIdx.x * 256 + threadIdx.x;
    if (idx >= A_TOT * H) return;
    int a = idx / H;
    int f = idx - a * H;
    float s = 0.f, mx = -INFINITY;
#pragma unroll
    for (int j = 0; j < NB; ++j) {
        int r = a2b[a * NB + j];
        float v = m1[(size_t)r * H + f];
        s += v;
        mx = fmaxf(mx, v);
    }
    msgA[idx] += s * mx;
}

// ===========================================================================
// aggl3 (R10/R11): Wh1 gemv eliminated via linearity — m2 = relu(x_b +
// A2W[p2] - M1W[rp]) with A2W = msgA2@Wh1, M1W = m1@Wh1 (k_gemm_rp).
// Writes aggL over msgA[a] (own-row only; cross-row msgA consumption is
// pre-materialized in A2W — race-free).  R8-proven 320-thread GC=2 layout.
// ===========================================================================
#define GC 2
#define RC (GC * NB)   // 12
__global__ __launch_bounds__(320) void k_aggl3f(
    const float* __restrict__ f_atoms, const float* __restrict__ f_bonds,
    const float4* __restrict__ PWia, const float4* __restrict__ PWib,
    const float* __restrict__ A2W, const float* __restrict__ M1W,
    const float* __restrict__ W_lr, const float* __restrict__ msgA2,
    const int* __restrict__ a2b, const int* __restrict__ b2a,
    const int* __restrict__ b2revb, float* __restrict__ aggLout)
{
    __shared__ __align__(16) float w[RC][304];
    __shared__ __align__(16) float fbl[RC][152];
    __shared__ __align__(16) float agg3r[GC][304];
    __shared__ __align__(16) float mA2r[GC][304];
    __shared__ __align__(16) float inAr[GC][304];
    __shared__ __align__(16) float fa[GC][136];
    __shared__ int b_[RC], rp_[RC], p2_[RC];

    const int a0 = blockIdx.x * GC;
    const int tid = threadIdx.x;
    const int f = tid;

    if (tid < RC) {
        int a = a0 + tid / NB;
        int b = (a < A_TOT) ? a2b[a * NB + (tid % NB)] : 0;
        b_[tid] = b;
        rp_[tid] = b2revb[b];
        p2_[tid] = b2a[b];
    }
    __syncthreads();
    for (int idx = tid; idx < RC * 75; idx += 320) {
        int i = idx / 75, k4 = idx - i * 75;
        float4 a4 = ((const float4*)(A2W + (size_t)p2_[i] * H))[k4];
        float4 b4 = ((const float4*)(M1W + (size_t)rp_[i] * H))[k4];
        ((float4*)w[i])[k4] = make_float4(a4.x - b4.x, a4.y - b4.y, a4.z - b4.z, a4.w - b4.w);
    }
    for (int idx = tid; idx < RC * 148; idx += 320) {
        int i = idx / 148, k = idx - i * 148;
        fbl[i][k] = (k < BF) ? f_bonds[(size_t)b_[i] * BF + k] : 0.f;
    }
    for (int idx = tid; idx < GC * 75; idx += 320) {
        int l = idx / 75, k4 = idx - l * 75;
        int a = a0 + l;
        ((float4*)mA2r[l])[k4] = (a < A_TOT) ? ((const float4*)(msgA2 + (size_t)a * H))[k4]
                                             : make_float4(0.f, 0.f, 0.f, 0.f);
    }
    for (int idx = tid; idx < GC * 136; idx += 320) {
        int l = idx / 136, k = idx - l * 136;
        int a = a0 + l;
        fa[l][k] = (a < A_TOT && k < AF) ? f_atoms[(size_t)a * AF + k] : 0.f;
    }
    __syncthreads();

    if (f < H) {
        float accb[RC];
#pragma unroll
        for (int i = 0; i < RC; ++i) accb[i] = 0.f;
        gemv4p<RC, 152>(fbl, PWib, 37, f, accb);
#pragma unroll
        for (int l = 0; l < GC; ++l) {
            float s = 0.f, mx = -INFINITY;
#pragma unroll
            for (int j = 0; j < NB; ++j) {
                int i = l * NB + j;
                float m2 = fmaxf(fmaxf(accb[i], 0.f) + w[i][f], 0.f);
                s += m2; mx = fmaxf(mx, m2);
            }
            agg3r[l][f] = s * mx;
        }
        float acc2[GC];
#pragma unroll
        for (int l = 0; l < GC; ++l) acc2[l] = 0.f;
        gemv4p<GC, 136>(fa, PWia, 34, f, acc2);
#pragma unroll
        for (int l = 0; l < GC; ++l) inAr[l][f] = fmaxf(acc2[l], 0.f);
    }
    __syncthreads();

    if (f < H) {
        float accL[GC];
#pragma unroll
        for (int l = 0; l < GC; ++l) accL[l] = 0.f;
        gemv4<GC, 304>(agg3r, W_lr,            H, f, accL);
        gemv4<GC, 304>(mA2r, W_lr + 300 * 300, H, f, accL);
        gemv4<GC, 304>(inAr, W_lr + 600 * 300, H, f, accL);
#pragma unroll
        for (int l = 0; l < GC; ++l) {
            int a = a0 + l;
            if (a < A_TOT) aggLout[(size_t)a * H + f] = accL[l];
        }
    }
}

// ===========================================================================
// PATH B kernels (not exercised when bigws) — unchanged.
// ===========================================================================
#define GB 4
#define RB (GB * NB)   // 24
__global__ __launch_bounds__(320) void k_msga2b(
    const float* __restrict__ f_bonds, const float* __restrict__ Wi_bond,
    const float* __restrict__ Wh0,
    const float* __restrict__ msgA1, float* __restrict__ msgA2,
    const int* __restrict__ a2b, const int* __restrict__ b2a,
    const int* __restrict__ b2revb)
{
    __shared__ __align__(16) float v[RB][304];
    __shared__ __align__(16) float fbl[RB][152];
    __shared__ int r_[RB], q_[RB], p_[RB];

    const int a0 = blockIdx.x * GB;
    const int tid = threadIdx.x;
    const int f = tid;

    if (tid < RB) {
        int a = a0 + tid / NB;
        int r = (a < A_TOT) ? a2b[a * NB + (tid % NB)] : 0;
        r_[tid] = r;
        q_[tid] = b2revb[r];
        p_[tid] = b2a[r];
    }
    __syncthreads();
    for (int idx = tid; idx < RB * 75; idx += 320) {
        int i = idx / 75, k4 = idx - i * 75;
        ((float4*)v[i])[k4] = ((const float4*)(msgA1 + (size_t)p_[i] * H))[k4];
    }
    for (int idx = tid; idx < RB * BF; idx += 320) {
        int i = idx / BF, k = idx - i * BF;
        fbl[i][k] = f_bonds[(size_t)q_[i] * BF + k];
    }
    __syncthreads();
    if (f < H) {
        float acc[RB];
#pragma unroll
        for (int i = 0; i < RB; ++i) acc[i] = 0.f;
        gemv4<RB, 152>(fbl, Wi_bond, BF, f, acc);
#pragma unroll
        for (int i = 0; i < RB; ++i) v[i][f] -= fmaxf(acc[i], 0.f);
    }
    __syncthreads();
    for (int idx = tid; idx < RB * BF; idx += 320) {
        int i = idx / BF, k = idx - i * BF;
        fbl[i][k] = f_bonds[(size_t)r_[i] * BF + k];
    }
    float accm[RB];
#pragma unroll
    for (int i = 0; i < RB; ++i) accm[i] = 0.f;
    if (f < H) gemv4<RB, 304>(v, Wh0, H, f, accm);
    __syncthreads();
    if (f < H) {
        float accr[RB];
#pragma unroll
        for (int i = 0; i < RB; ++i) accr[i] = 0.f;
        gemv4<RB, 152>(fbl, Wi_bond, BF, f, accr);
#pragma unroll
        for (int l = 0; l < GB; ++l) {
            float s = 0.f, mx = -INFINITY;
#pragma unroll
            for (int j = 0; j < NB; ++j) {
                int i = l * NB + j;
                float m1 = fmaxf(fmaxf(accr[i], 0.f) + accm[i], 0.f);
                s += m1; mx = fmaxf(mx, m1);
            }
            int a = a0 + l;
            if (a < A_TOT)
                msgA2[(size_t)a * H + f] = msgA1[(size_t)a * H + f] + s * mx;
        }
    }
}

#define GCB 2
#define RCB (GCB * NB)   // 12
__global__ __launch_bounds__(320) void k_agglb(
    const float* __restrict__ f_atoms, const float* __restrict__ f_bonds,
    const float* __restrict__ Wi_atom, const float* __restrict__ Wi_bond,
    const float* __restrict__ Wh0, const float* __restrict__ Wh1,
    const float* __restrict__ W_lr,
    const float* __restrict__ msgA1, const float* __restrict__ msgA2,
    const int* __restrict__ a2b, const int* __restrict__ b2a,
    const int* __restrict__ b2revb, float* __restrict__ aggL)
{
    __shared__ __align__(16) float u[RCB][304];
    __shared__ __align__(16) float w[RCB][304];
    __shared__ __align__(16) float fbl[RCB][152];
    __shared__ __align__(16) float agg3r[GCB][304];
    __shared__ __align__(16) float mA2r[GCB][304];
    __shared__ __align__(16) float inAr[GCB][304];
    __shared__ __align__(16) float fa[GCB][136];
    __shared__ int b_[RCB], rp_[RCB], p1_[RCB], q1_[RCB], p2_[RCB];

    const int a0 = blockIdx.x * GCB;
    const int tid = threadIdx.x;
    const int f = tid;

    if (tid < RCB) {
        int a = a0 + tid / NB;
        int b = (a < A_TOT) ? a2b[a * NB + (tid % NB)] : 0;
        int rp = b2revb[b];
        b_[tid] = b; rp_[tid] = rp;
        p1_[tid] = b2a[rp]; q1_[tid] = b2revb[rp]; p2_[tid] = b2a[b];
    }
    __syncthreads();
    for (int idx = tid; idx < RCB * 75; idx += 320) {
        int i = idx / 75, k4 = idx - i * 75;
        ((float4*)u[i])[k4] = ((const float4*)(msgA1 + (size_t)p1_[i] * H))[k4];
        ((float4*)w[i])[k4] = ((const float4*)(msgA2 + (size_t)p2_[i] * H))[k4];
    }
    for (int idx = tid; idx < RCB * BF; idx += 320) {
        int i = idx / BF, k = idx - i * BF;
        fbl[i][k] = f_bonds[(size_t)q1_[i] * BF + k];
    }
    for (int idx = tid; idx < GCB * 75; idx += 320) {
        int l = idx / 75, k4 = idx - l * 75;
        int a = a0 + l;
        ((float4*)mA2r[l])[k4] = (a < A_TOT) ? ((const float4*)(msgA2 + (size_t)a * H))[k4]
                                             : make_float4(0.f, 0.f, 0.f, 0.f);
    }
    for (int idx = tid; idx < GCB * AF; idx += 320) {
        int l = idx / AF, k = idx - l * AF;
        int a = a0 + l;
        fa[l][k] = (a < A_TOT) ? f_atoms[(size_t)a * AF + k] : 0.f;
    }
    __syncthreads();
    if (f < H) {
        float acc[RCB];
#pragma unroll
        for (int i = 0; i < RCB; ++i) acc[i] = 0.f;
        gemv4<RCB, 152>(fbl, Wi_bond, BF, f, acc);
#pragma unroll
        for (int i = 0; i < RCB; ++i) u[i][f] -= fmaxf(acc[i], 0.f);
    }
    __syncthreads();
    for (int idx = tid; idx < RCB * BF; idx += 320) {
        int i = idx / BF, k = idx - i * BF;
        fbl[i][k] = f_bonds[(size_t)rp_[i] * BF + k];
    }
    __syncthreads();
    if (f < H) {
        float accm[RCB], accr[RCB];
#pragma unroll
        for (int i = 0; i < RCB; ++i) { accm[i] = 0.f; accr[i] = 0.f; }
        gemv4<RCB, 304>(u, Wh0, H, f, accm);
        gemv4<RCB, 152>(fbl, Wi_bond, BF, f, accr);
#pragma unroll
        for (int i = 0; i < RCB; ++i)
            w[i][f] -= fmaxf(fmaxf(accr[i], 0.f) + accm[i], 0.f);
    }
    __syncthreads();
    for (int idx = tid; idx < RCB * BF; idx += 320) {
        int i = idx / BF, k = idx - i * BF;
        fbl[i][k] = f_bonds[(size_t)b_[i] * BF + k];
    }
    __syncthreads();
    if (f < H) {
        float accm[RCB], accb[RCB];
#pragma unroll
        for (int i = 0; i < RCB; ++i) { accm[i] = 0.f; accb[i] = 0.f; }
        gemv4<RCB, 304>(w, Wh1, H, f, accm);
        gemv4<RCB, 152>(fbl, Wi_bond, BF, f, accb);
#pragma unroll
        for (int l = 0; l < GCB; ++l) {
            float s = 0.f, mx = -INFINITY;
#pragma unroll
            for (int j = 0; j < NB; ++j) {
                int i = l * NB + j;
                float m2 = fmaxf(fmaxf(accb[i], 0.f) + accm[i], 0.f);
                s += m2; mx = fmaxf(mx, m2);
            }
            agg3r[l][f] = s * mx;
        }
        float acc2[GCB];
#pragma unroll
        for (int l = 0; l < GCB; ++l) acc2[l] = 0.f;
        gemv4<GCB, 136>(fa, Wi_atom, AF, f, acc2);
#pragma unroll
        for (int l = 0; l < GCB; ++l) inAr[l][f] = fmaxf(acc2[l], 0.f);
    }
    __syncthreads();
    if (f < H) {
        float accL[GCB];
#pragma unroll
        for (int l = 0; l < GCB; ++l) accL[l] = 0.f;
        gemv4<GCB, 304>(agg3r, W_lr,            H, f, accL);
        gemv4<GCB, 304>(mA2r, W_lr + 300 * 300, H, f, accL);
        gemv4<GCB, 304>(inAr, W_lr + 600 * 300, H, f, accL);
#pragma unroll
        for (int l = 0; l < GCB; ++l) {
            int a = a0 + l;
            if (a < A_TOT) aggL[(size_t)a * H + f] = accL[l];
        }
    }
}

// ===========================================================================
// Pack 4 [900,300] GRU weight mats -> P[k/4][gate][f][k%4]  (270000 each)
// ===========================================================================
__global__ __launch_bounds__(256) void k_pack4(
    const float* __restrict__ s0, const float* __restrict__ s1,
    const float* __restrict__ s2, const float* __restrict__ s3,
    float* __restrict__ d0, float* __restrict__ d1,
    float* __restrict__ d2, float* __restrict__ d3)
{
    const float* S[4] = {s0, s1, s2, s3};
    float* D[4] = {d0, d1, d2, d3};
    int z = blockIdx.y;
    int o = blockIdx.x * 256 + threadIdx.x;
    if (o < 270000) {
        int k4 = o / 3600; int rem = o - k4 * 3600;
        int g = rem / 1200; int rem2 = rem - g * 1200;
        int fx = rem2 >> 2; int kk = rem2 & 3;
        int k = k4 * 4 + kk;
        D[z][o] = S[z][(size_t)(g * 300 + fx) * 300 + k];
    }
}

// ===========================================================================
// prep: h0[m] = max_t aggL[1+m*40+t]; then aggL row <- relu(row + gru_bias)
// ===========================================================================
__global__ __launch_bounds__(256) void prep_kernel(
    float* aggL, const float* __restrict__ gru_bias, float* __restrict__ h0)
{
    int m = blockIdx.x;
    for (int f = threadIdx.x; f < H; f += 256) {
        float b = gru_bias[f];
        float mx = -INFINITY;
        for (int t = 0; t < ASZ; ++t) {
            size_t o = (size_t)(1 + m * ASZ + t) * H + f;
            float v = aggL[o];
            mx = fmaxf(mx, v);
            aggL[o] = fmaxf(v + b, 0.f);
        }
        h0[(size_t)m * H + f] = mx;
    }
}

__device__ __forceinline__ float dev_sigmoid(float x) {
    return 1.f / (1.f + __expf(-x));
}
__device__ __forceinline__ float dev_tanh(float x) {
    return 1.f - 2.f / (__expf(2.f * x) + 1.f);
}

// ===========================================================================
// Persistent GRU, v3 (R3-verified).
// ===========================================================================
#define GM 8
__global__ __launch_bounds__(320) void k_gru_all(
    const float* __restrict__ msg,
    const float* __restrict__ Pih_f, const float* __restrict__ Phh_f,
    const float* __restrict__ bih_f, const float* __restrict__ bhh_f,
    const float* __restrict__ Pih_b, const float* __restrict__ Phh_b,
    const float* __restrict__ bih_b, const float* __restrict__ bhh_b,
    const float* __restrict__ h0, float* __restrict__ out_f,
    float* __restrict__ out_b)
{
    __shared__ __align__(16) float hs[GM][304];
    __shared__ __align__(16) float ms[2][GM][304];

    const int bid  = blockIdx.x;
    const int xcd  = bid & 7;
    const int slot = bid >> 3;
    const int dir  = xcd >> 2;
    const int lg   = (xcd & 3) * 32 + slot;
    const int m0   = lg * GM;
    if (m0 >= NMOL) return;

    const float* Pih = dir ? Pih_b : Pih_f;
    const float* Phh = dir ? Phh_b : Phh_f;
    const float* bih = dir ? bih_b : bih_f;
    const float* bhh = dir ? bhh_b : bhh_f;
    float* out       = dir ? out_b : out_f;

    const int tid  = threadIdx.x;
    const bool act = tid < H;
    const int f    = act ? tid : (H - 1);

    for (int idx = tid; idx < GM * 75; idx += 320) {
        int i = idx / 75, k4 = idx - i * 75;
        int m = m0 + i;
        ((float4*)hs[i])[k4] = (m < NMOL) ? ((const float4*)(h0 + (size_t)m * H))[k4]
                                          : make_float4(0.f, 0.f, 0.f, 0.f);
    }
    {
        const int t0 = dir ? (ASZ - 1) : 0;
        for (int idx = tid; idx < GM * 75; idx += 320) {
            int i = idx / 75, k4 = idx - i * 75;
            int m = m0 + i;
            ((float4*)ms[0][i])[k4] = (m < NMOL)
                ? ((const float4*)(msg + (size_t)(m * ASZ + t0) * H))[k4]
                : make_float4(0.f, 0.f, 0.f, 0.f);
        }
    }

    float bR = 0.f, bZ = 0.f, bIN = 0.f, bHN = 0.f;
    if (act) {
        bR  = bih[f] + bhh[f];
        bZ  = bih[300 + f] + bhh[300 + f];
        bIN = bih[600 + f];
        bHN = bhh[600 + f];
    }
    const float* pi = Pih + (size_t)f * 4;
    const float* ph = Phh + (size_t)f * 4;

    for (int s = 0; s < ASZ; ++s) {
        const int cur = s & 1;
        const int t = dir ? (ASZ - 1 - s) : s;
        __syncthreads();

        float4 st0 = make_float4(0.f, 0.f, 0.f, 0.f);
        float4 st1 = make_float4(0.f, 0.f, 0.f, 0.f);
        const bool more = (s + 1 < ASZ);
        if (more) {
            const int tn = dir ? (ASZ - 2 - s) : (s + 1);
            {
                int i = tid / 75, k4 = tid - i * 75;
                int m = m0 + i;
                if (m < NMOL)
                    st0 = ((const float4*)(msg + (size_t)(m * ASZ + tn) * H))[k4];
            }
            {
                int idx = tid + 320;
                if (idx < GM * 75) {
                    int i = idx / 75, k4 = idx - i * 75;
                    int m = m0 + i;
                    if (m < NMOL)
                        st1 = ((const float4*)(msg + (size_t)(m * ASZ + tn) * H))[k4];
                }
            }
        }

        float aR[GM], aZ[GM], aIN[GM], aHN[GM];
#pragma unroll
        for (int i = 0; i < GM; ++i) { aR[i] = 0.f; aZ[i] = 0.f; aIN[i] = 0.f; aHN[i] = 0.f; }

        float4 wiR = *(const float4*)(pi);
        float4 wiZ = *(const float4*)(pi + 1200);
        float4 wiN = *(const float4*)(pi + 2400);
        float4 whR = *(const float4*)(ph);
        float4 whZ = *(const float4*)(ph + 1200);
        float4 whN = *(const float4*)(ph + 2400);

        for (int k4i = 0; k4i < 75; ++k4i) {
            const int kn = k4i + (k4i < 74 ? 1 : 0);
            const float* pin = pi + (size_t)kn * 3600;
            const float* phn = ph + (size_t)kn * 3600;
            float4 nR = *(const float4*)(pin);
            float4 nZ = *(const float4*)(pin + 1200);
            float4 nN = *(const float4*)(pin + 2400);
            float4 oR = *(const float4*)(phn);
            float4 oZ = *(const float4*)(phn + 1200);
            float4 oN = *(const float4*)(phn + 2400);

            const int k4 = k4i * 4;
#pragma unroll
            for (int i = 0; i < GM; ++i) {
                float4 m4 = *(const float4*)&ms[cur][i][k4];
                float4 h4 = *(const float4*)&hs[i][k4];
                aR[i]  = fmaf(m4.x, wiR.x, fmaf(m4.y, wiR.y, fmaf(m4.z, wiR.z, fmaf(m4.w, wiR.w, aR[i]))));
                aR[i]  = fmaf(h4.x, whR.x, fmaf(h4.y, whR.y, fmaf(h4.z, whR.z, fmaf(h4.w, whR.w, aR[i]))));
                aZ[i]  = fmaf(m4.x, wiZ.x, fmaf(m4.y, wiZ.y, fmaf(m4.z, wiZ.z, fmaf(m4.w, wiZ.w, aZ[i]))));
                aZ[i]  = fmaf(h4.x, whZ.x, fmaf(h4.y, whZ.y, fmaf(h4.z, whZ.z, fmaf(h4.w, whZ.w, aZ[i]))));
                aIN[i] = fmaf(m4.x, wiN.x, fmaf(m4.y, wiN.y, fmaf(m4.z, wiN.z, fmaf(m4.w, wiN.w, aIN[i]))));
                aHN[i] = fmaf(h4.x, whN.x, fmaf(h4.y, whN.y, fmaf(h4.z, whN.z, fmaf(h4.w, whN.w, aHN[i]))));
            }
            wiR = nR; wiZ = nZ; wiN = nN;
            whR = oR; whZ = oZ; whN = oN;
        }
        __syncthreads();

        if (act) {
#pragma unroll
            for (int i = 0; i < GM; ++i) {
                int m = m0 + i;
                if (m < NMOL) {
                    float r = dev_sigmoid(aR[i] + bR);
                    float z = dev_sigmoid(aZ[i] + bZ);
                    float n = dev_tanh(aIN[i] + bIN + r * (aHN[i] + bHN));
                    float hn = (1.f - z) * n + z * hs[i][f];
                    hs[i][f] = hn;
                    __builtin_nontemporal_store(hn, out + (size_t)(m * ASZ + t) * H + f);
                }
            }
        }
        if (more) {
            const int nxt = cur ^ 1;
            {
                int i = tid / 75, k4 = tid - i * 75;
                ((float4*)ms[nxt][i])[k4] = st0;
            }
            {
                int idx = tid + 320;
                if (idx < GM * 75) {
                    int i = idx / 75, k4 = idx - i * 75;
                    ((float4*)ms[nxt][i])[k4] = st1;
                }
            }
        }
    }
}

// ===========================================================================
// Fused output projection: hid = relu([outf|outb] @ W_o + b_o), K=600.
// ===========================================================================
__global__ __launch_bounds__(256) void gemm_wo(
    const float* __restrict__ A0, const float* __restrict__ A1,
    const float* __restrict__ W, float* __restrict__ C,
    const float* __restrict__ bias)
{
    const int M = NMOL * ASZ, K2 = 600, N = H;
    __shared__ float As[16][64];
    __shared__ float Bs[16][64];
    const int tx = threadIdx.x, ty = threadIdx.y;
    const int tid = ty * 16 + tx;
    const int m0 = blockIdx.x * 64, n0 = blockIdx.y * 64;
    const int am = tid >> 2, ak = (tid & 3) * 4;
    const int bk = tid >> 4, bn = (tid & 15) * 4;
    const int arow = m0 + am;

    float acc[4][4];
#pragma unroll
    for (int i = 0; i < 4; ++i)
#pragma unroll
        for (int j = 0; j < 4; ++j) acc[i][j] = 0.f;

    for (int k0 = 0; k0 < K2; k0 += 16) {
#pragma unroll
        for (int j = 0; j < 4; ++j) {
            int k = k0 + ak + j;
            float v = 0.f;
            if (arow < M && k < K2)
                v = (k < 300) ? A0[(size_t)arow * 300 + k]
                              : A1[(size_t)arow * 300 + (k - 300)];
            As[ak + j][am] = v;
        }
#pragma unroll
        for (int j = 0; j < 4; ++j) {
            int k = k0 + bk, n = n0 + bn + j;
            Bs[bk][bn + j] = (k < K2 && n < N) ? W[(size_t)k * N + n] : 0.f;
        }
        __syncthreads();
#pragma unroll
        for (int kk = 0; kk < 16; ++kk) {
            float4 av = *(const float4*)&As[kk][ty * 4];
            float4 bv = *(const float4*)&Bs[kk][tx * 4];
            float a4[4] = {av.x, av.y, av.z, av.w};
            float b4[4] = {bv.x, bv.y, bv.z, bv.w};
#pragma unroll
            for (int i = 0; i < 4; ++i)
#pragma unroll
                for (int j = 0; j < 4; ++j)
                    acc[i][j] = fmaf(a4[i], b4[j], acc[i][j]);
        }
        __syncthreads();
    }
#pragma unroll
    for (int i = 0; i < 4; ++i) {
        int m = m0 + ty * 4 + i;
        if (m >= M) continue;
#pragma unroll
        for (int j = 0; j < 4; ++j) {
            int n = n0 + tx * 4 + j;
            if (n >= N) continue;
            C[(size_t)m * N + n] = fmaxf(acc[i][j] + bias[n], 0.f);
        }
    }
}

__global__ __launch_bounds__(256) void mean_kernel(
    const float* __restrict__ hid, float* __restrict__ out)
{
    int m = blockIdx.x;
    for (int f = threadIdx.x; f < H; f += 256) {
        float s = 0.f;
        for (int t = 0; t < ASZ; ++t)
            s += hid[(size_t)(m * ASZ + t) * H + f];
        out[(size_t)m * H + f] = s * (1.f / 40.f);
    }
}

// ===========================================================================
extern "C" void kernel_launch(void* const* d_in, const int* in_sizes, int n_in,
                              void* d_out, int out_size, void* d_ws, size_t ws_size,
                              hipStream_t stream)
{
    const float* f_atoms  = (const float*)d_in[0];
    const float* f_bonds  = (const float*)d_in[1];
    const float* Wi_atom  = (const float*)d_in[2];
    const float* Wi_bond  = (const float*)d_in[3];
    const float* Wh0      = (const float*)d_in[4];
    const float* Wh1      = (const float*)d_in[5];
    const float* W_lr     = (const float*)d_in[6];
    const float* W_o      = (const float*)d_in[7];
    const float* b_o      = (const float*)d_in[8];
    const float* gru_bias = (const float*)d_in[9];
    const float* gWih_f   = (const float*)d_in[10];
    const float* gWhh_f   = (const float*)d_in[11];
    const float* gbih_f   = (const float*)d_in[12];
    const float* gbhh_f   = (const float*)d_in[13];
    const float* gWih_b   = (const float*)d_in[14];
    const float* gWhh_b   = (const float*)d_in[15];
    const float* gbih_b   = (const float*)d_in[16];
    const float* gbhh_b   = (const float*)d_in[17];
    const int*   a2b      = (const int*)d_in[18];
    const int*   b2a      = (const int*)d_in[19];
    const int*   b2revb   = (const int*)d_in[20];

    char* wsb = (char*)d_ws;
    const bool bigws = (ws_size >= (size_t)288003600);

    // Pack MP weights into d_out scratch (dead until mean_kernel overwrites it)
    float* dscratch = (float*)d_out;
    {
        dim3 g((90000 + 255) / 256, 4);
        k_packmp<<<g, 256, 0, stream>>>(Wh0, Wh1, Wi_bond, Wi_atom, dscratch);
    }
    const float4* PWh0 = (const float4*)(dscratch + PK_WH0);
    const float4* PWh1 = (const float4*)(dscratch + PK_WH1);
    const float4* PWib = (const float4*)(dscratch + PK_WIB);
    const float4* PWia = (const float4*)(dscratch + PK_WIA);

    float *aggLp, *outfp, *outbp, *h0p, *P0, *P1, *P2, *P3, *hidp;

    if (bigws) {
        // PATH A (R11 layout):
        //  R0 [0,48001200)          msgA1 -> msgA2 -> aggL (aggl3 own-row overwrite)
        //  R1 [48001200,96002400)   A2W (gemm) -> hid (post-GRU)
        //  R2 [96002400,288003600)  m1 -> M1W (row-staged in-place gemm)
        //                           | post-aggl3: outf/outb/packs/h0
        float* msgA = (float*)wsb;
        float* A2W  = (float*)(wsb + 48001200);
        float* m1   = (float*)(wsb + 96002400);
        outfp = (float*)(wsb + 96002400);
        outbp = (float*)(wsb + 144002400);
        P0 = (float*)(wsb + 192002400);
        P1 = P0 + 270000; P2 = P1 + 270000; P3 = P2 + 270000;
        h0p = (float*)(wsb + 196322400);
        aggLp = msgA; hidp = A2W;

        k_msga1<<<(A_TOT + GA - 1) / GA, 320, 0, stream>>>(
            f_atoms, f_bonds, PWia, PWib, a2b, msgA);
        k_m1f<<<(BN_TOT + NR2 - 1) / NR2, 320, 0, stream>>>(
            f_bonds, PWib, PWh0, msgA, b2a, b2revb, m1);
        k_msga2ef<<<(A_TOT * H + 255) / 256, 256, 0, stream>>>(m1, a2b, msgA);

        // A2W = msgA2 @ Wh1 (out of place); M1W = m1 @ Wh1 (in place, safe:
        // row-staged — each block stages its own rows in LDS before writing)
        k_gemm_rp<<<(A_TOT + RG - 1) / RG, 320, 0, stream>>>(msgA, A2W, PWh1, A_TOT);
        k_gemm_rp<<<(BN_TOT + RG - 1) / RG, 320, 0, stream>>>(m1, m1, PWh1, BN_TOT);

        k_aggl3f<<<(A_TOT + GC - 1) / GC, 320, 0, stream>>>(
            f_atoms, f_bonds, PWia, PWib, A2W, m1 /*=M1W*/, W_lr,
            msgA, a2b, b2a, b2revb, /*aggLout=*/msgA);
    } else {
        // PATH B: recompute path (no m1 buffer).  Peak = 240,003,600 B.
        float* ws = (float*)d_ws;
        float* msgA1 = ws;
        float* msgA2 = ws + 12000300;
        float* aggL  = ws + 24000600;
        outfp = ws + 36000900;
        outbp = ws + 48000900;
        h0p   = ws;
        P0 = ws + 300000; P1 = ws + 570000; P2 = ws + 840000; P3 = ws + 1110000;
        aggLp = aggL; hidp = msgA2;

        k_msga1<<<(A_TOT + GA - 1) / GA, 320, 0, stream>>>(
            f_atoms, f_bonds, PWia, PWib, a2b, msgA1);
        k_msga2b<<<(A_TOT + GB - 1) / GB, 320, 0, stream>>>(
            f_bonds, Wi_bond, Wh0, msgA1, msgA2, a2b, b2a, b2revb);
        k_agglb<<<(A_TOT + GCB - 1) / GCB, 320, 0, stream>>>(
            f_atoms, f_bonds, Wi_atom, Wi_bond, Wh0, Wh1, W_lr,
            msgA1, msgA2, a2b, b2a, b2revb, aggL);
    }

    // pack GRU weights (into regions dead after the MP phase)
    {
        dim3 g((270000 + 255) / 256, 4);
        k_pack4<<<g, 256, 0, stream>>>(gWih_f, gWhh_f, gWih_b, gWhh_b,
                                       P0, P1, P2, P3);
    }

    // h0 + in-place relu(aggL + bias)
    prep_kernel<<<NMOL, 256, 0, stream>>>(aggLp, gru_bias, h0p);

    // persistent GRU v3: 256 1D blocks x 320 threads, XCD-partitioned by dir
    k_gru_all<<<256, 320, 0, stream>>>(
        aggLp + H, P0, P1, gbih_f, gbhh_f, P2, P3, gbih_b, gbhh_b,
        h0p, outfp, outbp);

    // hid = relu([outf|outb]@W_o + b_o)
    {
        dim3 grid((NMOL * ASZ + 63) / 64, (H + 63) / 64);
        dim3 block(16, 16);
        gemm_wo<<<grid, block, 0, stream>>>(outfp, outbp, W_o, hidp, b_o);
    }

    // per-mol mean -> d_out (overwrites the weight-pack scratch)
    mean_kernel<<<NMOL, 256, 0, stream>>>(hidp, (float*)d_out);
}

// Round 12
// 6478.267 us; speedup vs baseline: 1.7838x; 1.0880x over previous
//
#include <hip/hip_runtime.h>
#include <math.h>

constexpr int A_TOT  = 40001;
constexpr int NB     = 6;
constexpr int BN_TOT = 160001;
constexpr int AF     = 133;
constexpr int BF     = 147;
constexpr int H      = 300;
constexpr int NMOL   = 1000;
constexpr int ASZ    = 40;

// Packed-weight layout: P[(k4*300+f)*4+j] = W[(k4*4+j)*300+f], zero-padded.
// Packs live in d_out scratch (dead until mean_kernel).
constexpr int PK_WH0 = 0;
constexpr int PK_WH1 = 90000;
constexpr int PK_WIB = 180000;
constexpr int PK_WIA = 224400;

// ---------------------------------------------------------------------------
// Raw GEMV core (W_lr and PATH B).
// ---------------------------------------------------------------------------
template<int NR, int P>
__device__ __forceinline__ void gemv4(const float (*rows)[P], const float* __restrict__ W,
                                      int K, int f, float* __restrict__ acc)
{
    int k4 = 0;
    for (; k4 + 4 <= K; k4 += 4) {
        float w0 = W[(k4 + 0) * H + f];
        float w1 = W[(k4 + 1) * H + f];
        float w2 = W[(k4 + 2) * H + f];
        float w3 = W[(k4 + 3) * H + f];
#pragma unroll
        for (int i = 0; i < NR; ++i) {
            float4 b = *(const float4*)&rows[i][k4];
            acc[i] = fmaf(b.x, w0, fmaf(b.y, w1, fmaf(b.z, w2, fmaf(b.w, w3, acc[i]))));
        }
    }
    for (; k4 < K; ++k4) {
        float wv = W[k4 * H + f];
#pragma unroll
        for (int i = 0; i < NR; ++i) acc[i] = fmaf(rows[i][k4], wv, acc[i]);
    }
}

// ---------------------------------------------------------------------------
// Packed GEMV core: one float4 weight load per k4. Rows zero-padded in LDS.
// k4i loop MUST stay rolled (R6: full unroll -> 128-VGPR cap spill).
// AMORTIZATION RULE (R7): rows-per-weight-load dominates; NR=12 > NR=6.
// ---------------------------------------------------------------------------
template<int NR, int P>
__device__ __forceinline__ void gemv4p(const float (*rows)[P], const float4* __restrict__ Pw,
                                       int K4, int f, float* __restrict__ acc)
{
#pragma clang loop unroll(disable)
    for (int k4i = 0; k4i < K4; ++k4i) {
        float4 w = Pw[k4i * 300 + f];
#pragma unroll
        for (int i = 0; i < NR; ++i) {
            float4 b = *(const float4*)&rows[i][k4i * 4];
            acc[i] = fmaf(b.x, w.x, fmaf(b.y, w.y, fmaf(b.z, w.z, fmaf(b.w, w.w, acc[i]))));
        }
    }
}

// ===========================================================================
// Pack Wh0/Wh1/Wi_bond/Wi_atom into d_out scratch.
// ===========================================================================
__global__ __launch_bounds__(256) void k_packmp(
    const float* __restrict__ s0, const float* __restrict__ s1,
    const float* __restrict__ s2, const float* __restrict__ s3,
    float* __restrict__ dout)
{
    const float* S[4] = {s0, s1, s2, s3};
    const int Ks[4]  = {300, 300, 147, 133};
    const int K4s[4] = {75, 75, 37, 34};
    const int off[4] = {PK_WH0, PK_WH1, PK_WIB, PK_WIA};
    int z = blockIdx.y;
    int o = blockIdx.x * 256 + threadIdx.x;
    int n = K4s[z] * 1200;
    if (o < n) {
        int k4 = o / 1200; int rem = o - k4 * 1200;
        int f = rem >> 2;  int j = rem & 3;
        int k = k4 * 4 + j;
        dout[off[z] + o] = (k < Ks[z]) ? S[z][(size_t)k * 300 + f] : 0.f;
    }
}

// ===========================================================================
// Row-staged GEMM: dst[M,300] = src[M,300] @ Wh1 (packed).  SAFE FOR
// dst == src: each block owns RG rows, stages them fully in LDS before any
// write, and no block touches another block's rows.  (R10 bug: tiled gemm
// with 5 n-blocks per row-group -> cross-block read/write race.)
// ===========================================================================
#define RG 16
__global__ __launch_bounds__(320) void k_gemm_rp(
    const float* __restrict__ src, float* __restrict__ dst,
    const float4* __restrict__ Pw, int M)
{
    __shared__ __align__(16) float rows[RG][304];
    const int r0 = blockIdx.x * RG;
    const int tid = threadIdx.x;
    const int f = tid;

    for (int idx = tid; idx < RG * 75; idx += 320) {
        int i = idx / 75, k4 = idx - i * 75;
        int r = r0 + i;
        ((float4*)rows[i])[k4] = (r < M) ? ((const float4*)(src + (size_t)r * H))[k4]
                                         : make_float4(0.f, 0.f, 0.f, 0.f);
    }
    __syncthreads();
    if (f < H) {
        float acc[RG];
#pragma unroll
        for (int i = 0; i < RG; ++i) acc[i] = 0.f;
        gemv4p<RG, 304>(rows, Pw, 75, f, acc);
#pragma unroll
        for (int i = 0; i < RG; ++i) {
            int r = r0 + i;
            if (r < M) dst[(size_t)r * H + f] = acc[i];
        }
    }
}

// ===========================================================================
// K1: msgA1[a,:] = relu(f_atoms[a]@Wi_atom) + sum*max of x_b.
// Chunked bond GEMV (NR=6) + rolled k4i loop.
// ===========================================================================
#define GA 4
__global__ __launch_bounds__(320) void k_msga1(
    const float* __restrict__ f_atoms, const float* __restrict__ f_bonds,
    const float4* __restrict__ PWia, const float4* __restrict__ PWib,
    const int* __restrict__ a2b, float* __restrict__ msgA1)
{
    __shared__ __align__(16) float fb[GA * NB][152];
    __shared__ __align__(16) float fa[GA][136];
    __shared__ int bidx[GA * NB];

    const int a0 = blockIdx.x * GA;
    const int tid = threadIdx.x;
    const int f = tid;

    if (tid < GA * NB) {
        int a = a0 + tid / NB;
        bidx[tid] = (a < A_TOT) ? a2b[a * NB + (tid % NB)] : 0;
    }
    __syncthreads();
    for (int idx = tid; idx < GA * NB * 148; idx += 320) {
        int i = idx / 148, k = idx - i * 148;
        fb[i][k] = (k < BF) ? f_bonds[(size_t)bidx[i] * BF + k] : 0.f;
    }
    for (int idx = tid; idx < GA * 136; idx += 320) {
        int l = idx / 136, k = idx - l * 136;
        int a = a0 + l;
        fa[l][k] = (a < A_TOT && k < AF) ? f_atoms[(size_t)a * AF + k] : 0.f;
    }
    __syncthreads();

    if (f < H) {
        float part[GA];
#pragma unroll
        for (int l = 0; l < GA; ++l) {
            float acc[NB];
#pragma unroll
            for (int j = 0; j < NB; ++j) acc[j] = 0.f;
            gemv4p<NB, 152>((const float (*)[152])&fb[l * NB], PWib, 37, f, acc);
            float s = 0.f, mx = -INFINITY;
#pragma unroll
            for (int j = 0; j < NB; ++j) {
                float x = fmaxf(acc[j], 0.f);
                s += x; mx = fmaxf(mx, x);
            }
            part[l] = s * mx;
        }
        float acc2[GA];
#pragma unroll
        for (int l = 0; l < GA; ++l) acc2[l] = 0.f;
        gemv4p<GA, 136>(fa, PWia, 34, f, acc2);
#pragma unroll
        for (int l = 0; l < GA; ++l) {
            int a = a0 + l;
            if (a < A_TOT) msgA1[(size_t)a * H + f] = fmaxf(acc2[l], 0.f) + part[l];
        }
    }
}

// ===========================================================================
// PATH A: m1 fp32 materialization.  NR2=8, rolled gemv loops.
// ===========================================================================
#define NR2 8
__global__ __launch_bounds__(320) void k_m1f(
    const float* __restrict__ f_bonds, const float4* __restrict__ PWib,
    const float4* __restrict__ PWh0, const float* __restrict__ msgA1,
    const int* __restrict__ b2a, const int* __restrict__ b2revb,
    float* __restrict__ m1)
{
    __shared__ __align__(16) float v[NR2][304];
    __shared__ __align__(16) float fbl[NR2][152];
    __shared__ int r_[NR2], q_[NR2], p_[NR2];

    const int r0 = blockIdx.x * NR2;
    const int tid = threadIdx.x;
    const int f = tid;

    if (tid < NR2) {
        int r = r0 + tid;
        if (r >= BN_TOT) r = 0;
        r_[tid] = r;
        q_[tid] = b2revb[r];
        p_[tid] = b2a[r];
    }
    __syncthreads();
    for (int idx = tid; idx < NR2 * 75; idx += 320) {
        int i = idx / 75, k4 = idx - i * 75;
        ((float4*)v[i])[k4] = ((const float4*)(msgA1 + (size_t)p_[i] * H))[k4];
    }
    for (int idx = tid; idx < NR2 * 148; idx += 320) {
        int i = idx / 148, k = idx - i * 148;
        fbl[i][k] = (k < BF) ? f_bonds[(size_t)q_[i] * BF + k] : 0.f;
    }
    __syncthreads();
    if (f < H) {
        float acc[NR2];
#pragma unroll
        for (int i = 0; i < NR2; ++i) acc[i] = 0.f;
        gemv4p<NR2, 152>(fbl, PWib, 37, f, acc);
#pragma unroll
        for (int i = 0; i < NR2; ++i) v[i][f] -= fmaxf(acc[i], 0.f);
    }
    __syncthreads();
    for (int idx = tid; idx < NR2 * 148; idx += 320) {
        int i = idx / 148, k = idx - i * 148;
        fbl[i][k] = (k < BF) ? f_bonds[(size_t)r_[i] * BF + k] : 0.f;
    }
    float accm[NR2];
#pragma unroll
    for (int i = 0; i < NR2; ++i) accm[i] = 0.f;
    if (f < H) gemv4p<NR2, 304>(v, PWh0, 75, f, accm);
    __syncthreads();
    if (f < H) {
        float accr[NR2];
#pragma unroll
        for (int i = 0; i < NR2; ++i) accr[i] = 0.f;
        gemv4p<NR2, 152>(fbl, PWib, 37, f, accr);
#pragma unroll
        for (int i = 0; i < NR2; ++i) {
            int r = r0 + i;
            if (r < BN_TOT)
                m1[(size_t)r * H + f] = fmaxf(fmaxf(accr[i], 0.f) + accm[i], 0.f);
        }
    }
}

__global__ __launch_bounds__(256) void k_msga2ef(
    const float* __restrict__ m1, const int* __restrict__ a2b, float* msgA)
{
    int idx = blockIdx.x * 256 + threadIdx.x;
    if (idx >= A_TOT * H) return;
    int a = idx / H;
    int f = idx - a * H;
    float s = 0.f, mx = -INFINITY;
#pragma unroll
    for (int j = 0; j < NB; ++j) {
        int r = a2b[a * NB + j];
        float v = m1[(size_t)r * H + f];
        s += v;
        mx = fmaxf(mx, v);
    }
    msgA[idx] += s * mx;
}

// ===========================================================================
// aggl3 (R11-verified): Wh1 gemv eliminated via linearity — m2 = relu(x_b +
// A2W[p2] - M1W[rp]) with A2W = msgA2@Wh1, M1W = m1@Wh1 (k_gemm_rp).
// Writes aggL over msgA[a] (own-row only; cross-row msgA consumption is
// pre-materialized in A2W — race-free).
// ===========================================================================
#define GC 2
#define RC (GC * NB)   // 12
__global__ __launch_bounds__(320) void k_aggl3f(
    const float* __restrict__ f_atoms, const float* __restrict__ f_bonds,
    const float4* __restrict__ PWia, const float4* __restrict__ PWib,
    const float* __restrict__ A2W, const float* __restrict__ M1W,
    const float* __restrict__ W_lr, const float* __restrict__ msgA2,
    const int* __restrict__ a2b, const int* __restrict__ b2a,
    const int* __restrict__ b2revb, float* __restrict__ aggLout)
{
    __shared__ __align__(16) float w[RC][304];
    __shared__ __align__(16) float fbl[RC][152];
    __shared__ __align__(16) float agg3r[GC][304];
    __shared__ __align__(16) float mA2r[GC][304];
    __shared__ __align__(16) float inAr[GC][304];
    __shared__ __align__(16) float fa[GC][136];
    __shared__ int b_[RC], rp_[RC], p2_[RC];

    const int a0 = blockIdx.x * GC;
    const int tid = threadIdx.x;
    const int f = tid;

    if (tid < RC) {
        int a = a0 + tid / NB;
        int b = (a < A_TOT) ? a2b[a * NB + (tid % NB)] : 0;
        b_[tid] = b;
        rp_[tid] = b2revb[b];
        p2_[tid] = b2a[b];
    }
    __syncthreads();
    for (int idx = tid; idx < RC * 75; idx += 320) {
        int i = idx / 75, k4 = idx - i * 75;
        float4 a4 = ((const float4*)(A2W + (size_t)p2_[i] * H))[k4];
        float4 b4 = ((const float4*)(M1W + (size_t)rp_[i] * H))[k4];
        ((float4*)w[i])[k4] = make_float4(a4.x - b4.x, a4.y - b4.y, a4.z - b4.z, a4.w - b4.w);
    }
    for (int idx = tid; idx < RC * 148; idx += 320) {
        int i = idx / 148, k = idx - i * 148;
        fbl[i][k] = (k < BF) ? f_bonds[(size_t)b_[i] * BF + k] : 0.f;
    }
    for (int idx = tid; idx < GC * 75; idx += 320) {
        int l = idx / 75, k4 = idx - l * 75;
        int a = a0 + l;
        ((float4*)mA2r[l])[k4] = (a < A_TOT) ? ((const float4*)(msgA2 + (size_t)a * H))[k4]
                                             : make_float4(0.f, 0.f, 0.f, 0.f);
    }
    for (int idx = tid; idx < GC * 136; idx += 320) {
        int l = idx / 136, k = idx - l * 136;
        int a = a0 + l;
        fa[l][k] = (a < A_TOT && k < AF) ? f_atoms[(size_t)a * AF + k] : 0.f;
    }
    __syncthreads();

    if (f < H) {
        float accb[RC];
#pragma unroll
        for (int i = 0; i < RC; ++i) accb[i] = 0.f;
        gemv4p<RC, 152>(fbl, PWib, 37, f, accb);
#pragma unroll
        for (int l = 0; l < GC; ++l) {
            float s = 0.f, mx = -INFINITY;
#pragma unroll
            for (int j = 0; j < NB; ++j) {
                int i = l * NB + j;
                float m2 = fmaxf(fmaxf(accb[i], 0.f) + w[i][f], 0.f);
                s += m2; mx = fmaxf(mx, m2);
            }
            agg3r[l][f] = s * mx;
        }
        float acc2[GC];
#pragma unroll
        for (int l = 0; l < GC; ++l) acc2[l] = 0.f;
        gemv4p<GC, 136>(fa, PWia, 34, f, acc2);
#pragma unroll
        for (int l = 0; l < GC; ++l) inAr[l][f] = fmaxf(acc2[l], 0.f);
    }
    __syncthreads();

    if (f < H) {
        float accL[GC];
#pragma unroll
        for (int l = 0; l < GC; ++l) accL[l] = 0.f;
        gemv4<GC, 304>(agg3r, W_lr,            H, f, accL);
        gemv4<GC, 304>(mA2r, W_lr + 300 * 300, H, f, accL);
        gemv4<GC, 304>(inAr, W_lr + 600 * 300, H, f, accL);
#pragma unroll
        for (int l = 0; l < GC; ++l) {
            int a = a0 + l;
            if (a < A_TOT) aggLout[(size_t)a * H + f] = accL[l];
        }
    }
}

// ===========================================================================
// PATH B kernels (not exercised when bigws) — unchanged.
// ===========================================================================
#define GB 4
#define RB (GB * NB)   // 24
__global__ __launch_bounds__(320) void k_msga2b(
    const float* __restrict__ f_bonds, const float* __restrict__ Wi_bond,
    const float* __restrict__ Wh0,
    const float* __restrict__ msgA1, float* __restrict__ msgA2,
    const int* __restrict__ a2b, const int* __restrict__ b2a,
    const int* __restrict__ b2revb)
{
    __shared__ __align__(16) float v[RB][304];
    __shared__ __align__(16) float fbl[RB][152];
    __shared__ int r_[RB], q_[RB], p_[RB];

    const int a0 = blockIdx.x * GB;
    const int tid = threadIdx.x;
    const int f = tid;

    if (tid < RB) {
        int a = a0 + tid / NB;
        int r = (a < A_TOT) ? a2b[a * NB + (tid % NB)] : 0;
        r_[tid] = r;
        q_[tid] = b2revb[r];
        p_[tid] = b2a[r];
    }
    __syncthreads();
    for (int idx = tid; idx < RB * 75; idx += 320) {
        int i = idx / 75, k4 = idx - i * 75;
        ((float4*)v[i])[k4] = ((const float4*)(msgA1 + (size_t)p_[i] * H))[k4];
    }
    for (int idx = tid; idx < RB * BF; idx += 320) {
        int i = idx / BF, k = idx - i * BF;
        fbl[i][k] = f_bonds[(size_t)q_[i] * BF + k];
    }
    __syncthreads();
    if (f < H) {
        float acc[RB];
#pragma unroll
        for (int i = 0; i < RB; ++i) acc[i] = 0.f;
        gemv4<RB, 152>(fbl, Wi_bond, BF, f, acc);
#pragma unroll
        for (int i = 0; i < RB; ++i) v[i][f] -= fmaxf(acc[i], 0.f);
    }
    __syncthreads();
    for (int idx = tid; idx < RB * BF; idx += 320) {
        int i = idx / BF, k = idx - i * BF;
        fbl[i][k] = f_bonds[(size_t)r_[i] * BF + k];
    }
    float accm[RB];
#pragma unroll
    for (int i = 0; i < RB; ++i) accm[i] = 0.f;
    if (f < H) gemv4<RB, 304>(v, Wh0, H, f, accm);
    __syncthreads();
    if (f < H) {
        float accr[RB];
#pragma unroll
        for (int i = 0; i < RB; ++i) accr[i] = 0.f;
        gemv4<RB, 152>(fbl, Wi_bond, BF, f, accr);
#pragma unroll
        for (int l = 0; l < GB; ++l) {
            float s = 0.f, mx = -INFINITY;
#pragma unroll
            for (int j = 0; j < NB; ++j) {
                int i = l * NB + j;
                float m1 = fmaxf(fmaxf(accr[i], 0.f) + accm[i], 0.f);
                s += m1; mx = fmaxf(mx, m1);
            }
            int a = a0 + l;
            if (a < A_TOT)
                msgA2[(size_t)a * H + f] = msgA1[(size_t)a * H + f] + s * mx;
        }
    }
}

#define GCB 2
#define RCB (GCB * NB)   // 12
__global__ __launch_bounds__(320) void k_agglb(
    const float* __restrict__ f_atoms, const float* __restrict__ f_bonds,
    const float* __restrict__ Wi_atom, const float* __restrict__ Wi_bond,
    const float* __restrict__ Wh0, const float* __restrict__ Wh1,
    const float* __restrict__ W_lr,
    const float* __restrict__ msgA1, const float* __restrict__ msgA2,
    const int* __restrict__ a2b, const int* __restrict__ b2a,
    const int* __restrict__ b2revb, float* __restrict__ aggL)
{
    __shared__ __align__(16) float u[RCB][304];
    __shared__ __align__(16) float w[RCB][304];
    __shared__ __align__(16) float fbl[RCB][152];
    __shared__ __align__(16) float agg3r[GCB][304];
    __shared__ __align__(16) float mA2r[GCB][304];
    __shared__ __align__(16) float inAr[GCB][304];
    __shared__ __align__(16) float fa[GCB][136];
    __shared__ int b_[RCB], rp_[RCB], p1_[RCB], q1_[RCB], p2_[RCB];

    const int a0 = blockIdx.x * GCB;
    const int tid = threadIdx.x;
    const int f = tid;

    if (tid < RCB) {
        int a = a0 + tid / NB;
        int b = (a < A_TOT) ? a2b[a * NB + (tid % NB)] : 0;
        int rp = b2revb[b];
        b_[tid] = b; rp_[tid] = rp;
        p1_[tid] = b2a[rp]; q1_[tid] = b2revb[rp]; p2_[tid] = b2a[b];
    }
    __syncthreads();
    for (int idx = tid; idx < RCB * 75; idx += 320) {
        int i = idx / 75, k4 = idx - i * 75;
        ((float4*)u[i])[k4] = ((const float4*)(msgA1 + (size_t)p1_[i] * H))[k4];
        ((float4*)w[i])[k4] = ((const float4*)(msgA2 + (size_t)p2_[i] * H))[k4];
    }
    for (int idx = tid; idx < RCB * BF; idx += 320) {
        int i = idx / BF, k = idx - i * BF;
        fbl[i][k] = f_bonds[(size_t)q1_[i] * BF + k];
    }
    for (int idx = tid; idx < GCB * 75; idx += 320) {
        int l = idx / 75, k4 = idx - l * 75;
        int a = a0 + l;
        ((float4*)mA2r[l])[k4] = (a < A_TOT) ? ((const float4*)(msgA2 + (size_t)a * H))[k4]
                                             : make_float4(0.f, 0.f, 0.f, 0.f);
    }
    for (int idx = tid; idx < GCB * AF; idx += 320) {
        int l = idx / AF, k = idx - l * AF;
        int a = a0 + l;
        fa[l][k] = (a < A_TOT) ? f_atoms[(size_t)a * AF + k] : 0.f;
    }
    __syncthreads();
    if (f < H) {
        float acc[RCB];
#pragma unroll
        for (int i = 0; i < RCB; ++i) acc[i] = 0.f;
        gemv4<RCB, 152>(fbl, Wi_bond, BF, f, acc);
#pragma unroll
        for (int i = 0; i < RCB; ++i) u[i][f] -= fmaxf(acc[i], 0.f);
    }
    __syncthreads();
    for (int idx = tid; idx < RCB * BF; idx += 320) {
        int i = idx / BF, k = idx - i * BF;
        fbl[i][k] = f_bonds[(size_t)rp_[i] * BF + k];
    }
    __syncthreads();
    if (f < H) {
        float accm[RCB], accr[RCB];
#pragma unroll
        for (int i = 0; i < RCB; ++i) { accm[i] = 0.f; accr[i] = 0.f; }
        gemv4<RCB, 304>(u, Wh0, H, f, accm);
        gemv4<RCB, 152>(fbl, Wi_bond, BF, f, accr);
#pragma unroll
        for (int i = 0; i < RCB; ++i)
            w[i][f] -= fmaxf(fmaxf(accr[i], 0.f) + accm[i], 0.f);
    }
    __syncthreads();
    for (int idx = tid; idx < RCB * BF; idx += 320) {
        int i = idx / BF, k = idx - i * BF;
        fbl[i][k] = f_bonds[(size_t)b_[i] * BF + k];
    }
    __syncthreads();
    if (f < H) {
        float accm[RCB], accb[RCB];
#pragma unroll
        for (int i = 0; i < RCB; ++i) { accm[i] = 0.f; accb[i] = 0.f; }
        gemv4<RCB, 304>(w, Wh1, H, f, accm);
        gemv4<RCB, 152>(fbl, Wi_bond, BF, f, accb);
#pragma unroll
        for (int l = 0; l < GCB; ++l) {
            float s = 0.f, mx = -INFINITY;
#pragma unroll
            for (int j = 0; j < NB; ++j) {
                int i = l * NB + j;
                float m2 = fmaxf(fmaxf(accb[i], 0.f) + accm[i], 0.f);
                s += m2; mx = fmaxf(mx, m2);
            }
            agg3r[l][f] = s * mx;
        }
        float acc2[GCB];
#pragma unroll
        for (int l = 0; l < GCB; ++l) acc2[l] = 0.f;
        gemv4<GCB, 136>(fa, Wi_atom, AF, f, acc2);
#pragma unroll
        for (int l = 0; l < GCB; ++l) inAr[l][f] = fmaxf(acc2[l], 0.f);
    }
    __syncthreads();
    if (f < H) {
        float accL[GCB];
#pragma unroll
        for (int l = 0; l < GCB; ++l) accL[l] = 0.f;
        gemv4<GCB, 304>(agg3r, W_lr,            H, f, accL);
        gemv4<GCB, 304>(mA2r, W_lr + 300 * 300, H, f, accL);
        gemv4<GCB, 304>(inAr, W_lr + 600 * 300, H, f, accL);
#pragma unroll
        for (int l = 0; l < GCB; ++l) {
            int a = a0 + l;
            if (a < A_TOT) aggL[(size_t)a * H + f] = accL[l];
        }
    }
}

// ===========================================================================
// Pack 4 [900,300] GRU weight mats -> P[k/4][gate][f][k%4]  (270000 each)
// ===========================================================================
__global__ __launch_bounds__(256) void k_pack4(
    const float* __restrict__ s0, const float* __restrict__ s1,
    const float* __restrict__ s2, const float* __restrict__ s3,
    float* __restrict__ d0, float* __restrict__ d1,
    float* __restrict__ d2, float* __restrict__ d3)
{
    const float* S[4] = {s0, s1, s2, s3};
    float* D[4] = {d0, d1, d2, d3};
    int z = blockIdx.y;
    int o = blockIdx.x * 256 + threadIdx.x;
    if (o < 270000) {
        int k4 = o / 3600; int rem = o - k4 * 3600;
        int g = rem / 1200; int rem2 = rem - g * 1200;
        int fx = rem2 >> 2; int kk = rem2 & 3;
        int k = k4 * 4 + kk;
        D[z][o] = S[z][(size_t)(g * 300 + fx) * 300 + k];
    }
}

// ===========================================================================
// prep: h0[m] = max_t aggL[1+m*40+t]; then aggL row <- relu(row + gru_bias)
// ===========================================================================
__global__ __launch_bounds__(256) void prep_kernel(
    float* aggL, const float* __restrict__ gru_bias, float* __restrict__ h0)
{
    int m = blockIdx.x;
    for (int f = threadIdx.x; f < H; f += 256) {
        float b = gru_bias[f];
        float mx = -INFINITY;
        for (int t = 0; t < ASZ; ++t) {
            size_t o = (size_t)(1 + m * ASZ + t) * H + f;
            float v = aggL[o];
            mx = fmaxf(mx, v);
            aggL[o] = fmaxf(v + b, 0.f);
        }
        h0[(size_t)m * H + f] = mx;
    }
}

__device__ __forceinline__ float dev_sigmoid(float x) {
    return 1.f / (1.f + __expf(-x));
}
__device__ __forceinline__ float dev_tanh(float x) {
    return 1.f - 2.f / (__expf(2.f * x) + 1.f);
}

// ===========================================================================
// Persistent GRU, v4 (R12): GM 8->4, 512 blocks -> 2 blocks/CU.
//  - R11 counters: occupancy 14.7%, VALUBusy 47% at 1 block/CU — imbalanced
//    VALU (2 waves on SIMD0) + nothing to overlap barriers/LDS with.
//  - Same XCD/direction partition: xcd=bid&7, dir=xcd>>2, 64 slots/quadrant.
//  - GM*75=300 <= 320: staging is single-shot (no strided loop, one st reg).
// ===========================================================================
#define GM 4
__global__ __launch_bounds__(320) void k_gru_all(
    const float* __restrict__ msg,
    const float* __restrict__ Pih_f, const float* __restrict__ Phh_f,
    const float* __restrict__ bih_f, const float* __restrict__ bhh_f,
    const float* __restrict__ Pih_b, const float* __restrict__ Phh_b,
    const float* __restrict__ bih_b, const float* __restrict__ bhh_b,
    const float* __restrict__ h0, float* __restrict__ out_f,
    float* __restrict__ out_b)
{
    __shared__ __align__(16) float hs[GM][304];
    __shared__ __align__(16) float ms[2][GM][304];

    const int bid  = blockIdx.x;
    const int xcd  = bid & 7;
    const int slot = bid >> 3;               // 0..63
    const int dir  = xcd >> 2;               // 0 on XCD 0-3, 1 on XCD 4-7
    const int lg   = (xcd & 3) * 64 + slot;  // 0..255 local mol-group
    const int m0   = lg * GM;
    if (m0 >= NMOL) return;

    const float* Pih = dir ? Pih_b : Pih_f;
    const float* Phh = dir ? Phh_b : Phh_f;
    const float* bih = dir ? bih_b : bih_f;
    const float* bhh = dir ? bhh_b : bhh_f;
    float* out       = dir ? out_b : out_f;

    const int tid  = threadIdx.x;
    const bool act = tid < H;
    const int f    = act ? tid : (H - 1);

    const bool stg = tid < GM * 75;          // 300 staging lanes
    const int si = stg ? tid / 75 : 0;
    const int sk = stg ? tid - si * 75 : 0;
    const int sm = m0 + si;

    if (stg) {
        ((float4*)hs[si])[sk] = (sm < NMOL) ? ((const float4*)(h0 + (size_t)sm * H))[sk]
                                            : make_float4(0.f, 0.f, 0.f, 0.f);
        const int t0 = dir ? (ASZ - 1) : 0;
        ((float4*)ms[0][si])[sk] = (sm < NMOL)
            ? ((const float4*)(msg + (size_t)(sm * ASZ + t0) * H))[sk]
            : make_float4(0.f, 0.f, 0.f, 0.f);
    }

    float bR = 0.f, bZ = 0.f, bIN = 0.f, bHN = 0.f;
    if (act) {
        bR  = bih[f] + bhh[f];
        bZ  = bih[300 + f] + bhh[300 + f];
        bIN = bih[600 + f];
        bHN = bhh[600 + f];
    }
    const float* pi = Pih + (size_t)f * 4;
    const float* ph = Phh + (size_t)f * 4;

    for (int s = 0; s < ASZ; ++s) {
        const int cur = s & 1;
        const int t = dir ? (ASZ - 1 - s) : s;
        __syncthreads();                      // ms[cur] + hs ready

        // issue next-step staging load early (hides under FMA phase)
        float4 st0 = make_float4(0.f, 0.f, 0.f, 0.f);
        const bool more = (s + 1 < ASZ);
        if (more && stg && sm < NMOL) {
            const int tn = dir ? (ASZ - 2 - s) : (s + 1);
            st0 = ((const float4*)(msg + (size_t)(sm * ASZ + tn) * H))[sk];
        }

        float aR[GM], aZ[GM], aIN[GM], aHN[GM];
#pragma unroll
        for (int i = 0; i < GM; ++i) { aR[i] = 0.f; aZ[i] = 0.f; aIN[i] = 0.f; aHN[i] = 0.f; }

        float4 wiR = *(const float4*)(pi);
        float4 wiZ = *(const float4*)(pi + 1200);
        float4 wiN = *(const float4*)(pi + 2400);
        float4 whR = *(const float4*)(ph);
        float4 whZ = *(const float4*)(ph + 1200);
        float4 whN = *(const float4*)(ph + 2400);

        for (int k4i = 0; k4i < 75; ++k4i) {
            const int kn = k4i + (k4i < 74 ? 1 : 0);
            const float* pin = pi + (size_t)kn * 3600;
            const float* phn = ph + (size_t)kn * 3600;
            float4 nR = *(const float4*)(pin);
            float4 nZ = *(const float4*)(pin + 1200);
            float4 nN = *(const float4*)(pin + 2400);
            float4 oR = *(const float4*)(phn);
            float4 oZ = *(const float4*)(phn + 1200);
            float4 oN = *(const float4*)(phn + 2400);

            const int k4 = k4i * 4;
#pragma unroll
            for (int i = 0; i < GM; ++i) {
                float4 m4 = *(const float4*)&ms[cur][i][k4];
                float4 h4 = *(const float4*)&hs[i][k4];
                aR[i]  = fmaf(m4.x, wiR.x, fmaf(m4.y, wiR.y, fmaf(m4.z, wiR.z, fmaf(m4.w, wiR.w, aR[i]))));
                aR[i]  = fmaf(h4.x, whR.x, fmaf(h4.y, whR.y, fmaf(h4.z, whR.z, fmaf(h4.w, whR.w, aR[i]))));
                aZ[i]  = fmaf(m4.x, wiZ.x, fmaf(m4.y, wiZ.y, fmaf(m4.z, wiZ.z, fmaf(m4.w, wiZ.w, aZ[i]))));
                aZ[i]  = fmaf(h4.x, whZ.x, fmaf(h4.y, whZ.y, fmaf(h4.z, whZ.z, fmaf(h4.w, whZ.w, aZ[i]))));
                aIN[i] = fmaf(m4.x, wiN.x, fmaf(m4.y, wiN.y, fmaf(m4.z, wiN.z, fmaf(m4.w, wiN.w, aIN[i]))));
                aHN[i] = fmaf(h4.x, whN.x, fmaf(h4.y, whN.y, fmaf(h4.z, whN.z, fmaf(h4.w, whN.w, aHN[i]))));
            }
            wiR = nR; wiZ = nZ; wiN = nN;
            whR = oR; whZ = oZ; whN = oN;
        }
        __syncthreads();   // all hs/ms[cur] reads done before updates

        if (act) {
#pragma unroll
            for (int i = 0; i < GM; ++i) {
                int m = m0 + i;
                if (m < NMOL) {
                    float r = dev_sigmoid(aR[i] + bR);
                    float z = dev_sigmoid(aZ[i] + bZ);
                    float n = dev_tanh(aIN[i] + bIN + r * (aHN[i] + bHN));
                    float hn = (1.f - z) * n + z * hs[i][f];
                    hs[i][f] = hn;
                    __builtin_nontemporal_store(hn, out + (size_t)(m * ASZ + t) * H + f);
                }
            }
        }
        if (more && stg) {
            ((float4*)ms[cur ^ 1][si])[sk] = st0;
        }
        // top-of-loop barrier orders hs/ms writes before next step's reads
    }
}

// ===========================================================================
// Fused output projection: hid = relu([outf|outb] @ W_o + b_o), K=600.
// ===========================================================================
__global__ __launch_bounds__(256) void gemm_wo(
    const float* __restrict__ A0, const float* __restrict__ A1,
    const float* __restrict__ W, float* __restrict__ C,
    const float* __restrict__ bias)
{
    const int M = NMOL * ASZ, K2 = 600, N = H;
    __shared__ float As[16][64];
    __shared__ float Bs[16][64];
    const int tx = threadIdx.x, ty = threadIdx.y;
    const int tid = ty * 16 + tx;
    const int m0 = blockIdx.x * 64, n0 = blockIdx.y * 64;
    const int am = tid >> 2, ak = (tid & 3) * 4;
    const int bk = tid >> 4, bn = (tid & 15) * 4;
    const int arow = m0 + am;

    float acc[4][4];
#pragma unroll
    for (int i = 0; i < 4; ++i)
#pragma unroll
        for (int j = 0; j < 4; ++j) acc[i][j] = 0.f;

    for (int k0 = 0; k0 < K2; k0 += 16) {
#pragma unroll
        for (int j = 0; j < 4; ++j) {
            int k = k0 + ak + j;
            float v = 0.f;
            if (arow < M && k < K2)
                v = (k < 300) ? A0[(size_t)arow * 300 + k]
                              : A1[(size_t)arow * 300 + (k - 300)];
            As[ak + j][am] = v;
        }
#pragma unroll
        for (int j = 0; j < 4; ++j) {
            int k = k0 + bk, n = n0 + bn + j;
            Bs[bk][bn + j] = (k < K2 && n < N) ? W[(size_t)k * N + n] : 0.f;
        }
        __syncthreads();
#pragma unroll
        for (int kk = 0; kk < 16; ++kk) {
            float4 av = *(const float4*)&As[kk][ty * 4];
            float4 bv = *(const float4*)&Bs[kk][tx * 4];
            float a4[4] = {av.x, av.y, av.z, av.w};
            float b4[4] = {bv.x, bv.y, bv.z, bv.w};
#pragma unroll
            for (int i = 0; i < 4; ++i)
#pragma unroll
                for (int j = 0; j < 4; ++j)
                    acc[i][j] = fmaf(a4[i], b4[j], acc[i][j]);
        }
        __syncthreads();
    }
#pragma unroll
    for (int i = 0; i < 4; ++i) {
        int m = m0 + ty * 4 + i;
        if (m >= M) continue;
#pragma unroll
        for (int j = 0; j < 4; ++j) {
            int n = n0 + tx * 4 + j;
            if (n >= N) continue;
            C[(size_t)m * N + n] = fmaxf(acc[i][j] + bias[n], 0.f);
        }
    }
}

__global__ __launch_bounds__(256) void mean_kernel(
    const float* __restrict__ hid, float* __restrict__ out)
{
    int m = blockIdx.x;
    for (int f = threadIdx.x; f < H; f += 256) {
        float s = 0.f;
        for (int t = 0; t < ASZ; ++t)
            s += hid[(size_t)(m * ASZ + t) * H + f];
        out[(size_t)m * H + f] = s * (1.f / 40.f);
    }
}

// ===========================================================================
extern "C" void kernel_launch(void* const* d_in, const int* in_sizes, int n_in,
                              void* d_out, int out_size, void* d_ws, size_t ws_size,
                              hipStream_t stream)
{
    const float* f_atoms  = (const float*)d_in[0];
    const float* f_bonds  = (const float*)d_in[1];
    const float* Wi_atom  = (const float*)d_in[2];
    const float* Wi_bond  = (const float*)d_in[3];
    const float* Wh0      = (const float*)d_in[4];
    const float* Wh1      = (const float*)d_in[5];
    const float* W_lr     = (const float*)d_in[6];
    const float* W_o      = (const float*)d_in[7];
    const float* b_o      = (const float*)d_in[8];
    const float* gru_bias = (const float*)d_in[9];
    const float* gWih_f   = (const float*)d_in[10];
    const float* gWhh_f   = (const float*)d_in[11];
    const float* gbih_f   = (const float*)d_in[12];
    const float* gbhh_f   = (const float*)d_in[13];
    const float* gWih_b   = (const float*)d_in[14];
    const float* gWhh_b   = (const float*)d_in[15];
    const float* gbih_b   = (const float*)d_in[16];
    const float* gbhh_b   = (const float*)d_in[17];
    const int*   a2b      = (const int*)d_in[18];
    const int*   b2a      = (const int*)d_in[19];
    const int*   b2revb   = (const int*)d_in[20];

    char* wsb = (char*)d_ws;
    const bool bigws = (ws_size >= (size_t)288003600);

    // Pack MP weights into d_out scratch (dead until mean_kernel overwrites it)
    float* dscratch = (float*)d_out;
    {
        dim3 g((90000 + 255) / 256, 4);
        k_packmp<<<g, 256, 0, stream>>>(Wh0, Wh1, Wi_bond, Wi_atom, dscratch);
    }
    const float4* PWh0 = (const float4*)(dscratch + PK_WH0);
    const float4* PWh1 = (const float4*)(dscratch + PK_WH1);
    const float4* PWib = (const float4*)(dscratch + PK_WIB);
    const float4* PWia = (const float4*)(dscratch + PK_WIA);

    float *aggLp, *outfp, *outbp, *h0p, *P0, *P1, *P2, *P3, *hidp;

    if (bigws) {
        // PATH A (R11-verified layout):
        //  R0 [0,48001200)          msgA1 -> msgA2 -> aggL (aggl3 own-row overwrite)
        //  R1 [48001200,96002400)   A2W (gemm) -> hid (post-GRU)
        //  R2 [96002400,288003600)  m1 -> M1W (row-staged in-place gemm)
        //                           | post-aggl3: outf/outb/packs/h0
        float* msgA = (float*)wsb;
        float* A2W  = (float*)(wsb + 48001200);
        float* m1   = (float*)(wsb + 96002400);
        outfp = (float*)(wsb + 96002400);
        outbp = (float*)(wsb + 144002400);
        P0 = (float*)(wsb + 192002400);
        P1 = P0 + 270000; P2 = P1 + 270000; P3 = P2 + 270000;
        h0p = (float*)(wsb + 196322400);
        aggLp = msgA; hidp = A2W;

        k_msga1<<<(A_TOT + GA - 1) / GA, 320, 0, stream>>>(
            f_atoms, f_bonds, PWia, PWib, a2b, msgA);
        k_m1f<<<(BN_TOT + NR2 - 1) / NR2, 320, 0, stream>>>(
            f_bonds, PWib, PWh0, msgA, b2a, b2revb, m1);
        k_msga2ef<<<(A_TOT * H + 255) / 256, 256, 0, stream>>>(m1, a2b, msgA);

        // A2W = msgA2 @ Wh1 (out of place); M1W = m1 @ Wh1 (in place, safe:
        // row-staged — each block stages its own rows in LDS before writing)
        k_gemm_rp<<<(A_TOT + RG - 1) / RG, 320, 0, stream>>>(msgA, A2W, PWh1, A_TOT);
        k_gemm_rp<<<(BN_TOT + RG - 1) / RG, 320, 0, stream>>>(m1, m1, PWh1, BN_TOT);

        k_aggl3f<<<(A_TOT + GC - 1) / GC, 320, 0, stream>>>(
            f_atoms, f_bonds, PWia, PWib, A2W, m1 /*=M1W*/, W_lr,
            msgA, a2b, b2a, b2revb, /*aggLout=*/msgA);
    } else {
        // PATH B: recompute path (no m1 buffer).  Peak = 240,003,600 B.
        float* ws = (float*)d_ws;
        float* msgA1 = ws;
        float* msgA2 = ws + 12000300;
        float* aggL  = ws + 24000600;
        outfp = ws + 36000900;
        outbp = ws + 48000900;
        h0p   = ws;
        P0 = ws + 300000; P1 = ws + 570000; P2 = ws + 840000; P3 = ws + 1110000;
        aggLp = aggL; hidp = msgA2;

        k_msga1<<<(A_TOT + GA - 1) / GA, 320, 0, stream>>>(
            f_atoms, f_bonds, PWia, PWib, a2b, msgA1);
        k_msga2b<<<(A_TOT + GB - 1) / GB, 320, 0, stream>>>(
            f_bonds, Wi_bond, Wh0, msgA1, msgA2, a2b, b2a, b2revb);
        k_agglb<<<(A_TOT + GCB - 1) / GCB, 320, 0, stream>>>(
            f_atoms, f_bonds, Wi_atom, Wi_bond, Wh0, Wh1, W_lr,
            msgA1, msgA2, a2b, b2a, b2revb, aggL);
    }

    // pack GRU weights (into regions dead after the MP phase)
    {
        dim3 g((270000 + 255) / 256, 4);
        k_pack4<<<g, 256, 0, stream>>>(gWih_f, gWhh_f, gWih_b, gWhh_b,
                                       P0, P1, P2, P3);
    }

    // h0 + in-place relu(aggL + bias)
    prep_kernel<<<NMOL, 256, 0, stream>>>(aggLp, gru_bias, h0p);

    // persistent GRU v4: 512 1D blocks x 320 threads (GM=4, 2 blocks/CU),
    // XCD-partitioned by direction
    k_gru_all<<<512, 320, 0, stream>>>(
        aggLp + H, P0, P1, gbih_f, gbhh_f, P2, P3, gbih_b, gbhh_b,
        h0p, outfp, outbp);

    // hid = relu([outf|outb]@W_o + b_o)
    {
        dim3 grid((NMOL * ASZ + 63) / 64, (H + 63) / 64);
        dim3 block(16, 16);
        gemm_wo<<<grid, block, 0, stream>>>(outfp, outbp, W_o, hidp, b_o);
    }

    // per-mol mean -> d_out (overwrites the weight-pack scratch)
    mean_kernel<<<NMOL, 256, 0, stream>>>(hidp, (float*)d_out);
}